// Round 1
// baseline (1795.358 us; speedup 1.0000x reference)
//
#include <hip/hip_runtime.h>
#include <hip/hip_bf16.h>

// Problem constants
#define NB 32
#define NC 256
#define NHW 3136                 // 56*56
#define NA 25690112ull           // NB*NC*NHW elements (one NCHW tensor)

typedef __attribute__((ext_vector_type(8))) short bf16x8;
typedef __attribute__((ext_vector_type(4))) float f32x4;

// Window mapping: h=h1*8+j1, w=w1*8+j2; j=j1*8+j2 (0..63), p=h1*7+w1 (0..48).
// Windowed linear index n' = j*49 + p within a (b,c) plane.

// ---------------------------------------------------------------------------
// K1: BatchNorm stats -> per-channel affine (a,b): xn = a*x + b.
// Also precomputes combined depthwise weights wcomb = 0.25*(w3+w5+w7) (7x7),
// bias sum bsum, and bf16 copy of qkv weights (rows 3c..3c+2 per block).
// ---------------------------------------------------------------------------
__launch_bounds__(256)
__global__ void bn_stats(const float* __restrict__ x, const float* __restrict__ gamma,
                         const float* __restrict__ beta,
                         const float* __restrict__ w3, const float* __restrict__ b3,
                         const float* __restrict__ w5, const float* __restrict__ b5,
                         const float* __restrict__ w7, const float* __restrict__ b7,
                         const float* __restrict__ qkvw,
                         float* __restrict__ ab, float* __restrict__ wcomb,
                         float* __restrict__ bsum, __hip_bfloat16* __restrict__ Wb)
{
    const int c = blockIdx.x;
    const int tid = threadIdx.x;

    if (tid < 49) {
        const int ty = tid / 7, tx = tid % 7;
        float wv = w7[c * 49 + tid];
        if (ty >= 1 && ty <= 5 && tx >= 1 && tx <= 5) wv += w5[c * 25 + (ty - 1) * 5 + (tx - 1)];
        if (ty >= 2 && ty <= 4 && tx >= 2 && tx <= 4) wv += w3[c * 9 + (ty - 2) * 3 + (tx - 2)];
        wcomb[c * 49 + tid] = 0.25f * wv;
    }
    if (tid == 63) bsum[c] = 0.25f * (b3[c] + b5[c] + b7[c]);

    // bf16 conversion of qkv weights: block c handles output rows 3c..3c+2
#pragma unroll
    for (int r = 0; r < 3; ++r) {
        const int o = 3 * c + r;
        Wb[o * 256 + tid] = __float2bfloat16(qkvw[o * 256 + tid]);
    }

    float s = 0.f, s2 = 0.f;
    for (int b = 0; b < NB; ++b) {
        const float4* p = reinterpret_cast<const float4*>(x + ((size_t)b * NC + c) * NHW);
        for (int i = tid; i < NHW / 4; i += 256) {      // 3136/4 = 784
            const float4 v = p[i];
            s += v.x + v.y + v.z + v.w;
            s2 = fmaf(v.x, v.x, s2); s2 = fmaf(v.y, v.y, s2);
            s2 = fmaf(v.z, v.z, s2); s2 = fmaf(v.w, v.w, s2);
        }
    }
    __shared__ float r1[256], r2[256];
    r1[tid] = s; r2[tid] = s2;
    __syncthreads();
    for (int off = 128; off > 0; off >>= 1) {
        if (tid < off) { r1[tid] += r1[tid + off]; r2[tid] += r2[tid + off]; }
        __syncthreads();
    }
    if (tid == 0) {
        const float inv_n = 1.f / (float)((size_t)NB * NHW);
        const float mean = r1[0] * inv_n;
        const float var = r2[0] * inv_n - mean * mean;
        const float a = gamma[c] / sqrtf(var + 1e-5f);
        ab[c] = a;
        ab[NC + c] = beta[c] - mean * a;
    }
}

// ---------------------------------------------------------------------------
// K1.5: xn = a*x+b applied once; emits
//   XW  bf16 [b][c][n]  (normal layout; later windowed in-place by repack_win)
//   XNt bf16 [(b*3136+n)][c]  (k-contiguous transposed activations for MFMA)
// Block: 64 n x 256 c of one batch. Transpose through LDS; all HBM accesses
// coalesced (x reads 256B runs, XW writes 128B runs, XNt writes 512B runs).
// ---------------------------------------------------------------------------
__launch_bounds__(256)
__global__ void xnt_make(const float* __restrict__ x, const float* __restrict__ ab,
                         unsigned short* __restrict__ XNt, unsigned short* __restrict__ XW)
{
    const int n0 = blockIdx.x * 64;
    const int b = blockIdx.y;
    __shared__ unsigned short lt[64 * 264];   // [n][c] pad 264 (8B-aligned rows)
    __shared__ float aa[256], bb[256];
    const int t = threadIdx.x;
    aa[t] = ab[t];
    bb[t] = ab[256 + t];
    __syncthreads();
    const int tl = t & 15, g = t >> 4;
    const int nq = tl * 4;
#pragma unroll
    for (int it = 0; it < 16; ++it) {
        const int c = it * 16 + g;
        const size_t base = ((size_t)b * NC + c) * NHW + n0 + nq;
        float4 v = *reinterpret_cast<const float4*>(&x[base]);
        const float a = aa[c], bv = bb[c];
        v.x = fmaf(a, v.x, bv); v.y = fmaf(a, v.y, bv);
        v.z = fmaf(a, v.z, bv); v.w = fmaf(a, v.w, bv);
        union { ushort4 u; __hip_bfloat16 h[4]; } pk;
        pk.h[0] = __float2bfloat16(v.x); pk.h[1] = __float2bfloat16(v.y);
        pk.h[2] = __float2bfloat16(v.z); pk.h[3] = __float2bfloat16(v.w);
        *reinterpret_cast<ushort4*>(&XW[base]) = pk.u;
        lt[(nq + 0) * 264 + c] = pk.u.x;
        lt[(nq + 1) * 264 + c] = pk.u.y;
        lt[(nq + 2) * 264 + c] = pk.u.z;
        lt[(nq + 3) * 264 + c] = pk.u.w;
    }
    __syncthreads();
#pragma unroll
    for (int p = 0; p < 16; ++p) {
        const int idx = p * 256 + t;          // 0..4095
        const int row = idx >> 6;             // 0..63
        const int c4 = (idx & 63) * 4;        // 0..252
        *reinterpret_cast<ushort4*>(&XNt[((size_t)b * NHW + n0 + row) * 256 + c4]) =
            *reinterpret_cast<const ushort4*>(&lt[row * 264 + c4]);
    }
}

// ---------------------------------------------------------------------------
// K2: QKV 1x1-conv as bf16 MFMA GEMM. Out[o][nn] = sum_c Wb[o][c]*XNt[nn][c],
// nn = b*3136+n merged (100352 rows = 784 exact 128-tiles). Block tile
// 128o x 128n, 4 waves (2x2), wave = 64x64 = 16 mfma_f32_16x16x32_bf16 frags.
// Both operands staged [row][k] with pad 72 (2-way bank aliasing = free),
// ds_read_b128 fragments. A/B lane->k maps are identical for 16x16 MFMA, so
// any within-instruction k permutation cancels (layout-hypothesis-invariant).
// Epilogue: bias add, o-major transpose through LDS, bf16 writes in 256B runs.
// ---------------------------------------------------------------------------
__launch_bounds__(256)
__global__ void gemm_qkv_mfma(const unsigned short* __restrict__ XNt,
                              const unsigned short* __restrict__ Wb,
                              const float* __restrict__ bias,
                              unsigned short* __restrict__ Qb)
{
    __shared__ unsigned short As[128 * 72];   // W tile   [o][k]
    __shared__ unsigned short Bs[128 * 72];   // XNt tile [n][k]
    const int t = threadIdx.x;
    const int nn0 = blockIdx.x * 128;
    const int o0 = blockIdx.y * 128;
    const int lane = t & 63;
    const int wid = t >> 6;
    const int lr = lane & 15, lg = lane >> 4;
    const int wo = (wid >> 1) * 64;
    const int wn = (wid & 1) * 64;

    f32x4 acc[4][4];
#pragma unroll
    for (int i = 0; i < 4; ++i)
#pragma unroll
        for (int j = 0; j < 4; ++j)
            acc[i][j] = (f32x4){0.f, 0.f, 0.f, 0.f};

    for (int kt = 0; kt < 4; ++kt) {
        const int k0 = kt * 64;
#pragma unroll
        for (int it = 0; it < 4; ++it) {
            const int idx = it * 256 + t;     // 0..1023
            const int row = idx >> 3;         // 0..127
            const int k8 = (idx & 7) * 8;     // 0..56
            *reinterpret_cast<uint4*>(&As[row * 72 + k8]) =
                *reinterpret_cast<const uint4*>(&Wb[(size_t)(o0 + row) * 256 + k0 + k8]);
            *reinterpret_cast<uint4*>(&Bs[row * 72 + k8]) =
                *reinterpret_cast<const uint4*>(&XNt[(size_t)(nn0 + row) * 256 + k0 + k8]);
        }
        __syncthreads();
#pragma unroll
        for (int ks = 0; ks < 2; ++ks) {
            const int kk = ks * 32 + lg * 8;
            bf16x8 af[4], bfr[4];
#pragma unroll
            for (int i = 0; i < 4; ++i) {
                af[i]  = *reinterpret_cast<const bf16x8*>(&As[(wo + i * 16 + lr) * 72 + kk]);
                bfr[i] = *reinterpret_cast<const bf16x8*>(&Bs[(wn + i * 16 + lr) * 72 + kk]);
            }
#pragma unroll
            for (int i = 0; i < 4; ++i)
#pragma unroll
                for (int j = 0; j < 4; ++j)
                    acc[i][j] = __builtin_amdgcn_mfma_f32_16x16x32_bf16(
                        af[i], bfr[j], acc[i][j], 0, 0, 0);
        }
        __syncthreads();
    }

    // Epilogue: per osub pass, 32 o-rows x 128 n-cols through LDS (aliases As).
    float* Ts = reinterpret_cast<float*>(As);  // 32 x 132 fp32 = 16.5 KB
#pragma unroll
    for (int osub = 0; osub < 4; ++osub) {
        const float4 b4 = *reinterpret_cast<const float4*>(&bias[o0 + wo + osub * 16 + 4 * lg]);
        const int rowb = (wid >> 1) * 16 + 4 * lg;
#pragma unroll
        for (int j = 0; j < 4; ++j) {
            const int col = wn + j * 16 + lr;
            Ts[(rowb + 0) * 132 + col] = acc[osub][j][0] + b4.x;
            Ts[(rowb + 1) * 132 + col] = acc[osub][j][1] + b4.y;
            Ts[(rowb + 2) * 132 + col] = acc[osub][j][2] + b4.z;
            Ts[(rowb + 3) * 132 + col] = acc[osub][j][3] + b4.w;
        }
        __syncthreads();
#pragma unroll
        for (int p = 0; p < 4; ++p) {
            const int idx = p * 256 + t;      // 0..1023
            const int row = idx >> 5;         // 0..31
            const int c4 = (idx & 31) * 4;    // 0..124
            const float4 v = *reinterpret_cast<const float4*>(&Ts[row * 132 + c4]);
            const int o = o0 + (row >> 4) * 64 + osub * 16 + (row & 15);
            const int nn = nn0 + c4;
            const int bb2 = nn / NHW;
            const int n = nn - bb2 * NHW;
            union { ushort4 u; __hip_bfloat16 h[4]; } pk;
            pk.h[0] = __float2bfloat16(v.x);
            pk.h[1] = __float2bfloat16(v.y);
            pk.h[2] = __float2bfloat16(v.z);
            pk.h[3] = __float2bfloat16(v.w);
            *reinterpret_cast<ushort4*>(&Qb[((size_t)bb2 * 768 + o) * NHW + n]) = pk.u;
        }
        __syncthreads();
    }
}

// ---------------------------------------------------------------------------
// K2/K4/K6 (fp32 path, now FFN only): 1x1-conv GEMM, K=256.
// 64x64 tile per block, 4x4 register tile per thread. n-order agnostic.
// RES: add shortcut (same n-order as output) contiguous float4 in epilogue.
// ---------------------------------------------------------------------------
template<bool AFF, bool WINOUT, bool RES>
__launch_bounds__(256)
__global__ void gemm_k256(const float* __restrict__ X, const float* __restrict__ Wt,
                          const float* __restrict__ bias, const float* __restrict__ ab,
                          const float* __restrict__ res, float* __restrict__ outF,
                          __hip_bfloat16* __restrict__ outW,
                          __hip_bfloat16* __restrict__ xnw, int O)
{
    __shared__ float Xs[64][64];
    __shared__ float Ws[64][64];
    const int b = blockIdx.z;
    const int n0 = blockIdx.x * 64;   // 49 tiles * 64 = 3136 exact
    const int o0 = blockIdx.y * 64;
    const float* Xb = X + (size_t)b * NC * NHW;
    const int t = threadIdx.x;
    const int f4 = (t & 15) * 4;      // staging column (x4)
    const int r16 = t >> 4;           // staging row group
    const int tn = (t & 15) * 4;      // compute: n offset
    const int to = (t >> 4) * 4;      // compute: o offset

    float4 acc[4];
#pragma unroll
    for (int i = 0; i < 4; ++i) acc[i] = make_float4(0.f, 0.f, 0.f, 0.f);

    for (int kc = 0; kc < 4; ++kc) {
#pragma unroll
        for (int ps = 0; ps < 4; ++ps) {
            const int rr = r16 + ps * 16;        // 0..63
            const int c = kc * 64 + rr;          // k index
            float4 xv = *reinterpret_cast<const float4*>(Xb + (size_t)c * NHW + n0 + f4);
            if (AFF) {
                const float aa = ab[c], bb = ab[NC + c];
                xv.x = fmaf(aa, xv.x, bb); xv.y = fmaf(aa, xv.y, bb);
                xv.z = fmaf(aa, xv.z, bb); xv.w = fmaf(aa, xv.w, bb);
                if (blockIdx.y == 0) {
                    union { ushort4 u; __hip_bfloat16 h[4]; } px;
                    px.h[0] = __float2bfloat16(xv.x); px.h[1] = __float2bfloat16(xv.y);
                    px.h[2] = __float2bfloat16(xv.z); px.h[3] = __float2bfloat16(xv.w);
                    *reinterpret_cast<ushort4*>(xnw + ((size_t)(b * NC + c)) * NHW + n0 + f4) = px.u;
                }
            }
            *reinterpret_cast<float4*>(&Xs[rr][f4]) = xv;
            float4 wv = *reinterpret_cast<const float4*>(Wt + (size_t)(o0 + rr) * NC + kc * 64 + f4);
            *reinterpret_cast<float4*>(&Ws[rr][f4]) = wv;
        }
        __syncthreads();
#pragma unroll
        for (int k4 = 0; k4 < 16; ++k4) {
            float4 xr[4], wr[4];
#pragma unroll
            for (int jj = 0; jj < 4; ++jj)
                xr[jj] = *reinterpret_cast<const float4*>(&Xs[k4 * 4 + jj][tn]);
#pragma unroll
            for (int i = 0; i < 4; ++i)
                wr[i] = *reinterpret_cast<const float4*>(&Ws[to + i][k4 * 4]);
#pragma unroll
            for (int i = 0; i < 4; ++i) {
                acc[i].x = fmaf(wr[i].x, xr[0].x, acc[i].x);
                acc[i].y = fmaf(wr[i].x, xr[0].y, acc[i].y);
                acc[i].z = fmaf(wr[i].x, xr[0].z, acc[i].z);
                acc[i].w = fmaf(wr[i].x, xr[0].w, acc[i].w);
                acc[i].x = fmaf(wr[i].y, xr[1].x, acc[i].x);
                acc[i].y = fmaf(wr[i].y, xr[1].y, acc[i].y);
                acc[i].z = fmaf(wr[i].y, xr[1].z, acc[i].z);
                acc[i].w = fmaf(wr[i].y, xr[1].w, acc[i].w);
                acc[i].x = fmaf(wr[i].z, xr[2].x, acc[i].x);
                acc[i].y = fmaf(wr[i].z, xr[2].y, acc[i].y);
                acc[i].z = fmaf(wr[i].z, xr[2].z, acc[i].z);
                acc[i].w = fmaf(wr[i].z, xr[2].w, acc[i].w);
                acc[i].x = fmaf(wr[i].w, xr[3].x, acc[i].x);
                acc[i].y = fmaf(wr[i].w, xr[3].y, acc[i].y);
                acc[i].z = fmaf(wr[i].w, xr[3].z, acc[i].z);
                acc[i].w = fmaf(wr[i].w, xr[3].w, acc[i].w);
            }
        }
        __syncthreads();
    }
    // epilogue
#pragma unroll
    for (int io = 0; io < 4; ++io) {
        const int o = o0 + to + io;
        const float bs = bias[o];
        float vals[4] = {acc[io].x + bs, acc[io].y + bs, acc[io].z + bs, acc[io].w + bs};
        if (WINOUT) {
            union { ushort4 u; __hip_bfloat16 h[4]; } pk;
#pragma unroll
            for (int i = 0; i < 4; ++i) pk.h[i] = __float2bfloat16(vals[i]);
            *reinterpret_cast<ushort4*>(outW + ((size_t)((size_t)b * 768 + o)) * NHW + n0 + tn) = pk.u;
        } else {
            if (RES) {
                const float4 rv = *reinterpret_cast<const float4*>(
                    res + ((size_t)(b * NC + o)) * NHW + n0 + tn);
                vals[0] += rv.x; vals[1] += rv.y; vals[2] += rv.z; vals[3] += rv.w;
            }
            float* op = outF + ((size_t)b * NC + o) * NHW + n0 + tn;
            *reinterpret_cast<float4*>(op) = make_float4(vals[0], vals[1], vals[2], vals[3]);
        }
    }
}

// ---------------------------------------------------------------------------
// K2.5: in-place normal -> windowed permute of one (b,c) plane (bf16).
// cg 0..767 -> Qb plane, 768..1023 -> XW plane.
// ---------------------------------------------------------------------------
__launch_bounds__(256)
__global__ void repack_win(__hip_bfloat16* __restrict__ Qb, __hip_bfloat16* __restrict__ XW)
{
    const int cg = blockIdx.x;
    const int b = blockIdx.y;
    unsigned short* plane = (unsigned short*)(
        (cg < 768) ? (Qb + ((size_t)b * 768 + cg) * NHW)
                   : (XW + ((size_t)b * 256 + (cg - 768)) * NHW));
    __shared__ unsigned short lds[3136];
    const int tid = threadIdx.x;
    const ushort4* in4 = reinterpret_cast<const ushort4*>(plane);
    for (int i = tid; i < 784; i += 256)
        reinterpret_cast<ushort4*>(lds)[i] = in4[i];
    __syncthreads();
    ushort4* out4 = reinterpret_cast<ushort4*>(plane);
    for (int i = tid; i < 784; i += 256) {
        unsigned short tmp[4];
#pragma unroll
        for (int e = 0; e < 4; ++e) {
            const int n = 4 * i + e;
            const int j = n / 49, p = n - 49 * j;
            const int h1 = p / 7, w1 = p - 7 * h1;
            tmp[e] = lds[(h1 * 8 + (j >> 3)) * 56 + w1 * 8 + (j & 7)];
        }
        ushort4 v; v.x = tmp[0]; v.y = tmp[1]; v.z = tmp[2]; v.w = tmp[3];
        out4[i] = v;
    }
}

// ---------------------------------------------------------------------------
// K3: per-(window, head) attention + combined 7x7 depthwise conv + residuals.
// NOTE: plain __launch_bounds__(256) — the (256,3) variant capped VGPRs at 84
// and spilled per-thread arrays to scratch (R2/R3 post-mortem). Do not re-add.
// ---------------------------------------------------------------------------
#define DOT4(accv, sv, vv2) \
    accv = fmaf(sv.x, vv2.x, accv); accv = fmaf(sv.y, vv2.y, accv); \
    accv = fmaf(sv.z, vv2.z, accv); accv = fmaf(sv.w, vv2.w, accv);

#define QK4(areg, qc) \
    areg.x = fmaf(qc, kv.x, areg.x); areg.y = fmaf(qc, kv.y, areg.y); \
    areg.z = fmaf(qc, kv.z, areg.z); areg.w = fmaf(qc, kv.w, areg.w);

__launch_bounds__(256)
__global__ void attn_win(const __hip_bfloat16* __restrict__ Q,
                         const __hip_bfloat16* __restrict__ XW,
                         const float* __restrict__ wcomb, const float* __restrict__ bsumg,
                         float* __restrict__ xa)
{
    const int j = blockIdx.x;            // window id 0..63
    const int nh = blockIdx.y;           // head
    const int b = blockIdx.z;
    const int c0 = nh * 32;
    __shared__ float qs[32][52];         // q, later reused as x_spa
    __shared__ float ks[32][52];
    __shared__ float vs[32][52];         // v + xn residual
    __shared__ float xs[32][52];         // xn window (dw conv input)
    __shared__ float S[52][52];          // scores / probs
    __shared__ float wc[32 * 49];        // combined dw weights
    __shared__ float bsum[32];
    const int tid = threadIdx.x;

    for (int idx = tid; idx < 32 * 49; idx += 256) wc[idx] = wcomb[c0 * 49 + idx];
    if (tid < 32) bsum[tid] = bsumg[c0 + tid];
    if (tid >= 32 && tid < 128) {        // zero pad cols 49..51 of vs
        const int k = tid - 32;
        vs[k / 3][49 + (k % 3)] = 0.f;
    }

    const size_t bq = (size_t)b * 768 * NHW;
    const int wb = j * 49;
    for (int idx = tid; idx < 32 * 49; idx += 256) {
        const int d = idx / 49, p = idx % 49;
        const int cq = c0 + d;
        const float xv = __bfloat162float(XW[((size_t)(b * NC + cq)) * NHW + wb + p]);
        xs[d][p] = xv;
        qs[d][p] = __bfloat162float(Q[bq + (size_t)cq * NHW + wb + p]);
        ks[d][p] = __bfloat162float(Q[bq + (size_t)(256 + cq) * NHW + wb + p]);
        vs[d][p] = __bfloat162float(Q[bq + (size_t)(512 + cq) * NHW + wb + p]) + xv;
    }
    __syncthreads();

    // S = (q^T k) * 1/sqrt(32), 4x4 tiles
    const float sc = 0.17677669529663687f;
    for (int it = tid; it < 169; it += 256) {
        const int i0 = (it / 13) * 4, j0 = (it % 13) * 4;
        float4 a0 = make_float4(0,0,0,0), a1 = a0, a2 = a0, a3 = a0;
#pragma unroll
        for (int d = 0; d < 32; ++d) {
            const float4 qv = *reinterpret_cast<const float4*>(&qs[d][i0]);
            const float4 kv = *reinterpret_cast<const float4*>(&ks[d][j0]);
            QK4(a0, qv.x) QK4(a1, qv.y) QK4(a2, qv.z) QK4(a3, qv.w)
        }
        const float4 rows[4] = {a0, a1, a2, a3};
#pragma unroll
        for (int m = 0; m < 4; ++m) {
            if (i0 + m < 49) {
                float4 sv;
                sv.x = rows[m].x * sc;
                sv.y = (j0 + 1 < 49) ? rows[m].y * sc : 0.f;
                sv.z = (j0 + 2 < 49) ? rows[m].z * sc : 0.f;
                sv.w = (j0 + 3 < 49) ? rows[m].w * sc : 0.f;
                *reinterpret_cast<float4*>(&S[i0 + m][j0]) = sv;
            }
        }
    }
    __syncthreads();

    // softmax over keys: 4 lanes per query row, shfl_xor row-combine
    if (tid < 196) {
        const int r = tid >> 2, qr = tid & 3;
        const int i0q = qr * 13;
        const int i1q = (qr == 3) ? 49 : i0q + 13;
        float m = -1e30f;
        for (int i = i0q; i < i1q; ++i) m = fmaxf(m, S[r][i]);
        m = fmaxf(m, __shfl_xor(m, 1));
        m = fmaxf(m, __shfl_xor(m, 2));
        float sum = 0.f;
        for (int i = i0q; i < i1q; ++i) {
            const float e = __expf(S[r][i] - m);
            S[r][i] = e; sum += e;
        }
        sum += __shfl_xor(sum, 1);
        sum += __shfl_xor(sum, 2);
        const float inv = 1.f / sum;
        for (int i = i0q; i < i1q; ++i) S[r][i] *= inv;
    }
    __syncthreads();

    // O = P @ V, 4p x 4d tiles; write into qs as spa[d][p]
    for (int it = tid; it < 104; it += 256) {
        const int p0 = (it / 8) * 4, d0 = (it % 8) * 4;
        float4 a0 = make_float4(0,0,0,0), a1 = a0, a2 = a0, a3 = a0;
#pragma unroll
        for (int jq = 0; jq < 13; ++jq) {
            const int jj = jq * 4;
            const float4 s0 = *reinterpret_cast<const float4*>(&S[p0 + 0][jj]);
            const float4 s1 = *reinterpret_cast<const float4*>(&S[p0 + 1][jj]);
            const float4 s2 = *reinterpret_cast<const float4*>(&S[p0 + 2][jj]);
            const float4 s3 = *reinterpret_cast<const float4*>(&S[p0 + 3][jj]);
            const float4 v0 = *reinterpret_cast<const float4*>(&vs[d0 + 0][jj]);
            const float4 v1 = *reinterpret_cast<const float4*>(&vs[d0 + 1][jj]);
            const float4 v2 = *reinterpret_cast<const float4*>(&vs[d0 + 2][jj]);
            const float4 v3 = *reinterpret_cast<const float4*>(&vs[d0 + 3][jj]);
            DOT4(a0.x, s0, v0) DOT4(a0.y, s0, v1) DOT4(a0.z, s0, v2) DOT4(a0.w, s0, v3)
            DOT4(a1.x, s1, v0) DOT4(a1.y, s1, v1) DOT4(a1.z, s1, v2) DOT4(a1.w, s1, v3)
            DOT4(a2.x, s2, v0) DOT4(a2.y, s2, v1) DOT4(a2.z, s2, v2) DOT4(a2.w, s2, v3)
            DOT4(a3.x, s3, v0) DOT4(a3.y, s3, v1) DOT4(a3.z, s3, v2) DOT4(a3.w, s3, v3)
        }
        const float4 rows[4] = {a0, a1, a2, a3};
#pragma unroll
        for (int mp = 0; mp < 4; ++mp) {
            if (p0 + mp < 49) {
                qs[d0 + 0][p0 + mp] = rows[mp].x;
                qs[d0 + 1][p0 + mp] = rows[mp].y;
                qs[d0 + 2][p0 + mp] = rows[mp].z;
                qs[d0 + 3][p0 + mp] = rows[mp].w;
            }
        }
    }
    __syncthreads();

    // combined dw conv + 0.25*spa + bsum + v residual; store WINDOWED layout
    if (tid < 224) {
        const int d = tid / 7, h1 = tid % 7;
        float accw[7];
#pragma unroll
        for (int w1 = 0; w1 < 7; ++w1) {
            const int p = h1 * 7 + w1;
            accw[w1] = fmaf(0.25f, qs[d][p], bsum[d] + vs[d][p]);
        }
#pragma unroll
        for (int dy = 0; dy < 7; ++dy) {
            const int ry = h1 + dy - 3;
            const bool rok = (ry >= 0) && (ry < 7);
            const float* rowp = &xs[d][(rok ? ry : 0) * 7];
            float xr[7];
#pragma unroll
            for (int i = 0; i < 7; ++i) xr[i] = rok ? rowp[i] : 0.f;
#pragma unroll
            for (int dx = 0; dx < 7; ++dx) {
                const float wv = wc[d * 49 + dy * 7 + dx];
#pragma unroll
                for (int w1 = 0; w1 < 7; ++w1) {
                    const int rx = w1 + dx - 3;
                    if (rx >= 0 && rx < 7) accw[w1] = fmaf(wv, xr[rx], accw[w1]);
                }
            }
        }
        float* xap = xa + ((size_t)(b * NC + c0 + d)) * NHW + wb + h1 * 7;
#pragma unroll
        for (int w1 = 0; w1 < 7; ++w1) xap[w1] = accw[w1];
    }
}

// ---------------------------------------------------------------------------
// K5: per-(b,c)-plane: 3x3 depthwise conv (conv_local) + SiLU on T
// (windowed -> LDS-normal -> stencil -> U normal), and in-place
// windowed->normal permute of xa (shortcut for the final GEMM).
// ---------------------------------------------------------------------------
__launch_bounds__(256)
__global__ void dw3_silu(const float* __restrict__ T, const float* __restrict__ wloc,
                         const float* __restrict__ bloc, float* __restrict__ U,
                         float* xa)
{
    const int c = blockIdx.x, b = blockIdx.y;
    const size_t pb = ((size_t)b * NC + c) * NHW;
    __shared__ float pl[56 * 57];        // T, normal order, stride-57 rows
    __shared__ float xpl[3136];          // xa, normal order
    const int tid = threadIdx.x;
    const float4* t4 = reinterpret_cast<const float4*>(T + pb);
    const float4* x4 = reinterpret_cast<const float4*>(xa + pb);
    for (int i = tid; i < 784; i += 256) {
        const float4 tv = t4[i];
        const float4 xv = x4[i];
        const float tt[4] = {tv.x, tv.y, tv.z, tv.w};
        const float xx[4] = {xv.x, xv.y, xv.z, xv.w};
#pragma unroll
        for (int e = 0; e < 4; ++e) {
            const int n = 4 * i + e;
            const int j = n / 49, p = n - 49 * j;
            const int h1 = p / 7, w1 = p - 7 * h1;
            const int h = h1 * 8 + (j >> 3), w = w1 * 8 + (j & 7);
            pl[h * 57 + w] = tt[e];
            xpl[h * 56 + w] = xx[e];
        }
    }
    __syncthreads();

    float wk[9];
#pragma unroll
    for (int k = 0; k < 9; ++k) wk[k] = wloc[c * 9 + k];
    const float bs = bloc[c];
    for (int i = tid; i < NHW; i += 256) {
        const int h = i / 56, w = i - 56 * h;
        float acc = bs;
#pragma unroll
        for (int dy = -1; dy <= 1; ++dy) {
            const int hh = h + dy;
            if (hh < 0 || hh >= 56) continue;
#pragma unroll
            for (int dx = -1; dx <= 1; ++dx) {
                const int ww = w + dx;
                if (ww < 0 || ww >= 56) continue;
                acc = fmaf(wk[(dy + 1) * 3 + (dx + 1)], pl[hh * 57 + ww], acc);
            }
        }
        U[pb + i] = acc / (1.f + __expf(-acc));   // silu
    }

    float4* xo4 = reinterpret_cast<float4*>(xa + pb);
    for (int i = tid; i < 784; i += 256)
        xo4[i] = make_float4(xpl[4 * i], xpl[4 * i + 1], xpl[4 * i + 2], xpl[4 * i + 3]);
}

// ---------------------------------------------------------------------------
// Launch. Workspace layout (floats):
//   [0,512)              : BN affine a[256], b[256]
//   wcomb = W+512        : 256*49 combined dw weights
//   bsum  = W+13056      : 256
//   Wb    = W+13312      : 768*256 bf16 qkv weights (98304 floats)
//   xa    = W+111616     : NA floats — XNt bf16 alias before attn (dead after
//                          the MFMA GEMM), windowed after K3, NORMAL after K5
//   R     = xa+NA        : 2*NA floats shared region:
//       phase 1: Qb bf16 3*NA + XW bf16 NA (normal, windowed IN-PLACE by K2.5)
//       phase 2: T (windowed fp32 NA) + U (normal fp32 NA), aliasing phase 1
//   total = (111616 + 3*NA)*4 B ~ 308.7 MB
// ---------------------------------------------------------------------------
extern "C" void kernel_launch(void* const* d_in, const int* in_sizes, int n_in,
                              void* d_out, int out_size, void* d_ws, size_t ws_size,
                              hipStream_t stream)
{
    (void)in_sizes; (void)n_in; (void)out_size; (void)ws_size;
    const float* x    = (const float*)d_in[0];
    const float* g    = (const float*)d_in[1];
    const float* be   = (const float*)d_in[2];
    const float* qkvw = (const float*)d_in[3];
    const float* qkvb = (const float*)d_in[4];
    const float* w3   = (const float*)d_in[5];
    const float* b3   = (const float*)d_in[6];
    const float* w5   = (const float*)d_in[7];
    const float* b5   = (const float*)d_in[8];
    const float* w7   = (const float*)d_in[9];
    const float* b7   = (const float*)d_in[10];
    const float* fiw  = (const float*)d_in[11];
    const float* fib  = (const float*)d_in[12];
    const float* clw  = (const float*)d_in[13];
    const float* clb  = (const float*)d_in[14];
    const float* fow  = (const float*)d_in[15];
    const float* fob  = (const float*)d_in[16];
    float* out = (float*)d_out;

    float* W     = (float*)d_ws;
    float* ab    = W;
    float* wcomb = W + 512;
    float* bsum  = W + 13056;
    __hip_bfloat16* Wb = (__hip_bfloat16*)(W + 13312);      // 768*256 bf16
    float* xa    = W + 111616;
    unsigned short* XNt = (unsigned short*)xa;              // NA bf16, dead after MFMA GEMM
    float* R     = xa + NA;
    __hip_bfloat16* Qb = (__hip_bfloat16*)R;                // 3*NA bf16
    __hip_bfloat16* XW = Qb + 3 * NA;                       // NA bf16
    float* T = R;                                           // aliases Qb (dead after K3)
    float* U = R + NA;

    bn_stats<<<dim3(256), dim3(256), 0, stream>>>(x, g, be, w3, b3, w5, b5, w7, b7,
                                                  qkvw, ab, wcomb, bsum, Wb);
    xnt_make<<<dim3(49, NB), dim3(256), 0, stream>>>(x, ab, XNt, (unsigned short*)XW);
    gemm_qkv_mfma<<<dim3(784, 6), dim3(256), 0, stream>>>(
        XNt, (const unsigned short*)Wb, qkvb, (unsigned short*)Qb);
    repack_win<<<dim3(1024, NB), dim3(256), 0, stream>>>(Qb, XW);
    attn_win<<<dim3(64, 8, NB), dim3(256), 0, stream>>>(Qb, XW, wcomb, bsum, xa);
    gemm_k256<false, false, false><<<dim3(49, 4, NB), dim3(256), 0, stream>>>(
        xa, fiw, fib, nullptr, nullptr, T, nullptr, nullptr, 256);
    dw3_silu<<<dim3(256, NB), dim3(256), 0, stream>>>(T, clw, clb, U, xa);
    gemm_k256<false, false, true><<<dim3(49, 4, NB), dim3(256), 0, stream>>>(
        U, fow, fob, nullptr, xa, out, nullptr, nullptr, 256);
}

// Round 2
// 1605.848 us; speedup vs baseline: 1.1180x; 1.1180x over previous
//
#include <hip/hip_runtime.h>
#include <hip/hip_bf16.h>

// Problem constants
#define NB 32
#define NC 256
#define NHW 3136                 // 56*56
#define NA 25690112ull           // NB*NC*NHW elements (one NCHW tensor)
#define NPW 3328                 // padded windowed plane: 64 windows * 52
#define LTS 396                  // xnt_make2 LDS row stride (ushorts, mult of 4)

typedef __attribute__((ext_vector_type(8))) short bf16x8;
typedef __attribute__((ext_vector_type(4))) float f32x4;

// Window mapping: h=h1*8+j1, w=w1*8+j2; j=j1*8+j2 (0..63), p=h1*7+w1 (0..48).
// PADDED windowed linear index n' = j*52 + p (p in [0,52), p>=49 = pad).

// ---------------------------------------------------------------------------
// K1: BatchNorm stats -> per-channel affine (a,b): xn = a*x + b.
// Also precomputes combined depthwise weights wcomb = 0.25*(w3+w5+w7) (7x7),
// bias sum bsum, and bf16 copy of qkv weights (rows 3c..3c+2 per block).
// ---------------------------------------------------------------------------
__launch_bounds__(256)
__global__ void bn_stats(const float* __restrict__ x, const float* __restrict__ gamma,
                         const float* __restrict__ beta,
                         const float* __restrict__ w3, const float* __restrict__ b3,
                         const float* __restrict__ w5, const float* __restrict__ b5,
                         const float* __restrict__ w7, const float* __restrict__ b7,
                         const float* __restrict__ qkvw,
                         float* __restrict__ ab, float* __restrict__ wcomb,
                         float* __restrict__ bsum, __hip_bfloat16* __restrict__ Wb)
{
    const int c = blockIdx.x;
    const int tid = threadIdx.x;

    if (tid < 49) {
        const int ty = tid / 7, tx = tid % 7;
        float wv = w7[c * 49 + tid];
        if (ty >= 1 && ty <= 5 && tx >= 1 && tx <= 5) wv += w5[c * 25 + (ty - 1) * 5 + (tx - 1)];
        if (ty >= 2 && ty <= 4 && tx >= 2 && tx <= 4) wv += w3[c * 9 + (ty - 2) * 3 + (tx - 2)];
        wcomb[c * 49 + tid] = 0.25f * wv;
    }
    if (tid == 63) bsum[c] = 0.25f * (b3[c] + b5[c] + b7[c]);

    // bf16 conversion of qkv weights: block c handles output rows 3c..3c+2
#pragma unroll
    for (int r = 0; r < 3; ++r) {
        const int o = 3 * c + r;
        Wb[o * 256 + tid] = __float2bfloat16(qkvw[o * 256 + tid]);
    }

    float s = 0.f, s2 = 0.f;
    for (int b = 0; b < NB; ++b) {
        const float4* p = reinterpret_cast<const float4*>(x + ((size_t)b * NC + c) * NHW);
        for (int i = tid; i < NHW / 4; i += 256) {      // 3136/4 = 784
            const float4 v = p[i];
            s += v.x + v.y + v.z + v.w;
            s2 = fmaf(v.x, v.x, s2); s2 = fmaf(v.y, v.y, s2);
            s2 = fmaf(v.z, v.z, s2); s2 = fmaf(v.w, v.w, s2);
        }
    }
    __shared__ float r1[256], r2[256];
    r1[tid] = s; r2[tid] = s2;
    __syncthreads();
    for (int off = 128; off > 0; off >>= 1) {
        if (tid < off) { r1[tid] += r1[tid + off]; r2[tid] += r2[tid + off]; }
        __syncthreads();
    }
    if (tid == 0) {
        const float inv_n = 1.f / (float)((size_t)NB * NHW);
        const float mean = r1[0] * inv_n;
        const float var = r2[0] * inv_n - mean * mean;
        const float a = gamma[c] / sqrtf(var + 1e-5f);
        ab[c] = a;
        ab[NC + c] = beta[c] - mean * a;
    }
}

// ---------------------------------------------------------------------------
// K1.5 v2: xn = a*x+b applied once; emits PADDED-WINDOWED outputs:
//   XNt bf16 [(b*3328 + n')][c]  (k-contiguous rows for the MFMA GEMM; the
//       GEMM is n-order agnostic, so its output lands directly windowed)
//   XWW bf16 [b][c][n']          (padded windowed planes, pads ZEROED)
// Block = (b, j1, c-chunk of 64): stages the 7 h-rows {h1*8+j1} x 56 w x 64 c
// in LDS (bf16 after affine), then writes both outputs with >=104B runs.
// Pad rows of XNt (p in 49..51) are left unwritten (garbage) — their GEMM
// outputs land in Qb pad slots which attention masks (NaN-safe, verified).
// ---------------------------------------------------------------------------
__launch_bounds__(256)
__global__ void xnt_make2(const float* __restrict__ x, const float* __restrict__ ab,
                          unsigned short* __restrict__ XNt, unsigned short* __restrict__ XWW)
{
    const int c0 = blockIdx.x * 64;      // channel chunk
    const int j1 = blockIdx.y;           // window row id
    const int b  = blockIdx.z;
    __shared__ unsigned short lt[64 * LTS];   // [c][px], px = h1*56 + w
    __shared__ float aa[64], bb[64];
    const int tid = threadIdx.x;
    if (tid < 64) { aa[tid] = ab[c0 + tid]; bb[tid] = ab[256 + c0 + tid]; }
    __syncthreads();

    // Phase A: load 64c x 7rows x 56w fp32, affine, cvt bf16 -> LDS
    for (int idx = tid; idx < 6272; idx += 256) {       // 64 * 98 float4
        const int c = idx / 98, f = idx - 98 * c;
        const int h1 = f / 14, w4 = (f - 14 * h1) * 4;
        const float4 v = *reinterpret_cast<const float4*>(
            &x[((size_t)(b * NC) + c0 + c) * NHW + (h1 * 8 + j1) * 56 + w4]);
        const float a = aa[c], bv = bb[c];
        union { ushort4 u; __hip_bfloat16 h[4]; } pk;
        pk.h[0] = __float2bfloat16(fmaf(a, v.x, bv));
        pk.h[1] = __float2bfloat16(fmaf(a, v.y, bv));
        pk.h[2] = __float2bfloat16(fmaf(a, v.z, bv));
        pk.h[3] = __float2bfloat16(fmaf(a, v.w, bv));
        *reinterpret_cast<ushort4*>(&lt[c * LTS + h1 * 56 + w4]) = pk.u;
    }
    __syncthreads();

    // Phase B: XWW planes: per (c, j2) one padded window run of 52 (13 ushort4)
    for (int idx = tid; idx < 6656; idx += 256) {       // 64c * 8j2 * 13
        const int c = idx / 104, r = idx - 104 * c;
        const int j2 = r / 13, q4 = (r - 13 * j2) * 4;
        unsigned short tmp[4];
#pragma unroll
        for (int e = 0; e < 4; ++e) {
            const int p = q4 + e;
            if (p < 49) {
                const int h1p = p / 7, w1 = p - 7 * h1p;
                tmp[e] = lt[c * LTS + h1p * 56 + w1 * 8 + j2];
            } else {
                tmp[e] = 0;                              // zero pad (+0.0 bf16)
            }
        }
        ushort4 v; v.x = tmp[0]; v.y = tmp[1]; v.z = tmp[2]; v.w = tmp[3];
        *reinterpret_cast<ushort4*>(
            &XWW[((size_t)(b * NC) + c0 + c) * NPW + (j1 * 8 + j2) * 52 + q4]) = v;
    }

    // Phase C: XNt rows: per (p, j2, c4): 4 channels of one windowed row
    for (int idx = tid; idx < 6272; idx += 256) {       // 49p * 8j2 * 16c4
        const int p = idx >> 7;                          // 0..48
        const int r = idx & 127;
        const int j2 = r >> 4, c4 = (r & 15) * 4;
        const int h1p = p / 7, w1 = p - 7 * h1p;
        const int px = h1p * 56 + w1 * 8 + j2;
        ushort4 v;
        v.x = lt[(c4 + 0) * LTS + px];
        v.y = lt[(c4 + 1) * LTS + px];
        v.z = lt[(c4 + 2) * LTS + px];
        v.w = lt[(c4 + 3) * LTS + px];
        *reinterpret_cast<ushort4*>(
            &XNt[((size_t)b * NPW + (j1 * 8 + j2) * 52 + p) * 256 + c0 + c4]) = v;
    }
}

// ---------------------------------------------------------------------------
// K2: QKV 1x1-conv as bf16 MFMA GEMM. Out[o][nn'] = sum_c Wb[o][c]*XNt[nn'][c],
// nn' = b*3328 + n' merged (106496 rows = 832 exact 128-tiles, 3328%128==0 so
// no tile straddles a batch). Output lands directly in PADDED-WINDOWED Qb.
// Block tile 128o x 128n, 4 waves (2x2), wave = 64x64 = 16 mfma 16x16x32 bf16.
// ---------------------------------------------------------------------------
__launch_bounds__(256)
__global__ void gemm_qkv_mfma(const unsigned short* __restrict__ XNt,
                              const unsigned short* __restrict__ Wb,
                              const float* __restrict__ bias,
                              unsigned short* __restrict__ Qb)
{
    __shared__ unsigned short As[128 * 72];   // W tile   [o][k]
    __shared__ unsigned short Bs[128 * 72];   // XNt tile [n][k]
    const int t = threadIdx.x;
    const int nn0 = blockIdx.x * 128;
    const int o0 = blockIdx.y * 128;
    const int lane = t & 63;
    const int wid = t >> 6;
    const int lr = lane & 15, lg = lane >> 4;
    const int wo = (wid >> 1) * 64;
    const int wn = (wid & 1) * 64;

    f32x4 acc[4][4];
#pragma unroll
    for (int i = 0; i < 4; ++i)
#pragma unroll
        for (int j = 0; j < 4; ++j)
            acc[i][j] = (f32x4){0.f, 0.f, 0.f, 0.f};

    for (int kt = 0; kt < 4; ++kt) {
        const int k0 = kt * 64;
#pragma unroll
        for (int it = 0; it < 4; ++it) {
            const int idx = it * 256 + t;     // 0..1023
            const int row = idx >> 3;         // 0..127
            const int k8 = (idx & 7) * 8;     // 0..56
            *reinterpret_cast<uint4*>(&As[row * 72 + k8]) =
                *reinterpret_cast<const uint4*>(&Wb[(size_t)(o0 + row) * 256 + k0 + k8]);
            *reinterpret_cast<uint4*>(&Bs[row * 72 + k8]) =
                *reinterpret_cast<const uint4*>(&XNt[(size_t)(nn0 + row) * 256 + k0 + k8]);
        }
        __syncthreads();
#pragma unroll
        for (int ks = 0; ks < 2; ++ks) {
            const int kk = ks * 32 + lg * 8;
            bf16x8 af[4], bfr[4];
#pragma unroll
            for (int i = 0; i < 4; ++i) {
                af[i]  = *reinterpret_cast<const bf16x8*>(&As[(wo + i * 16 + lr) * 72 + kk]);
                bfr[i] = *reinterpret_cast<const bf16x8*>(&Bs[(wn + i * 16 + lr) * 72 + kk]);
            }
#pragma unroll
            for (int i = 0; i < 4; ++i)
#pragma unroll
                for (int j = 0; j < 4; ++j)
                    acc[i][j] = __builtin_amdgcn_mfma_f32_16x16x32_bf16(
                        af[i], bfr[j], acc[i][j], 0, 0, 0);
        }
        __syncthreads();
    }

    // Epilogue: per osub pass, 32 o-rows x 128 n-cols through LDS (aliases As).
    float* Ts = reinterpret_cast<float*>(As);  // 32 x 132 fp32 = 16.5 KB
#pragma unroll
    for (int osub = 0; osub < 4; ++osub) {
        const float4 b4 = *reinterpret_cast<const float4*>(&bias[o0 + wo + osub * 16 + 4 * lg]);
        const int rowb = (wid >> 1) * 16 + 4 * lg;
#pragma unroll
        for (int j = 0; j < 4; ++j) {
            const int col = wn + j * 16 + lr;
            Ts[(rowb + 0) * 132 + col] = acc[osub][j][0] + b4.x;
            Ts[(rowb + 1) * 132 + col] = acc[osub][j][1] + b4.y;
            Ts[(rowb + 2) * 132 + col] = acc[osub][j][2] + b4.z;
            Ts[(rowb + 3) * 132 + col] = acc[osub][j][3] + b4.w;
        }
        __syncthreads();
#pragma unroll
        for (int p = 0; p < 4; ++p) {
            const int idx = p * 256 + t;      // 0..1023
            const int row = idx >> 5;         // 0..31
            const int c4 = (idx & 31) * 4;    // 0..124
            const float4 v = *reinterpret_cast<const float4*>(&Ts[row * 132 + c4]);
            const int o = o0 + (row >> 4) * 64 + osub * 16 + (row & 15);
            const int nn = nn0 + c4;
            const int bb2 = nn / NPW;
            const int n = nn - bb2 * NPW;     // padded-windowed n'
            union { ushort4 u; __hip_bfloat16 h[4]; } pk;
            pk.h[0] = __float2bfloat16(v.x);
            pk.h[1] = __float2bfloat16(v.y);
            pk.h[2] = __float2bfloat16(v.z);
            pk.h[3] = __float2bfloat16(v.w);
            *reinterpret_cast<ushort4*>(&Qb[((size_t)bb2 * 768 + o) * NPW + n]) = pk.u;
        }
        __syncthreads();
    }
}

// ---------------------------------------------------------------------------
// K4/K6 (fp32 FFN GEMMs): 1x1-conv GEMM, K=256. 64x64 tile per block, 4x4
// register tile per thread. n-order agnostic (xa stays UNPADDED windowed).
// RES: add shortcut (same n-order as output) contiguous float4 in epilogue.
// ---------------------------------------------------------------------------
template<bool RES>
__launch_bounds__(256)
__global__ void gemm_k256(const float* __restrict__ X, const float* __restrict__ Wt,
                          const float* __restrict__ bias,
                          const float* __restrict__ res, float* __restrict__ outF)
{
    __shared__ float Xs[64][64];
    __shared__ float Ws[64][64];
    const int b = blockIdx.z;
    const int n0 = blockIdx.x * 64;   // 49 tiles * 64 = 3136 exact
    const int o0 = blockIdx.y * 64;
    const float* Xb = X + (size_t)b * NC * NHW;
    const int t = threadIdx.x;
    const int f4 = (t & 15) * 4;      // staging column (x4)
    const int r16 = t >> 4;           // staging row group
    const int tn = (t & 15) * 4;      // compute: n offset
    const int to = (t >> 4) * 4;      // compute: o offset

    float4 acc[4];
#pragma unroll
    for (int i = 0; i < 4; ++i) acc[i] = make_float4(0.f, 0.f, 0.f, 0.f);

    for (int kc = 0; kc < 4; ++kc) {
#pragma unroll
        for (int ps = 0; ps < 4; ++ps) {
            const int rr = r16 + ps * 16;        // 0..63
            const int c = kc * 64 + rr;          // k index
            float4 xv = *reinterpret_cast<const float4*>(Xb + (size_t)c * NHW + n0 + f4);
            *reinterpret_cast<float4*>(&Xs[rr][f4]) = xv;
            float4 wv = *reinterpret_cast<const float4*>(Wt + (size_t)(o0 + rr) * NC + kc * 64 + f4);
            *reinterpret_cast<float4*>(&Ws[rr][f4]) = wv;
        }
        __syncthreads();
#pragma unroll
        for (int k4 = 0; k4 < 16; ++k4) {
            float4 xr[4], wr[4];
#pragma unroll
            for (int jj = 0; jj < 4; ++jj)
                xr[jj] = *reinterpret_cast<const float4*>(&Xs[k4 * 4 + jj][tn]);
#pragma unroll
            for (int i = 0; i < 4; ++i)
                wr[i] = *reinterpret_cast<const float4*>(&Ws[to + i][k4 * 4]);
#pragma unroll
            for (int i = 0; i < 4; ++i) {
                acc[i].x = fmaf(wr[i].x, xr[0].x, acc[i].x);
                acc[i].y = fmaf(wr[i].x, xr[0].y, acc[i].y);
                acc[i].z = fmaf(wr[i].x, xr[0].z, acc[i].z);
                acc[i].w = fmaf(wr[i].x, xr[0].w, acc[i].w);
                acc[i].x = fmaf(wr[i].y, xr[1].x, acc[i].x);
                acc[i].y = fmaf(wr[i].y, xr[1].y, acc[i].y);
                acc[i].z = fmaf(wr[i].y, xr[1].z, acc[i].z);
                acc[i].w = fmaf(wr[i].y, xr[1].w, acc[i].w);
                acc[i].x = fmaf(wr[i].z, xr[2].x, acc[i].x);
                acc[i].y = fmaf(wr[i].z, xr[2].y, acc[i].y);
                acc[i].z = fmaf(wr[i].z, xr[2].z, acc[i].z);
                acc[i].w = fmaf(wr[i].z, xr[2].w, acc[i].w);
                acc[i].x = fmaf(wr[i].w, xr[3].x, acc[i].x);
                acc[i].y = fmaf(wr[i].w, xr[3].y, acc[i].y);
                acc[i].z = fmaf(wr[i].w, xr[3].z, acc[i].z);
                acc[i].w = fmaf(wr[i].w, xr[3].w, acc[i].w);
            }
        }
        __syncthreads();
    }
    // epilogue
#pragma unroll
    for (int io = 0; io < 4; ++io) {
        const int o = o0 + to + io;
        const float bs = bias[o];
        float vals[4] = {acc[io].x + bs, acc[io].y + bs, acc[io].z + bs, acc[io].w + bs};
        if (RES) {
            const float4 rv = *reinterpret_cast<const float4*>(
                res + ((size_t)(b * NC + o)) * NHW + n0 + tn);
            vals[0] += rv.x; vals[1] += rv.y; vals[2] += rv.z; vals[3] += rv.w;
        }
        float* op = outF + ((size_t)b * NC + o) * NHW + n0 + tn;
        *reinterpret_cast<float4*>(op) = make_float4(vals[0], vals[1], vals[2], vals[3]);
    }
}

// ---------------------------------------------------------------------------
// K3: per-(window, head) attention + combined 7x7 depthwise conv + residuals.
// Reads q/k/v/xn from PADDED-WINDOWED bf16 planes (104B aligned runs, ushort4
// vector loads). Writes xa in UNPADDED WINDOWED fp32 layout (as before).
// wcomb staged into the dead S region post-PV (saves 6.3KB LDS).
// NOTE: plain __launch_bounds__(256) — the (256,3) variant capped VGPRs at 84
// and spilled per-thread arrays to scratch (R2/R3 post-mortem). Do not re-add.
// ---------------------------------------------------------------------------
#define DOT4(accv, sv, vv2) \
    accv = fmaf(sv.x, vv2.x, accv); accv = fmaf(sv.y, vv2.y, accv); \
    accv = fmaf(sv.z, vv2.z, accv); accv = fmaf(sv.w, vv2.w, accv);

#define QK4(areg, qc) \
    areg.x = fmaf(qc, kv.x, areg.x); areg.y = fmaf(qc, kv.y, areg.y); \
    areg.z = fmaf(qc, kv.z, areg.z); areg.w = fmaf(qc, kv.w, areg.w);

__launch_bounds__(256)
__global__ void attn_win(const __hip_bfloat16* __restrict__ Q,
                         const __hip_bfloat16* __restrict__ XW,
                         const float* __restrict__ wcomb, const float* __restrict__ bsumg,
                         float* __restrict__ xa)
{
    const int j = blockIdx.x;            // window id 0..63
    const int nh = blockIdx.y;           // head
    const int b = blockIdx.z;
    const int c0 = nh * 32;
    __shared__ float qs[32][52];         // q, later reused as x_spa
    __shared__ float ks[32][52];
    __shared__ float vs[32][52];         // v + xn residual (pads zeroed)
    __shared__ float xs[32][52];         // xn window (dw conv input, pads 0)
    __shared__ float S[52][52];          // scores / probs; later wcomb
    __shared__ float bsum[32];
    const int tid = threadIdx.x;
    if (tid < 32) bsum[tid] = bsumg[c0 + tid];

    // vectorized staging: 416 iters x 4 ushort4 loads (8B, aligned)
    const size_t qbase = ((size_t)b * 768 + c0) * NPW + j * 52;
    const size_t xbase = ((size_t)(b * NC) + c0) * NPW + j * 52;
    for (int idx = tid; idx < 416; idx += 256) {
        const int d = idx / 13, q4 = (idx - 13 * d) * 4;
        const size_t off = (size_t)d * NPW + q4;
        union { ushort4 u; __hip_bfloat16 h[4]; } uq, uk, uv, ux;
        uq.u = *reinterpret_cast<const ushort4*>(&Q[qbase + off]);
        uk.u = *reinterpret_cast<const ushort4*>(&Q[qbase + (size_t)256 * NPW + off]);
        uv.u = *reinterpret_cast<const ushort4*>(&Q[qbase + (size_t)512 * NPW + off]);
        ux.u = *reinterpret_cast<const ushort4*>(&XW[xbase + off]);
        float4 qf, kf, xf, vf;
        qf.x = __bfloat162float(uq.h[0]); qf.y = __bfloat162float(uq.h[1]);
        qf.z = __bfloat162float(uq.h[2]); qf.w = __bfloat162float(uq.h[3]);
        kf.x = __bfloat162float(uk.h[0]); kf.y = __bfloat162float(uk.h[1]);
        kf.z = __bfloat162float(uk.h[2]); kf.w = __bfloat162float(uk.h[3]);
        xf.x = __bfloat162float(ux.h[0]); xf.y = __bfloat162float(ux.h[1]);
        xf.z = __bfloat162float(ux.h[2]); xf.w = __bfloat162float(ux.h[3]);
        vf.x = __bfloat162float(uv.h[0]) + xf.x;
        vf.y = __bfloat162float(uv.h[1]) + xf.y;
        vf.z = __bfloat162float(uv.h[2]) + xf.z;
        vf.w = __bfloat162float(uv.h[3]) + xf.w;
        if (q4 == 48) { vf.y = 0.f; vf.z = 0.f; vf.w = 0.f; }   // zero v pads
        *reinterpret_cast<float4*>(&qs[d][q4]) = qf;
        *reinterpret_cast<float4*>(&ks[d][q4]) = kf;
        *reinterpret_cast<float4*>(&xs[d][q4]) = xf;
        *reinterpret_cast<float4*>(&vs[d][q4]) = vf;
    }
    __syncthreads();

    // S = (q^T k) * 1/sqrt(32), 4x4 tiles
    const float sc = 0.17677669529663687f;
    for (int it = tid; it < 169; it += 256) {
        const int i0 = (it / 13) * 4, j0 = (it % 13) * 4;
        float4 a0 = make_float4(0,0,0,0), a1 = a0, a2 = a0, a3 = a0;
#pragma unroll
        for (int d = 0; d < 32; ++d) {
            const float4 qv = *reinterpret_cast<const float4*>(&qs[d][i0]);
            const float4 kv = *reinterpret_cast<const float4*>(&ks[d][j0]);
            QK4(a0, qv.x) QK4(a1, qv.y) QK4(a2, qv.z) QK4(a3, qv.w)
        }
        const float4 rows[4] = {a0, a1, a2, a3};
#pragma unroll
        for (int m = 0; m < 4; ++m) {
            if (i0 + m < 49) {
                float4 sv;
                sv.x = rows[m].x * sc;
                sv.y = (j0 + 1 < 49) ? rows[m].y * sc : 0.f;
                sv.z = (j0 + 2 < 49) ? rows[m].z * sc : 0.f;
                sv.w = (j0 + 3 < 49) ? rows[m].w * sc : 0.f;
                *reinterpret_cast<float4*>(&S[i0 + m][j0]) = sv;
            }
        }
    }
    __syncthreads();

    // softmax over keys: 4 lanes per query row, shfl_xor row-combine
    if (tid < 196) {
        const int r = tid >> 2, qr = tid & 3;
        const int i0q = qr * 13;
        const int i1q = (qr == 3) ? 49 : i0q + 13;
        float m = -1e30f;
        for (int i = i0q; i < i1q; ++i) m = fmaxf(m, S[r][i]);
        m = fmaxf(m, __shfl_xor(m, 1));
        m = fmaxf(m, __shfl_xor(m, 2));
        float sum = 0.f;
        for (int i = i0q; i < i1q; ++i) {
            const float e = __expf(S[r][i] - m);
            S[r][i] = e; sum += e;
        }
        sum += __shfl_xor(sum, 1);
        sum += __shfl_xor(sum, 2);
        const float inv = 1.f / sum;
        for (int i = i0q; i < i1q; ++i) S[r][i] *= inv;
    }
    __syncthreads();

    // O = P @ V, 4p x 4d tiles; write into qs as spa[d][p]
    for (int it = tid; it < 104; it += 256) {
        const int p0 = (it / 8) * 4, d0 = (it % 8) * 4;
        float4 a0 = make_float4(0,0,0,0), a1 = a0, a2 = a0, a3 = a0;
#pragma unroll
        for (int jq = 0; jq < 13; ++jq) {
            const int jj = jq * 4;
            const float4 s0 = *reinterpret_cast<const float4*>(&S[p0 + 0][jj]);
            const float4 s1 = *reinterpret_cast<const float4*>(&S[p0 + 1][jj]);
            const float4 s2 = *reinterpret_cast<const float4*>(&S[p0 + 2][jj]);
            const float4 s3 = *reinterpret_cast<const float4*>(&S[p0 + 3][jj]);
            const float4 v0 = *reinterpret_cast<const float4*>(&vs[d0 + 0][jj]);
            const float4 v1 = *reinterpret_cast<const float4*>(&vs[d0 + 1][jj]);
            const float4 v2 = *reinterpret_cast<const float4*>(&vs[d0 + 2][jj]);
            const float4 v3 = *reinterpret_cast<const float4*>(&vs[d0 + 3][jj]);
            DOT4(a0.x, s0, v0) DOT4(a0.y, s0, v1) DOT4(a0.z, s0, v2) DOT4(a0.w, s0, v3)
            DOT4(a1.x, s1, v0) DOT4(a1.y, s1, v1) DOT4(a1.z, s1, v2) DOT4(a1.w, s1, v3)
            DOT4(a2.x, s2, v0) DOT4(a2.y, s2, v1) DOT4(a2.z, s2, v2) DOT4(a2.w, s2, v3)
            DOT4(a3.x, s3, v0) DOT4(a3.y, s3, v1) DOT4(a3.z, s3, v2) DOT4(a3.w, s3, v3)
        }
        const float4 rows[4] = {a0, a1, a2, a3};
#pragma unroll
        for (int mp = 0; mp < 4; ++mp) {
            if (p0 + mp < 49) {
                qs[d0 + 0][p0 + mp] = rows[mp].x;
                qs[d0 + 1][p0 + mp] = rows[mp].y;
                qs[d0 + 2][p0 + mp] = rows[mp].z;
                qs[d0 + 3][p0 + mp] = rows[mp].w;
            }
        }
    }
    __syncthreads();

    // stage wcomb into the now-dead S region
    float* wcS = &S[0][0];
    for (int idx = tid; idx < 392; idx += 256)
        *reinterpret_cast<float4*>(&wcS[idx * 4]) =
            *reinterpret_cast<const float4*>(&wcomb[c0 * 49 + idx * 4]);
    __syncthreads();

    // combined dw conv + 0.25*spa + bsum + v residual; store WINDOWED layout
    if (tid < 224) {
        const int d = tid / 7, h1 = tid % 7;
        float accw[7];
#pragma unroll
        for (int w1 = 0; w1 < 7; ++w1) {
            const int p = h1 * 7 + w1;
            accw[w1] = fmaf(0.25f, qs[d][p], bsum[d] + vs[d][p]);
        }
#pragma unroll
        for (int dy = 0; dy < 7; ++dy) {
            const int ry = h1 + dy - 3;
            const bool rok = (ry >= 0) && (ry < 7);
            const float* rowp = &xs[d][(rok ? ry : 0) * 7];
            float xr[7];
#pragma unroll
            for (int i = 0; i < 7; ++i) xr[i] = rok ? rowp[i] : 0.f;
#pragma unroll
            for (int dx = 0; dx < 7; ++dx) {
                const float wv = wcS[d * 49 + dy * 7 + dx];
#pragma unroll
                for (int w1 = 0; w1 < 7; ++w1) {
                    const int rx = w1 + dx - 3;
                    if (rx >= 0 && rx < 7) accw[w1] = fmaf(wv, xr[rx], accw[w1]);
                }
            }
        }
        float* xap = xa + ((size_t)(b * NC + c0 + d)) * NHW + j * 49 + h1 * 7;
#pragma unroll
        for (int w1 = 0; w1 < 7; ++w1) xap[w1] = accw[w1];
    }
}

// ---------------------------------------------------------------------------
// K5: per-(b,c)-plane: 3x3 depthwise conv (conv_local) + SiLU on T
// (windowed -> LDS-normal -> stencil -> U normal), and in-place
// windowed->normal permute of xa (shortcut for the final GEMM).
// ---------------------------------------------------------------------------
__launch_bounds__(256)
__global__ void dw3_silu(const float* __restrict__ T, const float* __restrict__ wloc,
                         const float* __restrict__ bloc, float* __restrict__ U,
                         float* xa)
{
    const int c = blockIdx.x, b = blockIdx.y;
    const size_t pb = ((size_t)b * NC + c) * NHW;
    __shared__ float pl[56 * 57];        // T, normal order, stride-57 rows
    __shared__ float xpl[3136];          // xa, normal order
    const int tid = threadIdx.x;
    const float4* t4 = reinterpret_cast<const float4*>(T + pb);
    const float4* x4 = reinterpret_cast<const float4*>(xa + pb);
    for (int i = tid; i < 784; i += 256) {
        const float4 tv = t4[i];
        const float4 xv = x4[i];
        const float tt[4] = {tv.x, tv.y, tv.z, tv.w};
        const float xx[4] = {xv.x, xv.y, xv.z, xv.w};
#pragma unroll
        for (int e = 0; e < 4; ++e) {
            const int n = 4 * i + e;
            const int j = n / 49, p = n - 49 * j;
            const int h1 = p / 7, w1 = p - 7 * h1;
            const int h = h1 * 8 + (j >> 3), w = w1 * 8 + (j & 7);
            pl[h * 57 + w] = tt[e];
            xpl[h * 56 + w] = xx[e];
        }
    }
    __syncthreads();

    float wk[9];
#pragma unroll
    for (int k = 0; k < 9; ++k) wk[k] = wloc[c * 9 + k];
    const float bs = bloc[c];
    for (int i = tid; i < NHW; i += 256) {
        const int h = i / 56, w = i - 56 * h;
        float acc = bs;
#pragma unroll
        for (int dy = -1; dy <= 1; ++dy) {
            const int hh = h + dy;
            if (hh < 0 || hh >= 56) continue;
#pragma unroll
            for (int dx = -1; dx <= 1; ++dx) {
                const int ww = w + dx;
                if (ww < 0 || ww >= 56) continue;
                acc = fmaf(wk[(dy + 1) * 3 + (dx + 1)], pl[hh * 57 + ww], acc);
            }
        }
        U[pb + i] = acc / (1.f + __expf(-acc));   // silu
    }

    float4* xo4 = reinterpret_cast<float4*>(xa + pb);
    for (int i = tid; i < 784; i += 256)
        xo4[i] = make_float4(xpl[4 * i], xpl[4 * i + 1], xpl[4 * i + 2], xpl[4 * i + 3]);
}

// ---------------------------------------------------------------------------
// Launch. Workspace layout (floats):
//   [0,512)              : BN affine a[256], b[256]
//   wcomb = W+512        : 256*49 combined dw weights
//   bsum  = W+13056      : 256
//   Wb    = W+13312      : 768*256 bf16 qkv weights (98304 floats)
//   xa    = W+111616     : NA floats — XNt bf16 alias (padded-windowed rows,
//                          32*3328*256 ush = 13.63M floats, dead after GEMM),
//                          then attn output (windowed), NORMAL after K5
//   R     = xa+NA        : 54.53M floats shared region:
//       phase 1: QbW bf16 768*32*3328 (40.9M fl) + XWW bf16 256*32*3328 (13.6M)
//       phase 2: T (windowed fp32 NA) + U (normal fp32 NA), aliasing phase 1
//   total = (111616 + NA + 54,525,952)*4 B ~ 321.3 MB
// ---------------------------------------------------------------------------
extern "C" void kernel_launch(void* const* d_in, const int* in_sizes, int n_in,
                              void* d_out, int out_size, void* d_ws, size_t ws_size,
                              hipStream_t stream)
{
    (void)in_sizes; (void)n_in; (void)out_size; (void)ws_size;
    const float* x    = (const float*)d_in[0];
    const float* g    = (const float*)d_in[1];
    const float* be   = (const float*)d_in[2];
    const float* qkvw = (const float*)d_in[3];
    const float* qkvb = (const float*)d_in[4];
    const float* w3   = (const float*)d_in[5];
    const float* b3   = (const float*)d_in[6];
    const float* w5   = (const float*)d_in[7];
    const float* b5   = (const float*)d_in[8];
    const float* w7   = (const float*)d_in[9];
    const float* b7   = (const float*)d_in[10];
    const float* fiw  = (const float*)d_in[11];
    const float* fib  = (const float*)d_in[12];
    const float* clw  = (const float*)d_in[13];
    const float* clb  = (const float*)d_in[14];
    const float* fow  = (const float*)d_in[15];
    const float* fob  = (const float*)d_in[16];
    float* out = (float*)d_out;

    float* W     = (float*)d_ws;
    float* ab    = W;
    float* wcomb = W + 512;
    float* bsum  = W + 13056;
    __hip_bfloat16* Wb = (__hip_bfloat16*)(W + 13312);      // 768*256 bf16
    float* xa    = W + 111616;
    unsigned short* XNt = (unsigned short*)xa;              // padded rows, dead after GEMM
    float* R     = xa + NA;
    unsigned short* QbW = (unsigned short*)R;               // 768*NB planes of NPW
    unsigned short* XWW = QbW + (size_t)768 * NB * NPW;     // 256*NB planes of NPW
    float* T = R;                                           // aliases QbW (dead after K3)
    float* U = R + NA;

    bn_stats<<<dim3(256), dim3(256), 0, stream>>>(x, g, be, w3, b3, w5, b5, w7, b7,
                                                  qkvw, ab, wcomb, bsum, Wb);
    xnt_make2<<<dim3(4, 8, NB), dim3(256), 0, stream>>>(x, ab, XNt, XWW);
    gemm_qkv_mfma<<<dim3(832, 6), dim3(256), 0, stream>>>(
        XNt, (const unsigned short*)Wb, qkvb, QbW);
    attn_win<<<dim3(64, 8, NB), dim3(256), 0, stream>>>(
        (const __hip_bfloat16*)QbW, (const __hip_bfloat16*)XWW, wcomb, bsum, xa);
    gemm_k256<false><<<dim3(49, 4, NB), dim3(256), 0, stream>>>(xa, fiw, fib, nullptr, T);
    dw3_silu<<<dim3(256, NB), dim3(256), 0, stream>>>(T, clw, clb, U, xa);
    gemm_k256<true><<<dim3(49, 4, NB), dim3(256), 0, stream>>>(U, fow, fob, xa, out);
}

// Round 3
// 1060.980 us; speedup vs baseline: 1.6922x; 1.5136x over previous
//
#include <hip/hip_runtime.h>
#include <hip/hip_bf16.h>

// Problem constants
#define NB 32
#define NC 256
#define NHW 3136                 // 56*56
#define NA 25690112ull           // NB*NC*NHW elements (one NCHW tensor)
#define NPW 3328                 // padded windowed plane: 64 windows * 52
#define LTS 396                  // xnt_make2 LDS row stride (ushorts, mult of 4)

typedef __attribute__((ext_vector_type(8))) short bf16x8;
typedef __attribute__((ext_vector_type(4))) float f32x4;

// Window mapping: h=h1*8+j1, w=w1*8+j2; j=j1*8+j2 (0..63), p=h1*7+w1 (0..48).
// PADDED windowed linear index n' = j*52 + p (p in [0,52), p>=49 = pad).

static __device__ __forceinline__ unsigned short f2bu(float f) {
    union { __hip_bfloat16 h; unsigned short u; } c;
    c.h = __float2bfloat16(f);
    return c.u;
}
static __device__ __forceinline__ float bu2f(unsigned short us) {
    union { unsigned short u; __hip_bfloat16 h; } c;
    c.u = us;
    return __bfloat162float(c.h);
}

// ---------------------------------------------------------------------------
// K1: BatchNorm stats -> per-channel affine (a,b): xn = a*x + b.
// Also precomputes combined depthwise weights wcomb = 0.25*(w3+w5+w7) (7x7),
// bias sum bsum, and bf16 copy of qkv weights (rows 3c..3c+2 per block).
// ---------------------------------------------------------------------------
__launch_bounds__(256)
__global__ void bn_stats(const float* __restrict__ x, const float* __restrict__ gamma,
                         const float* __restrict__ beta,
                         const float* __restrict__ w3, const float* __restrict__ b3,
                         const float* __restrict__ w5, const float* __restrict__ b5,
                         const float* __restrict__ w7, const float* __restrict__ b7,
                         const float* __restrict__ qkvw,
                         float* __restrict__ ab, float* __restrict__ wcomb,
                         float* __restrict__ bsum, __hip_bfloat16* __restrict__ Wb)
{
    const int c = blockIdx.x;
    const int tid = threadIdx.x;

    if (tid < 49) {
        const int ty = tid / 7, tx = tid % 7;
        float wv = w7[c * 49 + tid];
        if (ty >= 1 && ty <= 5 && tx >= 1 && tx <= 5) wv += w5[c * 25 + (ty - 1) * 5 + (tx - 1)];
        if (ty >= 2 && ty <= 4 && tx >= 2 && tx <= 4) wv += w3[c * 9 + (ty - 2) * 3 + (tx - 2)];
        wcomb[c * 49 + tid] = 0.25f * wv;
    }
    if (tid == 63) bsum[c] = 0.25f * (b3[c] + b5[c] + b7[c]);

#pragma unroll
    for (int r = 0; r < 3; ++r) {
        const int o = 3 * c + r;
        Wb[o * 256 + tid] = __float2bfloat16(qkvw[o * 256 + tid]);
    }

    float s = 0.f, s2 = 0.f;
    for (int b = 0; b < NB; ++b) {
        const float4* p = reinterpret_cast<const float4*>(x + ((size_t)b * NC + c) * NHW);
        for (int i = tid; i < NHW / 4; i += 256) {      // 3136/4 = 784
            const float4 v = p[i];
            s += v.x + v.y + v.z + v.w;
            s2 = fmaf(v.x, v.x, s2); s2 = fmaf(v.y, v.y, s2);
            s2 = fmaf(v.z, v.z, s2); s2 = fmaf(v.w, v.w, s2);
        }
    }
    __shared__ float r1[256], r2[256];
    r1[tid] = s; r2[tid] = s2;
    __syncthreads();
    for (int off = 128; off > 0; off >>= 1) {
        if (tid < off) { r1[tid] += r1[tid + off]; r2[tid] += r2[tid + off]; }
        __syncthreads();
    }
    if (tid == 0) {
        const float inv_n = 1.f / (float)((size_t)NB * NHW);
        const float mean = r1[0] * inv_n;
        const float var = r2[0] * inv_n - mean * mean;
        const float a = gamma[c] / sqrtf(var + 1e-5f);
        ab[c] = a;
        ab[NC + c] = beta[c] - mean * a;
    }
}

// ---------------------------------------------------------------------------
// K1.5: xn = a*x+b applied once; emits PADDED-WINDOWED outputs:
//   XNt bf16 [(b*3328 + n')][c]  (k-contiguous rows for the MFMA GEMM)
//   XWW bf16 [b][c][n']          (padded windowed planes, pads ZEROED)
// Pad rows of XNt (p in 49..51) are left unwritten (garbage) — their GEMM
// outputs land in pad slots which attention never reads (QKt) or masks (Vb).
// ---------------------------------------------------------------------------
__launch_bounds__(256)
__global__ void xnt_make2(const float* __restrict__ x, const float* __restrict__ ab,
                          unsigned short* __restrict__ XNt, unsigned short* __restrict__ XWW)
{
    const int c0 = blockIdx.x * 64;      // channel chunk
    const int j1 = blockIdx.y;           // window row id
    const int b  = blockIdx.z;
    __shared__ unsigned short lt[64 * LTS];   // [c][px], px = h1*56 + w
    __shared__ float aa[64], bb[64];
    const int tid = threadIdx.x;
    if (tid < 64) { aa[tid] = ab[c0 + tid]; bb[tid] = ab[256 + c0 + tid]; }
    __syncthreads();

    // Phase A: load 64c x 7rows x 56w fp32, affine, cvt bf16 -> LDS
    for (int idx = tid; idx < 6272; idx += 256) {       // 64 * 98 float4
        const int c = idx / 98, f = idx - 98 * c;
        const int h1 = f / 14, w4 = (f - 14 * h1) * 4;
        const float4 v = *reinterpret_cast<const float4*>(
            &x[((size_t)(b * NC) + c0 + c) * NHW + (h1 * 8 + j1) * 56 + w4]);
        const float a = aa[c], bv = bb[c];
        union { ushort4 u; __hip_bfloat16 h[4]; } pk;
        pk.h[0] = __float2bfloat16(fmaf(a, v.x, bv));
        pk.h[1] = __float2bfloat16(fmaf(a, v.y, bv));
        pk.h[2] = __float2bfloat16(fmaf(a, v.z, bv));
        pk.h[3] = __float2bfloat16(fmaf(a, v.w, bv));
        *reinterpret_cast<ushort4*>(&lt[c * LTS + h1 * 56 + w4]) = pk.u;
    }
    __syncthreads();

    // Phase B: XWW planes: per (c, j2) one padded window run of 52 (13 ushort4)
    for (int idx = tid; idx < 6656; idx += 256) {       // 64c * 8j2 * 13
        const int c = idx / 104, r = idx - 104 * c;
        const int j2 = r / 13, q4 = (r - 13 * j2) * 4;
        unsigned short tmp[4];
#pragma unroll
        for (int e = 0; e < 4; ++e) {
            const int p = q4 + e;
            if (p < 49) {
                const int h1p = p / 7, w1 = p - 7 * h1p;
                tmp[e] = lt[c * LTS + h1p * 56 + w1 * 8 + j2];
            } else {
                tmp[e] = 0;                              // zero pad (+0.0 bf16)
            }
        }
        ushort4 v; v.x = tmp[0]; v.y = tmp[1]; v.z = tmp[2]; v.w = tmp[3];
        *reinterpret_cast<ushort4*>(
            &XWW[((size_t)(b * NC) + c0 + c) * NPW + (j1 * 8 + j2) * 52 + q4]) = v;
    }

    // Phase C: XNt rows: per (p, j2, c4): 4 channels of one windowed row
    for (int idx = tid; idx < 6272; idx += 256) {       // 49p * 8j2 * 16c4
        const int p = idx >> 7;                          // 0..48
        const int r = idx & 127;
        const int j2 = r >> 4, c4 = (r & 15) * 4;
        const int h1p = p / 7, w1 = p - 7 * h1p;
        const int px = h1p * 56 + w1 * 8 + j2;
        ushort4 v;
        v.x = lt[(c4 + 0) * LTS + px];
        v.y = lt[(c4 + 1) * LTS + px];
        v.z = lt[(c4 + 2) * LTS + px];
        v.w = lt[(c4 + 3) * LTS + px];
        *reinterpret_cast<ushort4*>(
            &XNt[((size_t)b * NPW + (j1 * 8 + j2) * 52 + p) * 256 + c0 + c4]) = v;
    }
}

// ---------------------------------------------------------------------------
// K2: QKV 1x1-conv as bf16 MFMA GEMM. Out[o][nn'] = sum_c Wb[o][c]*XNt[nn'][c].
// Epilogue splits by output range:
//   o in [0,512)  (Q and K): write QKt[b][n'][512] k-major — attention's
//                  A/B fragments then stage with plain 16B copies.
//   o in [512,768) (V):      write plane-major Vb[c][n'] (that IS PV's B^T).
// ---------------------------------------------------------------------------
__launch_bounds__(256)
__global__ void gemm_qkv_mfma(const unsigned short* __restrict__ XNt,
                              const unsigned short* __restrict__ Wb,
                              const float* __restrict__ bias,
                              unsigned short* __restrict__ QKt,
                              unsigned short* __restrict__ Vb)
{
    __shared__ unsigned short As[128 * 72];   // W tile   [o][k]
    __shared__ unsigned short Bs[128 * 72];   // XNt tile [n][k]
    const int t = threadIdx.x;
    const int nn0 = blockIdx.x * 128;
    const int o0 = blockIdx.y * 128;
    const int lane = t & 63;
    const int wid = t >> 6;
    const int lr = lane & 15, lg = lane >> 4;
    const int wo = (wid >> 1) * 64;
    const int wn = (wid & 1) * 64;

    f32x4 acc[4][4];
#pragma unroll
    for (int i = 0; i < 4; ++i)
#pragma unroll
        for (int j = 0; j < 4; ++j)
            acc[i][j] = (f32x4){0.f, 0.f, 0.f, 0.f};

    for (int kt = 0; kt < 4; ++kt) {
        const int k0 = kt * 64;
#pragma unroll
        for (int it = 0; it < 4; ++it) {
            const int idx = it * 256 + t;     // 0..1023
            const int row = idx >> 3;         // 0..127
            const int k8 = (idx & 7) * 8;     // 0..56
            *reinterpret_cast<uint4*>(&As[row * 72 + k8]) =
                *reinterpret_cast<const uint4*>(&Wb[(size_t)(o0 + row) * 256 + k0 + k8]);
            *reinterpret_cast<uint4*>(&Bs[row * 72 + k8]) =
                *reinterpret_cast<const uint4*>(&XNt[(size_t)(nn0 + row) * 256 + k0 + k8]);
        }
        __syncthreads();
#pragma unroll
        for (int ks = 0; ks < 2; ++ks) {
            const int kk = ks * 32 + lg * 8;
            bf16x8 af[4], bfr[4];
#pragma unroll
            for (int i = 0; i < 4; ++i) {
                af[i]  = *reinterpret_cast<const bf16x8*>(&As[(wo + i * 16 + lr) * 72 + kk]);
                bfr[i] = *reinterpret_cast<const bf16x8*>(&Bs[(wn + i * 16 + lr) * 72 + kk]);
            }
#pragma unroll
            for (int i = 0; i < 4; ++i)
#pragma unroll
                for (int j = 0; j < 4; ++j)
                    acc[i][j] = __builtin_amdgcn_mfma_f32_16x16x32_bf16(
                        af[i], bfr[j], acc[i][j], 0, 0, 0);
        }
        __syncthreads();
    }

    // Epilogue: per osub pass, 32 o-rows x 128 n-cols through LDS (aliases As).
    float* Ts = reinterpret_cast<float*>(As);  // 32 x 132 fp32 = 16.5 KB
#pragma unroll
    for (int osub = 0; osub < 4; ++osub) {
        const float4 b4 = *reinterpret_cast<const float4*>(&bias[o0 + wo + osub * 16 + 4 * lg]);
        const int rowb = (wid >> 1) * 16 + 4 * lg;
#pragma unroll
        for (int j = 0; j < 4; ++j) {
            const int col = wn + j * 16 + lr;
            Ts[(rowb + 0) * 132 + col] = acc[osub][j][0] + b4.x;
            Ts[(rowb + 1) * 132 + col] = acc[osub][j][1] + b4.y;
            Ts[(rowb + 2) * 132 + col] = acc[osub][j][2] + b4.z;
            Ts[(rowb + 3) * 132 + col] = acc[osub][j][3] + b4.w;
        }
        __syncthreads();
        if (o0 < 512) {
            // Q/K: k-major QKt[b][n'][512], transposed read of Ts columns
#pragma unroll
            for (int p = 0; p < 4; ++p) {
                const int item = p * 256 + t;     // 0..1023
                const int n = item >> 3;          // 0..127
                const int half = (item >> 2) & 1;
                const int o4 = (item & 3) * 4;
                union { ushort4 u; __hip_bfloat16 h[4]; } pk;
#pragma unroll
                for (int e = 0; e < 4; ++e)
                    pk.h[e] = __float2bfloat16(Ts[(half * 16 + o4 + e) * 132 + n]);
                const int nn = nn0 + n;
                const int bb2 = nn / NPW;
                const int np = nn - bb2 * NPW;
                const int o = o0 + half * 64 + osub * 16 + o4;
                *reinterpret_cast<ushort4*>(&QKt[((size_t)bb2 * NPW + np) * 512 + o]) = pk.u;
            }
        } else {
            // V: plane-major [c][n'] (c = o-512)
#pragma unroll
            for (int p = 0; p < 4; ++p) {
                const int idx = p * 256 + t;      // 0..1023
                const int row = idx >> 5;         // 0..31
                const int c4 = (idx & 31) * 4;    // 0..124
                const float4 v = *reinterpret_cast<const float4*>(&Ts[row * 132 + c4]);
                const int o = o0 + (row >> 4) * 64 + osub * 16 + (row & 15);
                const int nn = nn0 + c4;
                const int bb2 = nn / NPW;
                const int n = nn - bb2 * NPW;     // padded-windowed n'
                union { ushort4 u; __hip_bfloat16 h[4]; } pk;
                pk.h[0] = __float2bfloat16(v.x);
                pk.h[1] = __float2bfloat16(v.y);
                pk.h[2] = __float2bfloat16(v.z);
                pk.h[3] = __float2bfloat16(v.w);
                *reinterpret_cast<ushort4*>(&Vb[((size_t)bb2 * 256 + (o - 512)) * NPW + n]) = pk.u;
            }
        }
        __syncthreads();
    }
}

// ---------------------------------------------------------------------------
// K4/K6 (fp32 FFN GEMMs): 1x1-conv GEMM, K=256. 64x64 tile per block, 4x4
// register tile per thread. n-order agnostic (xa stays UNPADDED windowed).
// ---------------------------------------------------------------------------
template<bool RES>
__launch_bounds__(256)
__global__ void gemm_k256(const float* __restrict__ X, const float* __restrict__ Wt,
                          const float* __restrict__ bias,
                          const float* __restrict__ res, float* __restrict__ outF)
{
    __shared__ float Xs[64][64];
    __shared__ float Ws[64][64];
    const int b = blockIdx.z;
    const int n0 = blockIdx.x * 64;   // 49 tiles * 64 = 3136 exact
    const int o0 = blockIdx.y * 64;
    const float* Xb = X + (size_t)b * NC * NHW;
    const int t = threadIdx.x;
    const int f4 = (t & 15) * 4;
    const int r16 = t >> 4;
    const int tn = (t & 15) * 4;
    const int to = (t >> 4) * 4;

    float4 acc[4];
#pragma unroll
    for (int i = 0; i < 4; ++i) acc[i] = make_float4(0.f, 0.f, 0.f, 0.f);

    for (int kc = 0; kc < 4; ++kc) {
#pragma unroll
        for (int ps = 0; ps < 4; ++ps) {
            const int rr = r16 + ps * 16;
            const int c = kc * 64 + rr;
            float4 xv = *reinterpret_cast<const float4*>(Xb + (size_t)c * NHW + n0 + f4);
            *reinterpret_cast<float4*>(&Xs[rr][f4]) = xv;
            float4 wv = *reinterpret_cast<const float4*>(Wt + (size_t)(o0 + rr) * NC + kc * 64 + f4);
            *reinterpret_cast<float4*>(&Ws[rr][f4]) = wv;
        }
        __syncthreads();
#pragma unroll
        for (int k4 = 0; k4 < 16; ++k4) {
            float4 xr[4], wr[4];
#pragma unroll
            for (int jj = 0; jj < 4; ++jj)
                xr[jj] = *reinterpret_cast<const float4*>(&Xs[k4 * 4 + jj][tn]);
#pragma unroll
            for (int i = 0; i < 4; ++i)
                wr[i] = *reinterpret_cast<const float4*>(&Ws[to + i][k4 * 4]);
#pragma unroll
            for (int i = 0; i < 4; ++i) {
                acc[i].x = fmaf(wr[i].x, xr[0].x, acc[i].x);
                acc[i].y = fmaf(wr[i].x, xr[0].y, acc[i].y);
                acc[i].z = fmaf(wr[i].x, xr[0].z, acc[i].z);
                acc[i].w = fmaf(wr[i].x, xr[0].w, acc[i].w);
                acc[i].x = fmaf(wr[i].y, xr[1].x, acc[i].x);
                acc[i].y = fmaf(wr[i].y, xr[1].y, acc[i].y);
                acc[i].z = fmaf(wr[i].y, xr[1].z, acc[i].z);
                acc[i].w = fmaf(wr[i].y, xr[1].w, acc[i].w);
                acc[i].x = fmaf(wr[i].z, xr[2].x, acc[i].x);
                acc[i].y = fmaf(wr[i].z, xr[2].y, acc[i].y);
                acc[i].z = fmaf(wr[i].z, xr[2].z, acc[i].z);
                acc[i].w = fmaf(wr[i].z, xr[2].w, acc[i].w);
                acc[i].x = fmaf(wr[i].w, xr[3].x, acc[i].x);
                acc[i].y = fmaf(wr[i].w, xr[3].y, acc[i].y);
                acc[i].z = fmaf(wr[i].w, xr[3].z, acc[i].z);
                acc[i].w = fmaf(wr[i].w, xr[3].w, acc[i].w);
            }
        }
        __syncthreads();
    }
#pragma unroll
    for (int io = 0; io < 4; ++io) {
        const int o = o0 + to + io;
        const float bs = bias[o];
        float vals[4] = {acc[io].x + bs, acc[io].y + bs, acc[io].z + bs, acc[io].w + bs};
        if (RES) {
            const float4 rv = *reinterpret_cast<const float4*>(
                res + ((size_t)(b * NC + o)) * NHW + n0 + tn);
            vals[0] += rv.x; vals[1] += rv.y; vals[2] += rv.z; vals[3] += rv.w;
        }
        float* op = outF + ((size_t)b * NC + o) * NHW + n0 + tn;
        *reinterpret_cast<float4*>(op) = make_float4(vals[0], vals[1], vals[2], vals[3]);
    }
}

// ---------------------------------------------------------------------------
// K3: MFMA attention. ONE WAVE per (window, head), 64-thread blocks, ZERO
// __syncthreads. QK^T and PV on the matrix pipe (32 mfma 16x16x32 bf16/head,
// fp32 accum); softmax fully in registers (shfl_xor over 16-lane row groups).
// LDS 18176 B/block, phase-aliased:
//   [0,10240)  QT[64][40] + KT[64][40]  ->  P[64][72]  ->  wc f32 + spa bf16
//   [10240,..) VT[32][72]   [14848,..) X[32][52]
// Strides 40/72 ushorts give 2-way bank aliasing on ds_read_b128 (free, m136).
// Q/K pad rows and V pad cols zeroed -> S pads are exact zeros, no NaN path.
// ---------------------------------------------------------------------------
__launch_bounds__(64)
__global__ void attn_mfma(const unsigned short* __restrict__ QKt,
                          const unsigned short* __restrict__ Vb,
                          const unsigned short* __restrict__ XWW,
                          const float* __restrict__ wcomb,
                          const float* __restrict__ bsumg,
                          float* __restrict__ xa)
{
    const int j = blockIdx.x;            // window id 0..63
    const int head = blockIdx.y;         // 0..7
    const int b = blockIdx.z;
    const int c0 = head * 32;
    const int lane = threadIdx.x;
    const int lr = lane & 15, lg = lane >> 4;

    __shared__ __align__(16) char smem[18176];
    unsigned short* QT = (unsigned short*)smem;             // [64][40]
    unsigned short* KT = QT + 64 * 40;                      // [64][40]
    unsigned short* P  = (unsigned short*)smem;             // [64][72], aliases QT/KT
    float*          wcl = (float*)smem;                     // [1568] f32, aliases P
    unsigned short* SP = (unsigned short*)(smem + 6272);    // spa [32][52] bf16
    unsigned short* VT = (unsigned short*)(smem + 10240);   // [32][72]
    unsigned short* X  = (unsigned short*)(smem + 14848);   // [32][52]

    // ---- stage: zero Q/K pad rows 49..63 (cols 0..31)
    {
        ushort4 z; z.x = 0; z.y = 0; z.z = 0; z.w = 0;
        for (int i = lane; i < 120; i += 64) {
            const int r = 49 + (i >> 3), c4 = (i & 7) * 4;
            *reinterpret_cast<ushort4*>(&QT[r * 40 + c4]) = z;
            *reinterpret_cast<ushort4*>(&KT[r * 40 + c4]) = z;
        }
    }
    // ---- stage Q^T / K^T: direct 16B copies from k-major QKt
    const size_t qkbase = ((size_t)b * NPW + j * 52) * 512 + c0;
    for (int i = lane; i < 98; i += 64) {            // 49 p x {q,k}
        const int p = i >> 1;
        const unsigned short* src = QKt + qkbase + (size_t)p * 512 + (i & 1) * 256;
        unsigned short* dst = ((i & 1) ? KT : QT) + p * 40;
#pragma unroll
        for (int e = 0; e < 4; ++e)
            *reinterpret_cast<uint4*>(&dst[e * 8]) =
                *reinterpret_cast<const uint4*>(&src[e * 8]);
    }
    // ---- stage V^T (= plane-major v + xn, bf16, pads zero) and X
    const size_t pbase = ((size_t)(b * NC) + c0) * NPW + j * 52;
    for (int i = lane; i < 416; i += 64) {           // 32 d x 13 q4
        const int d = i / 13, q4 = (i - 13 * d) * 4;
        union { ushort4 u; unsigned short s[4]; } uv, ux, uo;
        uv.u = *reinterpret_cast<const ushort4*>(&Vb[pbase + (size_t)d * NPW + q4]);
        ux.u = *reinterpret_cast<const ushort4*>(&XWW[pbase + (size_t)d * NPW + q4]);
#pragma unroll
        for (int e = 0; e < 4; ++e) {
            const float vv = bu2f(uv.s[e]) + bu2f(ux.s[e]);
            uo.s[e] = (q4 + e >= 49) ? (unsigned short)0 : f2bu(vv);
        }
        *reinterpret_cast<ushort4*>(&VT[d * 72 + q4]) = uo.u;
        *reinterpret_cast<ushort4*>(&X[d * 52 + q4]) = ux.u;
    }
    {
        ushort4 z; z.x = 0; z.y = 0; z.z = 0; z.w = 0;
        for (int i = lane; i < 96; i += 64) {        // zero VT cols 52..63
            const int d = i / 3, c4 = 52 + (i % 3) * 4;
            *reinterpret_cast<ushort4*>(&VT[d * 72 + c4]) = z;
        }
    }

    // ---- S = Q^T K via MFMA (fp32 accum). A=QT rows, B^T=KT rows, K-dim=32.
    f32x4 acc[4][4];
#pragma unroll
    for (int mi = 0; mi < 4; ++mi)
#pragma unroll
        for (int ni = 0; ni < 4; ++ni)
            acc[mi][ni] = (f32x4){0.f, 0.f, 0.f, 0.f};
    {
        bf16x8 aq[4], bk[4];
#pragma unroll
        for (int mi = 0; mi < 4; ++mi)
            aq[mi] = *reinterpret_cast<const bf16x8*>(&QT[(mi * 16 + lr) * 40 + lg * 8]);
#pragma unroll
        for (int ni = 0; ni < 4; ++ni)
            bk[ni] = *reinterpret_cast<const bf16x8*>(&KT[(ni * 16 + lr) * 40 + lg * 8]);
#pragma unroll
        for (int mi = 0; mi < 4; ++mi)
#pragma unroll
            for (int ni = 0; ni < 4; ++ni)
                acc[mi][ni] = __builtin_amdgcn_mfma_f32_16x16x32_bf16(
                    aq[mi], bk[ni], acc[mi][ni], 0, 0, 0);
    }

    // ---- softmax in registers. Row r = mi*16+lg*4+reg spans the 16 lanes of
    // this lg-group; cols per lane: lr, lr+16, lr+32, lr+48 (48+lr valid iff lr==0).
    const float sc = 0.17677669529663687f;
#pragma unroll
    for (int mi = 0; mi < 4; ++mi)
#pragma unroll
        for (int reg = 0; reg < 4; ++reg) {
            const float v0 = acc[mi][0][reg] * sc;
            const float v1 = acc[mi][1][reg] * sc;
            const float v2 = acc[mi][2][reg] * sc;
            const float v3 = acc[mi][3][reg] * sc;
            float m = fmaxf(fmaxf(v0, v1), v2);
            if (lr == 0) m = fmaxf(m, v3);
            m = fmaxf(m, __shfl_xor(m, 1));
            m = fmaxf(m, __shfl_xor(m, 2));
            m = fmaxf(m, __shfl_xor(m, 4));
            m = fmaxf(m, __shfl_xor(m, 8));
            const float e0 = __expf(v0 - m), e1 = __expf(v1 - m), e2 = __expf(v2 - m);
            const float e3 = (lr == 0) ? __expf(v3 - m) : 0.f;
            float s = e0 + e1 + e2 + e3;
            s += __shfl_xor(s, 1);
            s += __shfl_xor(s, 2);
            s += __shfl_xor(s, 4);
            s += __shfl_xor(s, 8);
            const float inv = 1.f / s;
            acc[mi][0][reg] = e0 * inv;
            acc[mi][1][reg] = e1 * inv;
            acc[mi][2][reg] = e2 * inv;
            acc[mi][3][reg] = e3 * inv;
        }

    // ---- P -> LDS bf16 [p][k] (aliases dead QT/KT; ordered by acc data-dep)
#pragma unroll
    for (int mi = 0; mi < 4; ++mi)
#pragma unroll
        for (int ni = 0; ni < 4; ++ni)
#pragma unroll
            for (int reg = 0; reg < 4; ++reg)
                P[(mi * 16 + lg * 4 + reg) * 72 + ni * 16 + lr] = f2bu(acc[mi][ni][reg]);

    // ---- O = P @ V via MFMA, K-dim = 64 (2 steps). B^T = VT rows.
    f32x4 acc2[4][2];
#pragma unroll
    for (int mi = 0; mi < 4; ++mi)
#pragma unroll
        for (int ni = 0; ni < 2; ++ni)
            acc2[mi][ni] = (f32x4){0.f, 0.f, 0.f, 0.f};
#pragma unroll
    for (int ks = 0; ks < 2; ++ks) {
        bf16x8 ap[4], bv2[2];
#pragma unroll
        for (int mi = 0; mi < 4; ++mi)
            ap[mi] = *reinterpret_cast<const bf16x8*>(&P[(mi * 16 + lr) * 72 + ks * 32 + lg * 8]);
#pragma unroll
        for (int ni = 0; ni < 2; ++ni)
            bv2[ni] = *reinterpret_cast<const bf16x8*>(&VT[(ni * 16 + lr) * 72 + ks * 32 + lg * 8]);
#pragma unroll
        for (int mi = 0; mi < 4; ++mi)
#pragma unroll
            for (int ni = 0; ni < 2; ++ni)
                acc2[mi][ni] = __builtin_amdgcn_mfma_f32_16x16x32_bf16(
                    ap[mi], bv2[ni], acc2[mi][ni], 0, 0, 0);
    }
    __builtin_amdgcn_sched_barrier(0);   // keep wc/spa stores below all P reads

    // ---- spa[d][p] bf16 (D2: row=p, col=d), then wc fp32 into dead P region
#pragma unroll
    for (int mi = 0; mi < 4; ++mi)
#pragma unroll
        for (int ni = 0; ni < 2; ++ni)
#pragma unroll
            for (int reg = 0; reg < 4; ++reg) {
                const int p = mi * 16 + lg * 4 + reg;
                if (p < 49)
                    SP[(ni * 16 + lr) * 52 + p] = f2bu(acc2[mi][ni][reg]);
            }
    for (int i = lane; i < 392; i += 64)
        *reinterpret_cast<float4*>(&wcl[i * 4]) =
            *reinterpret_cast<const float4*>(&wcomb[c0 * 49 + i * 4]);

    // ---- combined 7x7 dw conv + 0.25*spa + bsum + v residual; windowed store
    for (int it = 0; it < 4; ++it) {
        const int item = it * 64 + lane;
        if (item < 224) {
            const int d = item / 7, h1 = item - 7 * d;
            const float bsv = bsumg[c0 + d];
            float accw[7];
#pragma unroll
            for (int w1 = 0; w1 < 7; ++w1) {
                const int p = h1 * 7 + w1;
                accw[w1] = fmaf(0.25f, bu2f(SP[d * 52 + p]), bsv + bu2f(VT[d * 72 + p]));
            }
#pragma unroll
            for (int dy = 0; dy < 7; ++dy) {
                const int ry = h1 + dy - 3;
                const bool rok = (ry >= 0) && (ry < 7);
                const int ryc = rok ? ry : 0;
                float xr[7];
#pragma unroll
                for (int i2 = 0; i2 < 7; ++i2) {
                    const float xv = bu2f(X[d * 52 + ryc * 7 + i2]);
                    xr[i2] = rok ? xv : 0.f;
                }
#pragma unroll
                for (int dx = 0; dx < 7; ++dx) {
                    const float wv = wcl[d * 49 + dy * 7 + dx];
#pragma unroll
                    for (int w1 = 0; w1 < 7; ++w1) {
                        const int rx = w1 + dx - 3;
                        if (rx >= 0 && rx < 7) accw[w1] = fmaf(wv, xr[rx], accw[w1]);
                    }
                }
            }
            float* xap = xa + ((size_t)(b * NC + c0 + d)) * NHW + j * 49 + h1 * 7;
#pragma unroll
            for (int w1 = 0; w1 < 7; ++w1) xap[w1] = accw[w1];
        }
    }
}

// ---------------------------------------------------------------------------
// K5: per-(b,c)-plane: 3x3 depthwise conv (conv_local) + SiLU on T
// (windowed -> LDS-normal -> stencil -> U normal), and in-place
// windowed->normal permute of xa (shortcut for the final GEMM).
// ---------------------------------------------------------------------------
__launch_bounds__(256)
__global__ void dw3_silu(const float* __restrict__ T, const float* __restrict__ wloc,
                         const float* __restrict__ bloc, float* __restrict__ U,
                         float* xa)
{
    const int c = blockIdx.x, b = blockIdx.y;
    const size_t pb = ((size_t)b * NC + c) * NHW;
    __shared__ float pl[56 * 57];        // T, normal order, stride-57 rows
    __shared__ float xpl[3136];          // xa, normal order
    const int tid = threadIdx.x;
    const float4* t4 = reinterpret_cast<const float4*>(T + pb);
    const float4* x4 = reinterpret_cast<const float4*>(xa + pb);
    for (int i = tid; i < 784; i += 256) {
        const float4 tv = t4[i];
        const float4 xv = x4[i];
        const float tt[4] = {tv.x, tv.y, tv.z, tv.w};
        const float xx[4] = {xv.x, xv.y, xv.z, xv.w};
#pragma unroll
        for (int e = 0; e < 4; ++e) {
            const int n = 4 * i + e;
            const int j = n / 49, p = n - 49 * j;
            const int h1 = p / 7, w1 = p - 7 * h1;
            const int h = h1 * 8 + (j >> 3), w = w1 * 8 + (j & 7);
            pl[h * 57 + w] = tt[e];
            xpl[h * 56 + w] = xx[e];
        }
    }
    __syncthreads();

    float wk[9];
#pragma unroll
    for (int k = 0; k < 9; ++k) wk[k] = wloc[c * 9 + k];
    const float bs = bloc[c];
    for (int i = tid; i < NHW; i += 256) {
        const int h = i / 56, w = i - 56 * h;
        float acc = bs;
#pragma unroll
        for (int dy = -1; dy <= 1; ++dy) {
            const int hh = h + dy;
            if (hh < 0 || hh >= 56) continue;
#pragma unroll
            for (int dx = -1; dx <= 1; ++dx) {
                const int ww = w + dx;
                if (ww < 0 || ww >= 56) continue;
                acc = fmaf(wk[(dy + 1) * 3 + (dx + 1)], pl[hh * 57 + ww], acc);
            }
        }
        U[pb + i] = acc / (1.f + __expf(-acc));   // silu
    }

    float4* xo4 = reinterpret_cast<float4*>(xa + pb);
    for (int i = tid; i < 784; i += 256)
        xo4[i] = make_float4(xpl[4 * i], xpl[4 * i + 1], xpl[4 * i + 2], xpl[4 * i + 3]);
}

// ---------------------------------------------------------------------------
// Launch. Workspace layout (floats):
//   [0,512)              : BN affine a[256], b[256]
//   wcomb = W+512        : 256*49 combined dw weights
//   bsum  = W+13056      : 256
//   Wb    = W+13312      : 768*256 bf16 qkv weights (98304 floats)
//   xa    = W+111616     : NA floats — XNt bf16 alias (padded-windowed rows,
//                          dead after GEMM), attn output (windowed), then
//                          NORMAL after K5 (in-place)
//   R     = xa+NA        : 54.53M floats shared region:
//       phase 1: QKt ush [b][3328][512] (27.26M fl) + Vb planes (13.63M fl)
//                + XWW planes (13.63M fl)
//       phase 2: T (windowed fp32 NA) + U (normal fp32 NA), aliasing phase 1
//   total ~ 321.3 MB (same as R1)
// ---------------------------------------------------------------------------
extern "C" void kernel_launch(void* const* d_in, const int* in_sizes, int n_in,
                              void* d_out, int out_size, void* d_ws, size_t ws_size,
                              hipStream_t stream)
{
    (void)in_sizes; (void)n_in; (void)out_size; (void)ws_size;
    const float* x    = (const float*)d_in[0];
    const float* g    = (const float*)d_in[1];
    const float* be   = (const float*)d_in[2];
    const float* qkvw = (const float*)d_in[3];
    const float* qkvb = (const float*)d_in[4];
    const float* w3   = (const float*)d_in[5];
    const float* b3   = (const float*)d_in[6];
    const float* w5   = (const float*)d_in[7];
    const float* b5   = (const float*)d_in[8];
    const float* w7   = (const float*)d_in[9];
    const float* b7   = (const float*)d_in[10];
    const float* fiw  = (const float*)d_in[11];
    const float* fib  = (const float*)d_in[12];
    const float* clw  = (const float*)d_in[13];
    const float* clb  = (const float*)d_in[14];
    const float* fow  = (const float*)d_in[15];
    const float* fob  = (const float*)d_in[16];
    float* out = (float*)d_out;

    float* W     = (float*)d_ws;
    float* ab    = W;
    float* wcomb = W + 512;
    float* bsum  = W + 13056;
    __hip_bfloat16* Wb = (__hip_bfloat16*)(W + 13312);      // 768*256 bf16
    float* xa    = W + 111616;
    unsigned short* XNt = (unsigned short*)xa;              // padded rows, dead after GEMM
    float* R     = xa + NA;
    unsigned short* QKt = (unsigned short*)R;               // [b][3328][512]
    unsigned short* Vb  = QKt + (size_t)NB * NPW * 512;     // 256*NB planes of NPW
    unsigned short* XWW = Vb + (size_t)NB * 256 * NPW;      // 256*NB planes of NPW
    float* T = R;                                           // aliases QKt (dead after K3)
    float* U = R + NA;                                      // aliases Vb/XWW tail

    bn_stats<<<dim3(256), dim3(256), 0, stream>>>(x, g, be, w3, b3, w5, b5, w7, b7,
                                                  qkvw, ab, wcomb, bsum, Wb);
    xnt_make2<<<dim3(4, 8, NB), dim3(256), 0, stream>>>(x, ab, XNt, XWW);
    gemm_qkv_mfma<<<dim3(832, 6), dim3(256), 0, stream>>>(
        XNt, (const unsigned short*)Wb, qkvb, QKt, Vb);
    attn_mfma<<<dim3(64, 8, NB), dim3(64), 0, stream>>>(
        QKt, Vb, XWW, wcomb, bsum, xa);
    gemm_k256<false><<<dim3(49, 4, NB), dim3(256), 0, stream>>>(xa, fiw, fib, nullptr, T);
    dw3_silu<<<dim3(256, NB), dim3(256), 0, stream>>>(T, clw, clb, U, xa);
    gemm_k256<true><<<dim3(49, 4, NB), dim3(256), 0, stream>>>(U, fow, fob, xa, out);
}

// Round 4
// 883.181 us; speedup vs baseline: 2.0328x; 1.2013x over previous
//
#include <hip/hip_runtime.h>
#include <hip/hip_bf16.h>

// Problem constants
#define NB 32
#define NC 256
#define NHW 3136                 // 56*56
#define NA 25690112ull           // NB*NC*NHW elements (one NCHW tensor)
#define NPW 3328                 // padded windowed plane: 64 windows * 52
#define LTS 396                  // xnt_make2 LDS row stride (ushorts, mult of 4)

typedef __attribute__((ext_vector_type(8))) short bf16x8;
typedef __attribute__((ext_vector_type(4))) float f32x4;

// Window mapping: h=h1*8+j1, w=w1*8+j2; j=j1*8+j2 (0..63), p=h1*7+w1 (0..48).
// PADDED windowed linear index n' = j*52 + p (p in [0,52), p>=49 = pad).

static __device__ __forceinline__ unsigned short f2bu(float f) {
    union { __hip_bfloat16 h; unsigned short u; } c;
    c.h = __float2bfloat16(f);
    return c.u;
}
static __device__ __forceinline__ float bu2f(unsigned short us) {
    union { unsigned short u; __hip_bfloat16 h; } c;
    c.u = us;
    return __bfloat162float(c.h);
}

// ---------------------------------------------------------------------------
// K1: BatchNorm stats -> per-channel affine (a,b): xn = a*x + b.
// Also precomputes combined depthwise weights wcomb = 0.25*(w3+w5+w7) (7x7),
// bias sum bsum, and bf16 copies of qkv/ffn_in/ffn_out weights.
// ---------------------------------------------------------------------------
__launch_bounds__(256)
__global__ void bn_stats(const float* __restrict__ x, const float* __restrict__ gamma,
                         const float* __restrict__ beta,
                         const float* __restrict__ w3, const float* __restrict__ b3,
                         const float* __restrict__ w5, const float* __restrict__ b5,
                         const float* __restrict__ w7, const float* __restrict__ b7,
                         const float* __restrict__ qkvw,
                         const float* __restrict__ fiw, const float* __restrict__ fow,
                         float* __restrict__ ab, float* __restrict__ wcomb,
                         float* __restrict__ bsum, __hip_bfloat16* __restrict__ Wb,
                         __hip_bfloat16* __restrict__ Wfb, __hip_bfloat16* __restrict__ Wob)
{
    const int c = blockIdx.x;
    const int tid = threadIdx.x;

    if (tid < 49) {
        const int ty = tid / 7, tx = tid % 7;
        float wv = w7[c * 49 + tid];
        if (ty >= 1 && ty <= 5 && tx >= 1 && tx <= 5) wv += w5[c * 25 + (ty - 1) * 5 + (tx - 1)];
        if (ty >= 2 && ty <= 4 && tx >= 2 && tx <= 4) wv += w3[c * 9 + (ty - 2) * 3 + (tx - 2)];
        wcomb[c * 49 + tid] = 0.25f * wv;
    }
    if (tid == 63) bsum[c] = 0.25f * (b3[c] + b5[c] + b7[c]);

#pragma unroll
    for (int r = 0; r < 3; ++r) {
        const int o = 3 * c + r;
        Wb[o * 256 + tid] = __float2bfloat16(qkvw[o * 256 + tid]);
    }
    Wfb[c * 256 + tid] = __float2bfloat16(fiw[c * 256 + tid]);
    Wob[c * 256 + tid] = __float2bfloat16(fow[c * 256 + tid]);

    float s = 0.f, s2 = 0.f;
    for (int b = 0; b < NB; ++b) {
        const float4* p = reinterpret_cast<const float4*>(x + ((size_t)b * NC + c) * NHW);
        for (int i = tid; i < NHW / 4; i += 256) {      // 3136/4 = 784
            const float4 v = p[i];
            s += v.x + v.y + v.z + v.w;
            s2 = fmaf(v.x, v.x, s2); s2 = fmaf(v.y, v.y, s2);
            s2 = fmaf(v.z, v.z, s2); s2 = fmaf(v.w, v.w, s2);
        }
    }
    __shared__ float r1[256], r2[256];
    r1[tid] = s; r2[tid] = s2;
    __syncthreads();
    for (int off = 128; off > 0; off >>= 1) {
        if (tid < off) { r1[tid] += r1[tid + off]; r2[tid] += r2[tid + off]; }
        __syncthreads();
    }
    if (tid == 0) {
        const float inv_n = 1.f / (float)((size_t)NB * NHW);
        const float mean = r1[0] * inv_n;
        const float var = r2[0] * inv_n - mean * mean;
        const float a = gamma[c] / sqrtf(var + 1e-5f);
        ab[c] = a;
        ab[NC + c] = beta[c] - mean * a;
    }
}

// ---------------------------------------------------------------------------
// K1.5: xn = a*x+b applied once; emits PADDED-WINDOWED outputs:
//   XNt bf16 [(b*3328 + n')][c]  (k-contiguous rows for the MFMA GEMM)
//   XWW bf16 [b][c][n']          (padded windowed planes, pads ZEROED)
// ---------------------------------------------------------------------------
__launch_bounds__(256)
__global__ void xnt_make2(const float* __restrict__ x, const float* __restrict__ ab,
                          unsigned short* __restrict__ XNt, unsigned short* __restrict__ XWW)
{
    const int c0 = blockIdx.x * 64;      // channel chunk
    const int j1 = blockIdx.y;           // window row id
    const int b  = blockIdx.z;
    __shared__ unsigned short lt[64 * LTS];   // [c][px], px = h1*56 + w
    __shared__ float aa[64], bb[64];
    const int tid = threadIdx.x;
    if (tid < 64) { aa[tid] = ab[c0 + tid]; bb[tid] = ab[256 + c0 + tid]; }
    __syncthreads();

    // Phase A: load 64c x 7rows x 56w fp32, affine, cvt bf16 -> LDS
    for (int idx = tid; idx < 6272; idx += 256) {       // 64 * 98 float4
        const int c = idx / 98, f = idx - 98 * c;
        const int h1 = f / 14, w4 = (f - 14 * h1) * 4;
        const float4 v = *reinterpret_cast<const float4*>(
            &x[((size_t)(b * NC) + c0 + c) * NHW + (h1 * 8 + j1) * 56 + w4]);
        const float a = aa[c], bv = bb[c];
        union { ushort4 u; __hip_bfloat16 h[4]; } pk;
        pk.h[0] = __float2bfloat16(fmaf(a, v.x, bv));
        pk.h[1] = __float2bfloat16(fmaf(a, v.y, bv));
        pk.h[2] = __float2bfloat16(fmaf(a, v.z, bv));
        pk.h[3] = __float2bfloat16(fmaf(a, v.w, bv));
        *reinterpret_cast<ushort4*>(&lt[c * LTS + h1 * 56 + w4]) = pk.u;
    }
    __syncthreads();

    // Phase B: XWW planes: per (c, j2) one padded window run of 52 (13 ushort4)
    for (int idx = tid; idx < 6656; idx += 256) {       // 64c * 8j2 * 13
        const int c = idx / 104, r = idx - 104 * c;
        const int j2 = r / 13, q4 = (r - 13 * j2) * 4;
        unsigned short tmp[4];
#pragma unroll
        for (int e = 0; e < 4; ++e) {
            const int p = q4 + e;
            if (p < 49) {
                const int h1p = p / 7, w1 = p - 7 * h1p;
                tmp[e] = lt[c * LTS + h1p * 56 + w1 * 8 + j2];
            } else {
                tmp[e] = 0;                              // zero pad (+0.0 bf16)
            }
        }
        ushort4 v; v.x = tmp[0]; v.y = tmp[1]; v.z = tmp[2]; v.w = tmp[3];
        *reinterpret_cast<ushort4*>(
            &XWW[((size_t)(b * NC) + c0 + c) * NPW + (j1 * 8 + j2) * 52 + q4]) = v;
    }

    // Phase C: XNt rows: per (p, j2, c4): 4 channels of one windowed row
    for (int idx = tid; idx < 6272; idx += 256) {       // 49p * 8j2 * 16c4
        const int p = idx >> 7;                          // 0..48
        const int r = idx & 127;
        const int j2 = r >> 4, c4 = (r & 15) * 4;
        const int h1p = p / 7, w1 = p - 7 * h1p;
        const int px = h1p * 56 + w1 * 8 + j2;
        ushort4 v;
        v.x = lt[(c4 + 0) * LTS + px];
        v.y = lt[(c4 + 1) * LTS + px];
        v.z = lt[(c4 + 2) * LTS + px];
        v.w = lt[(c4 + 3) * LTS + px];
        *reinterpret_cast<ushort4*>(
            &XNt[((size_t)b * NPW + (j1 * 8 + j2) * 52 + p) * 256 + c0 + c4]) = v;
    }
}

// ---------------------------------------------------------------------------
// K2: QKV 1x1-conv as bf16 MFMA GEMM. Out[o][nn'] = sum_c Wb[o][c]*XNt[nn'][c].
//   o in [0,512)  (Q,K): QKt[b][n'][512] k-major.
//   o in [512,768) (V):  plane-major Vb[c][n'].
// ---------------------------------------------------------------------------
__launch_bounds__(256)
__global__ void gemm_qkv_mfma(const unsigned short* __restrict__ XNt,
                              const unsigned short* __restrict__ Wb,
                              const float* __restrict__ bias,
                              unsigned short* __restrict__ QKt,
                              unsigned short* __restrict__ Vb)
{
    __shared__ unsigned short As[128 * 72];   // W tile   [o][k]
    __shared__ unsigned short Bs[128 * 72];   // XNt tile [n][k]
    const int t = threadIdx.x;
    const int nn0 = blockIdx.x * 128;
    const int o0 = blockIdx.y * 128;
    const int lane = t & 63;
    const int wid = t >> 6;
    const int lr = lane & 15, lg = lane >> 4;
    const int wo = (wid >> 1) * 64;
    const int wn = (wid & 1) * 64;

    f32x4 acc[4][4];
#pragma unroll
    for (int i = 0; i < 4; ++i)
#pragma unroll
        for (int j = 0; j < 4; ++j)
            acc[i][j] = (f32x4){0.f, 0.f, 0.f, 0.f};

    for (int kt = 0; kt < 4; ++kt) {
        const int k0 = kt * 64;
#pragma unroll
        for (int it = 0; it < 4; ++it) {
            const int idx = it * 256 + t;     // 0..1023
            const int row = idx >> 3;         // 0..127
            const int k8 = (idx & 7) * 8;     // 0..56
            *reinterpret_cast<uint4*>(&As[row * 72 + k8]) =
                *reinterpret_cast<const uint4*>(&Wb[(size_t)(o0 + row) * 256 + k0 + k8]);
            *reinterpret_cast<uint4*>(&Bs[row * 72 + k8]) =
                *reinterpret_cast<const uint4*>(&XNt[(size_t)(nn0 + row) * 256 + k0 + k8]);
        }
        __syncthreads();
#pragma unroll
        for (int ks = 0; ks < 2; ++ks) {
            const int kk = ks * 32 + lg * 8;
            bf16x8 af[4], bfr[4];
#pragma unroll
            for (int i = 0; i < 4; ++i) {
                af[i]  = *reinterpret_cast<const bf16x8*>(&As[(wo + i * 16 + lr) * 72 + kk]);
                bfr[i] = *reinterpret_cast<const bf16x8*>(&Bs[(wn + i * 16 + lr) * 72 + kk]);
            }
#pragma unroll
            for (int i = 0; i < 4; ++i)
#pragma unroll
                for (int j = 0; j < 4; ++j)
                    acc[i][j] = __builtin_amdgcn_mfma_f32_16x16x32_bf16(
                        af[i], bfr[j], acc[i][j], 0, 0, 0);
        }
        __syncthreads();
    }

    // Epilogue: per osub pass, 32 o-rows x 128 n-cols through LDS (aliases As).
    float* Ts = reinterpret_cast<float*>(As);  // 32 x 132 fp32 = 16.5 KB
#pragma unroll
    for (int osub = 0; osub < 4; ++osub) {
        const float4 b4 = *reinterpret_cast<const float4*>(&bias[o0 + wo + osub * 16 + 4 * lg]);
        const int rowb = (wid >> 1) * 16 + 4 * lg;
#pragma unroll
        for (int j = 0; j < 4; ++j) {
            const int col = wn + j * 16 + lr;
            Ts[(rowb + 0) * 132 + col] = acc[osub][j][0] + b4.x;
            Ts[(rowb + 1) * 132 + col] = acc[osub][j][1] + b4.y;
            Ts[(rowb + 2) * 132 + col] = acc[osub][j][2] + b4.z;
            Ts[(rowb + 3) * 132 + col] = acc[osub][j][3] + b4.w;
        }
        __syncthreads();
        if (o0 < 512) {
            // Q/K: k-major QKt[b][n'][512], transposed read of Ts columns
#pragma unroll
            for (int p = 0; p < 4; ++p) {
                const int item = p * 256 + t;     // 0..1023
                const int n = item >> 3;          // 0..127
                const int half = (item >> 2) & 1;
                const int o4 = (item & 3) * 4;
                union { ushort4 u; __hip_bfloat16 h[4]; } pk;
#pragma unroll
                for (int e = 0; e < 4; ++e)
                    pk.h[e] = __float2bfloat16(Ts[(half * 16 + o4 + e) * 132 + n]);
                const int nn = nn0 + n;
                const int bb2 = nn / NPW;
                const int np = nn - bb2 * NPW;
                const int o = o0 + half * 64 + osub * 16 + o4;
                *reinterpret_cast<ushort4*>(&QKt[((size_t)bb2 * NPW + np) * 512 + o]) = pk.u;
            }
        } else {
            // V: plane-major [c][n'] (c = o-512)
#pragma unroll
            for (int p = 0; p < 4; ++p) {
                const int idx = p * 256 + t;      // 0..1023
                const int row = idx >> 5;         // 0..31
                const int c4 = (idx & 31) * 4;    // 0..124
                const float4 v = *reinterpret_cast<const float4*>(&Ts[row * 132 + c4]);
                const int o = o0 + (row >> 4) * 64 + osub * 16 + (row & 15);
                const int nn = nn0 + c4;
                const int bb2 = nn / NPW;
                const int n = nn - bb2 * NPW;     // padded-windowed n'
                union { ushort4 u; __hip_bfloat16 h[4]; } pk;
                pk.h[0] = __float2bfloat16(v.x);
                pk.h[1] = __float2bfloat16(v.y);
                pk.h[2] = __float2bfloat16(v.z);
                pk.h[3] = __float2bfloat16(v.w);
                *reinterpret_cast<ushort4*>(&Vb[((size_t)bb2 * 256 + (o - 512)) * NPW + n]) = pk.u;
            }
        }
        __syncthreads();
    }
}

// ---------------------------------------------------------------------------
// K4/K6: FFN 1x1-conv as bf16 MFMA GEMM (K=256, O=256).
// B = k-major bf16 activations [(nn)][256]; nn = b*3136 + n (n-order carried
// through from the transpose producing B). Epilogue: bias, optional fp32
// shortcut add (res, plane-major, same n-order), fp32 plane-major output.
// nn-tiles may straddle batch boundary (3136%128!=0) -> per-float4 b2 calc.
// ---------------------------------------------------------------------------
template<bool RES>
__launch_bounds__(256)
__global__ void gemm_ffn_mfma(const unsigned short* __restrict__ Bt,
                              const unsigned short* __restrict__ Wb2,
                              const float* __restrict__ bias,
                              const float* __restrict__ res, float* __restrict__ outF)
{
    __shared__ unsigned short As[128 * 72];   // W tile [o][k]
    __shared__ unsigned short Bs[128 * 72];   // act tile [n][k]
    const int t = threadIdx.x;
    const int o0 = blockIdx.x * 128;
    const int nn0 = blockIdx.y * 128;
    const int lane = t & 63;
    const int wid = t >> 6;
    const int lr = lane & 15, lg = lane >> 4;
    const int wo = (wid >> 1) * 64;
    const int wn = (wid & 1) * 64;

    f32x4 acc[4][4];
#pragma unroll
    for (int i = 0; i < 4; ++i)
#pragma unroll
        for (int j = 0; j < 4; ++j)
            acc[i][j] = (f32x4){0.f, 0.f, 0.f, 0.f};

    for (int kt = 0; kt < 4; ++kt) {
        const int k0 = kt * 64;
#pragma unroll
        for (int it = 0; it < 4; ++it) {
            const int idx = it * 256 + t;
            const int row = idx >> 3;
            const int k8 = (idx & 7) * 8;
            *reinterpret_cast<uint4*>(&As[row * 72 + k8]) =
                *reinterpret_cast<const uint4*>(&Wb2[(size_t)(o0 + row) * 256 + k0 + k8]);
            *reinterpret_cast<uint4*>(&Bs[row * 72 + k8]) =
                *reinterpret_cast<const uint4*>(&Bt[(size_t)(nn0 + row) * 256 + k0 + k8]);
        }
        __syncthreads();
#pragma unroll
        for (int ks = 0; ks < 2; ++ks) {
            const int kk = ks * 32 + lg * 8;
            bf16x8 af[4], bfr[4];
#pragma unroll
            for (int i = 0; i < 4; ++i) {
                af[i]  = *reinterpret_cast<const bf16x8*>(&As[(wo + i * 16 + lr) * 72 + kk]);
                bfr[i] = *reinterpret_cast<const bf16x8*>(&Bs[(wn + i * 16 + lr) * 72 + kk]);
            }
#pragma unroll
            for (int i = 0; i < 4; ++i)
#pragma unroll
                for (int j = 0; j < 4; ++j)
                    acc[i][j] = __builtin_amdgcn_mfma_f32_16x16x32_bf16(
                        af[i], bfr[j], acc[i][j], 0, 0, 0);
        }
        __syncthreads();
    }

    float* Ts = reinterpret_cast<float*>(As);  // 32 x 132 fp32
#pragma unroll
    for (int osub = 0; osub < 4; ++osub) {
        const float4 b4 = *reinterpret_cast<const float4*>(&bias[o0 + wo + osub * 16 + 4 * lg]);
        const int rowb = (wid >> 1) * 16 + 4 * lg;
#pragma unroll
        for (int j = 0; j < 4; ++j) {
            const int col = wn + j * 16 + lr;
            Ts[(rowb + 0) * 132 + col] = acc[osub][j][0] + b4.x;
            Ts[(rowb + 1) * 132 + col] = acc[osub][j][1] + b4.y;
            Ts[(rowb + 2) * 132 + col] = acc[osub][j][2] + b4.z;
            Ts[(rowb + 3) * 132 + col] = acc[osub][j][3] + b4.w;
        }
        __syncthreads();
#pragma unroll
        for (int p = 0; p < 4; ++p) {
            const int idx = p * 256 + t;      // 0..1023
            const int row = idx >> 5;         // 0..31
            const int c4 = (idx & 31) * 4;    // 0..124
            float4 v = *reinterpret_cast<const float4*>(&Ts[row * 132 + c4]);
            const int o = o0 + (row >> 4) * 64 + osub * 16 + (row & 15);
            const int nn = nn0 + c4;
            const int b2 = nn / NHW;
            const int n = nn - b2 * NHW;      // float4 never straddles (NHW%4==0)
            const size_t po = ((size_t)(b2 * NC + o)) * NHW + n;
            if (RES) {
                const float4 rv = *reinterpret_cast<const float4*>(&res[po]);
                v.x += rv.x; v.y += rv.y; v.z += rv.z; v.w += rv.w;
            }
            *reinterpret_cast<float4*>(&outF[po]) = v;
        }
        __syncthreads();
    }
}

// ---------------------------------------------------------------------------
// K3: MFMA attention. ONE WAVE per (window, head), 64-thread blocks, ZERO
// __syncthreads. QK^T and PV on the matrix pipe; softmax in registers.
// ---------------------------------------------------------------------------
__launch_bounds__(64)
__global__ void attn_mfma(const unsigned short* __restrict__ QKt,
                          const unsigned short* __restrict__ Vb,
                          const unsigned short* __restrict__ XWW,
                          const float* __restrict__ wcomb,
                          const float* __restrict__ bsumg,
                          float* __restrict__ xa)
{
    const int j = blockIdx.x;            // window id 0..63
    const int head = blockIdx.y;         // 0..7
    const int b = blockIdx.z;
    const int c0 = head * 32;
    const int lane = threadIdx.x;
    const int lr = lane & 15, lg = lane >> 4;

    __shared__ __align__(16) char smem[18176];
    unsigned short* QT = (unsigned short*)smem;             // [64][40]
    unsigned short* KT = QT + 64 * 40;                      // [64][40]
    unsigned short* P  = (unsigned short*)smem;             // [64][72], aliases QT/KT
    float*          wcl = (float*)smem;                     // [1568] f32, aliases P
    unsigned short* SP = (unsigned short*)(smem + 6272);    // spa [32][52] bf16
    unsigned short* VT = (unsigned short*)(smem + 10240);   // [32][72]
    unsigned short* X  = (unsigned short*)(smem + 14848);   // [32][52]

    // ---- stage: zero Q/K pad rows 49..63 (cols 0..31)
    {
        ushort4 z; z.x = 0; z.y = 0; z.z = 0; z.w = 0;
        for (int i = lane; i < 120; i += 64) {
            const int r = 49 + (i >> 3), c4 = (i & 7) * 4;
            *reinterpret_cast<ushort4*>(&QT[r * 40 + c4]) = z;
            *reinterpret_cast<ushort4*>(&KT[r * 40 + c4]) = z;
        }
    }
    // ---- stage Q^T / K^T: direct 16B copies from k-major QKt
    const size_t qkbase = ((size_t)b * NPW + j * 52) * 512 + c0;
    for (int i = lane; i < 98; i += 64) {            // 49 p x {q,k}
        const int p = i >> 1;
        const unsigned short* src = QKt + qkbase + (size_t)p * 512 + (i & 1) * 256;
        unsigned short* dst = ((i & 1) ? KT : QT) + p * 40;
#pragma unroll
        for (int e = 0; e < 4; ++e)
            *reinterpret_cast<uint4*>(&dst[e * 8]) =
                *reinterpret_cast<const uint4*>(&src[e * 8]);
    }
    // ---- stage V^T (= plane-major v + xn, bf16, pads zero) and X
    const size_t pbase = ((size_t)(b * NC) + c0) * NPW + j * 52;
    for (int i = lane; i < 416; i += 64) {           // 32 d x 13 q4
        const int d = i / 13, q4 = (i - 13 * d) * 4;
        union { ushort4 u; unsigned short s[4]; } uv, ux, uo;
        uv.u = *reinterpret_cast<const ushort4*>(&Vb[pbase + (size_t)d * NPW + q4]);
        ux.u = *reinterpret_cast<const ushort4*>(&XWW[pbase + (size_t)d * NPW + q4]);
#pragma unroll
        for (int e = 0; e < 4; ++e) {
            const float vv = bu2f(uv.s[e]) + bu2f(ux.s[e]);
            uo.s[e] = (q4 + e >= 49) ? (unsigned short)0 : f2bu(vv);
        }
        *reinterpret_cast<ushort4*>(&VT[d * 72 + q4]) = uo.u;
        *reinterpret_cast<ushort4*>(&X[d * 52 + q4]) = ux.u;
    }
    {
        ushort4 z; z.x = 0; z.y = 0; z.z = 0; z.w = 0;
        for (int i = lane; i < 96; i += 64) {        // zero VT cols 52..63
            const int d = i / 3, c4 = 52 + (i % 3) * 4;
            *reinterpret_cast<ushort4*>(&VT[d * 72 + c4]) = z;
        }
    }

    // ---- S = Q^T K via MFMA (fp32 accum)
    f32x4 acc[4][4];
#pragma unroll
    for (int mi = 0; mi < 4; ++mi)
#pragma unroll
        for (int ni = 0; ni < 4; ++ni)
            acc[mi][ni] = (f32x4){0.f, 0.f, 0.f, 0.f};
    {
        bf16x8 aq[4], bk[4];
#pragma unroll
        for (int mi = 0; mi < 4; ++mi)
            aq[mi] = *reinterpret_cast<const bf16x8*>(&QT[(mi * 16 + lr) * 40 + lg * 8]);
#pragma unroll
        for (int ni = 0; ni < 4; ++ni)
            bk[ni] = *reinterpret_cast<const bf16x8*>(&KT[(ni * 16 + lr) * 40 + lg * 8]);
#pragma unroll
        for (int mi = 0; mi < 4; ++mi)
#pragma unroll
            for (int ni = 0; ni < 4; ++ni)
                acc[mi][ni] = __builtin_amdgcn_mfma_f32_16x16x32_bf16(
                    aq[mi], bk[ni], acc[mi][ni], 0, 0, 0);
    }

    // ---- softmax in registers
    const float sc = 0.17677669529663687f;
#pragma unroll
    for (int mi = 0; mi < 4; ++mi)
#pragma unroll
        for (int reg = 0; reg < 4; ++reg) {
            const float v0 = acc[mi][0][reg] * sc;
            const float v1 = acc[mi][1][reg] * sc;
            const float v2 = acc[mi][2][reg] * sc;
            const float v3 = acc[mi][3][reg] * sc;
            float m = fmaxf(fmaxf(v0, v1), v2);
            if (lr == 0) m = fmaxf(m, v3);
            m = fmaxf(m, __shfl_xor(m, 1));
            m = fmaxf(m, __shfl_xor(m, 2));
            m = fmaxf(m, __shfl_xor(m, 4));
            m = fmaxf(m, __shfl_xor(m, 8));
            const float e0 = __expf(v0 - m), e1 = __expf(v1 - m), e2 = __expf(v2 - m);
            const float e3 = (lr == 0) ? __expf(v3 - m) : 0.f;
            float s = e0 + e1 + e2 + e3;
            s += __shfl_xor(s, 1);
            s += __shfl_xor(s, 2);
            s += __shfl_xor(s, 4);
            s += __shfl_xor(s, 8);
            const float inv = 1.f / s;
            acc[mi][0][reg] = e0 * inv;
            acc[mi][1][reg] = e1 * inv;
            acc[mi][2][reg] = e2 * inv;
            acc[mi][3][reg] = e3 * inv;
        }

    // ---- P -> LDS bf16 [p][k]
#pragma unroll
    for (int mi = 0; mi < 4; ++mi)
#pragma unroll
        for (int ni = 0; ni < 4; ++ni)
#pragma unroll
            for (int reg = 0; reg < 4; ++reg)
                P[(mi * 16 + lg * 4 + reg) * 72 + ni * 16 + lr] = f2bu(acc[mi][ni][reg]);

    // ---- O = P @ V via MFMA
    f32x4 acc2[4][2];
#pragma unroll
    for (int mi = 0; mi < 4; ++mi)
#pragma unroll
        for (int ni = 0; ni < 2; ++ni)
            acc2[mi][ni] = (f32x4){0.f, 0.f, 0.f, 0.f};
#pragma unroll
    for (int ks = 0; ks < 2; ++ks) {
        bf16x8 ap[4], bv2[2];
#pragma unroll
        for (int mi = 0; mi < 4; ++mi)
            ap[mi] = *reinterpret_cast<const bf16x8*>(&P[(mi * 16 + lr) * 72 + ks * 32 + lg * 8]);
#pragma unroll
        for (int ni = 0; ni < 2; ++ni)
            bv2[ni] = *reinterpret_cast<const bf16x8*>(&VT[(ni * 16 + lr) * 72 + ks * 32 + lg * 8]);
#pragma unroll
        for (int mi = 0; mi < 4; ++mi)
#pragma unroll
            for (int ni = 0; ni < 2; ++ni)
                acc2[mi][ni] = __builtin_amdgcn_mfma_f32_16x16x32_bf16(
                    ap[mi], bv2[ni], acc2[mi][ni], 0, 0, 0);
    }
    __builtin_amdgcn_sched_barrier(0);   // keep wc/spa stores below all P reads

    // ---- spa[d][p] bf16, then wc fp32 into dead P region
#pragma unroll
    for (int mi = 0; mi < 4; ++mi)
#pragma unroll
        for (int ni = 0; ni < 2; ++ni)
#pragma unroll
            for (int reg = 0; reg < 4; ++reg) {
                const int p = mi * 16 + lg * 4 + reg;
                if (p < 49)
                    SP[(ni * 16 + lr) * 52 + p] = f2bu(acc2[mi][ni][reg]);
            }
    for (int i = lane; i < 392; i += 64)
        *reinterpret_cast<float4*>(&wcl[i * 4]) =
            *reinterpret_cast<const float4*>(&wcomb[c0 * 49 + i * 4]);

    // ---- combined 7x7 dw conv + 0.25*spa + bsum + v residual; windowed store
    for (int it = 0; it < 4; ++it) {
        const int item = it * 64 + lane;
        if (item < 224) {
            const int d = item / 7, h1 = item - 7 * d;
            const float bsv = bsumg[c0 + d];
            float accw[7];
#pragma unroll
            for (int w1 = 0; w1 < 7; ++w1) {
                const int p = h1 * 7 + w1;
                accw[w1] = fmaf(0.25f, bu2f(SP[d * 52 + p]), bsv + bu2f(VT[d * 72 + p]));
            }
#pragma unroll
            for (int dy = 0; dy < 7; ++dy) {
                const int ry = h1 + dy - 3;
                const bool rok = (ry >= 0) && (ry < 7);
                const int ryc = rok ? ry : 0;
                float xr[7];
#pragma unroll
                for (int i2 = 0; i2 < 7; ++i2) {
                    const float xv = bu2f(X[d * 52 + ryc * 7 + i2]);
                    xr[i2] = rok ? xv : 0.f;
                }
#pragma unroll
                for (int dx = 0; dx < 7; ++dx) {
                    const float wv = wcl[d * 49 + dy * 7 + dx];
#pragma unroll
                    for (int w1 = 0; w1 < 7; ++w1) {
                        const int rx = w1 + dx - 3;
                        if (rx >= 0 && rx < 7) accw[w1] = fmaf(wv, xr[rx], accw[w1]);
                    }
                }
            }
            float* xap = xa + ((size_t)(b * NC + c0 + d)) * NHW + j * 49 + h1 * 7;
#pragma unroll
            for (int w1 = 0; w1 < 7; ++w1) xap[w1] = accw[w1];
        }
    }
}

// ---------------------------------------------------------------------------
// K_t256: plane-major -> k-major bf16 transpose (per batch, 64-n chunks).
// F32IN: src fp32 plane stride NHW (xa). else: src bf16 plane stride 6272 (U).
// dst[(b*3136 + n)][256] bf16, n-order = src's plane order.
// ---------------------------------------------------------------------------
template<bool F32IN>
__launch_bounds__(256)
__global__ void t256(const float* __restrict__ srcF, const unsigned short* __restrict__ srcU,
                     unsigned short* __restrict__ dst)
{
    const int n0 = blockIdx.x * 64;
    const int b = blockIdx.y;
    __shared__ unsigned short lt[64 * 264];
    const int t = threadIdx.x;
    for (int idx = t; idx < 4096; idx += 256) {       // 256c x 16 n-quads
        const int c = idx >> 4, nq = (idx & 15) * 4;
        ushort4 u;
        if (F32IN) {
            const float4 v = *reinterpret_cast<const float4*>(
                &srcF[((size_t)(b * NC) + c) * NHW + n0 + nq]);
            u.x = f2bu(v.x); u.y = f2bu(v.y); u.z = f2bu(v.z); u.w = f2bu(v.w);
        } else {
            u = *reinterpret_cast<const ushort4*>(
                &srcU[((size_t)(b * NC) + c) * 6272 + n0 + nq]);
        }
        lt[(nq + 0) * 264 + c] = u.x;
        lt[(nq + 1) * 264 + c] = u.y;
        lt[(nq + 2) * 264 + c] = u.z;
        lt[(nq + 3) * 264 + c] = u.w;
    }
    __syncthreads();
#pragma unroll
    for (int p = 0; p < 16; ++p) {
        const int idx = p * 256 + t;
        const int row = idx >> 6;             // 0..63
        const int c4 = (idx & 63) * 4;
        *reinterpret_cast<ushort4*>(&dst[((size_t)b * NHW + n0 + row) * 256 + c4]) =
            *reinterpret_cast<const ushort4*>(&lt[row * 264 + c4]);
    }
}

// ---------------------------------------------------------------------------
// K5: per-(b,c)-plane: 3x3 depthwise conv (conv_local) + SiLU on T
// (windowed -> LDS-normal -> stencil -> U bf16, stored IN-PLACE in the first
// half of this plane's T footprint — no cross-block hazard), and in-place
// windowed->normal permute of xa (shortcut for the final GEMM).
// ---------------------------------------------------------------------------
__launch_bounds__(256)
__global__ void dw3_silu(const float* __restrict__ T, const float* __restrict__ wloc,
                         const float* __restrict__ bloc, unsigned short* __restrict__ Uu,
                         float* xa)
{
    const int c = blockIdx.x, b = blockIdx.y;
    const size_t pb = ((size_t)b * NC + c) * NHW;
    __shared__ float pl[56 * 57];        // T, normal order, stride-57 rows
    __shared__ float xpl[3136];          // xa, normal order
    const int tid = threadIdx.x;
    const float4* t4 = reinterpret_cast<const float4*>(T + pb);
    const float4* x4 = reinterpret_cast<const float4*>(xa + pb);
    for (int i = tid; i < 784; i += 256) {
        const float4 tv = t4[i];
        const float4 xv = x4[i];
        const float tt[4] = {tv.x, tv.y, tv.z, tv.w};
        const float xx[4] = {xv.x, xv.y, xv.z, xv.w};
#pragma unroll
        for (int e = 0; e < 4; ++e) {
            const int n = 4 * i + e;
            const int j = n / 49, p = n - 49 * j;
            const int h1 = p / 7, w1 = p - 7 * h1;
            const int h = h1 * 8 + (j >> 3), w = w1 * 8 + (j & 7);
            pl[h * 57 + w] = tt[e];
            xpl[h * 56 + w] = xx[e];
        }
    }
    __syncthreads();

    float wk[9];
#pragma unroll
    for (int k = 0; k < 9; ++k) wk[k] = wloc[c * 9 + k];
    const float bs = bloc[c];
    unsigned short* up = Uu + ((size_t)(b * NC + c)) * 6272;
    for (int i4 = tid; i4 < 784; i4 += 256) {
        ushort4 pk;
        unsigned short* pks = (unsigned short*)&pk;
#pragma unroll
        for (int e = 0; e < 4; ++e) {
            const int i = 4 * i4 + e;
            const int h = i / 56, w = i - 56 * h;
            float acc = bs;
#pragma unroll
            for (int dy = -1; dy <= 1; ++dy) {
                const int hh = h + dy;
                if (hh < 0 || hh >= 56) continue;
#pragma unroll
                for (int dx = -1; dx <= 1; ++dx) {
                    const int ww = w + dx;
                    if (ww < 0 || ww >= 56) continue;
                    acc = fmaf(wk[(dy + 1) * 3 + (dx + 1)], pl[hh * 57 + ww], acc);
                }
            }
            pks[e] = f2bu(acc / (1.f + __expf(-acc)));   // silu
        }
        *reinterpret_cast<ushort4*>(&up[4 * i4]) = pk;
    }

    float4* xo4 = reinterpret_cast<float4*>(xa + pb);
    for (int i = tid; i < 784; i += 256)
        xo4[i] = make_float4(xpl[4 * i], xpl[4 * i + 1], xpl[4 * i + 2], xpl[4 * i + 3]);
}

// ---------------------------------------------------------------------------
// Launch. Workspace layout (floats):
//   [0,512)              : BN affine a[256], b[256]
//   wcomb = W+512        : 256*49
//   bsum  = W+13056      : 256
//   Wb    = W+13312      : 768*256 bf16 qkv weights (98304 fl) -> ends 111616
//   Wfb   = W+111616     : 256*256 bf16 (32768 fl) -> ends 144384
//   Wob   = W+144384     : 256*256 bf16 (32768 fl) -> ends 177152
//   xa    = W+177152     : NA fl — XNt alias (dead after QKV GEMM), attn
//                          output (windowed), NORMAL after K5 (in-place)
//   R     = xa+NA        : 54,525,952 fl shared region:
//     phase 1: QKt us [b][3328][512] (27.26M fl) | Vb (13.63M fl) | XWW (13.63M fl)
//     phase 2: T fp32 NA in QKt region; U bf16 in-place first-half of T planes
//              (plane stride 6272 us = T plane byte size); XAt bf16 in Vb
//              region; Ut bf16 in XWW region.
//   total ~ 321.6 MB
// ---------------------------------------------------------------------------
extern "C" void kernel_launch(void* const* d_in, const int* in_sizes, int n_in,
                              void* d_out, int out_size, void* d_ws, size_t ws_size,
                              hipStream_t stream)
{
    (void)in_sizes; (void)n_in; (void)out_size; (void)ws_size;
    const float* x    = (const float*)d_in[0];
    const float* g    = (const float*)d_in[1];
    const float* be   = (const float*)d_in[2];
    const float* qkvw = (const float*)d_in[3];
    const float* qkvb = (const float*)d_in[4];
    const float* w3   = (const float*)d_in[5];
    const float* b3   = (const float*)d_in[6];
    const float* w5   = (const float*)d_in[7];
    const float* b5   = (const float*)d_in[8];
    const float* w7   = (const float*)d_in[9];
    const float* b7   = (const float*)d_in[10];
    const float* fiw  = (const float*)d_in[11];
    const float* fib  = (const float*)d_in[12];
    const float* clw  = (const float*)d_in[13];
    const float* clb  = (const float*)d_in[14];
    const float* fow  = (const float*)d_in[15];
    const float* fob  = (const float*)d_in[16];
    float* out = (float*)d_out;

    float* W     = (float*)d_ws;
    float* ab    = W;
    float* wcomb = W + 512;
    float* bsum  = W + 13056;
    __hip_bfloat16* Wb  = (__hip_bfloat16*)(W + 13312);
    __hip_bfloat16* Wfb = (__hip_bfloat16*)(W + 111616);
    __hip_bfloat16* Wob = (__hip_bfloat16*)(W + 144384);
    float* xa    = W + 177152;
    unsigned short* XNt = (unsigned short*)xa;              // dead after QKV GEMM
    float* R     = xa + NA;
    unsigned short* QKt = (unsigned short*)R;               // [b][3328][512]
    unsigned short* Vb  = QKt + (size_t)NB * NPW * 512;
    unsigned short* XWW = Vb + (size_t)NB * 256 * NPW;
    float* T = R;                                           // aliases QKt (dead after attn)
    unsigned short* Uu  = (unsigned short*)R;               // in-place half-planes of T
    unsigned short* XAt = Vb;                               // aliases Vb (dead after attn)
    unsigned short* Ut  = XWW;                              // aliases XWW (dead after attn)

    bn_stats<<<dim3(256), dim3(256), 0, stream>>>(x, g, be, w3, b3, w5, b5, w7, b7,
                                                  qkvw, fiw, fow, ab, wcomb, bsum,
                                                  Wb, Wfb, Wob);
    xnt_make2<<<dim3(4, 8, NB), dim3(256), 0, stream>>>(x, ab, XNt, XWW);
    gemm_qkv_mfma<<<dim3(832, 6), dim3(256), 0, stream>>>(
        XNt, (const unsigned short*)Wb, qkvb, QKt, Vb);
    attn_mfma<<<dim3(64, 8, NB), dim3(64), 0, stream>>>(
        QKt, Vb, XWW, wcomb, bsum, xa);
    t256<true><<<dim3(49, NB), dim3(256), 0, stream>>>(xa, nullptr, XAt);
    gemm_ffn_mfma<false><<<dim3(2, 784), dim3(256), 0, stream>>>(
        XAt, (const unsigned short*)Wfb, fib, nullptr, T);
    dw3_silu<<<dim3(256, NB), dim3(256), 0, stream>>>(T, clw, clb, Uu, xa);
    t256<false><<<dim3(49, NB), dim3(256), 0, stream>>>(nullptr, Uu, Ut);
    gemm_ffn_mfma<true><<<dim3(2, 784), dim3(256), 0, stream>>>(
        Ut, (const unsigned short*)Wob, fob, xa, out);
}

// Round 6
// 834.261 us; speedup vs baseline: 2.1520x; 1.0586x over previous
//
#include <hip/hip_runtime.h>
#include <hip/hip_bf16.h>

// Problem constants
#define NB 32
#define NC 256
#define NHW 3136                 // 56*56
#define NA 25690112ull           // NB*NC*NHW elements (one NCHW tensor)
#define NPW 3328                 // padded windowed plane: 64 windows * 52
#define LTS 396                  // xnt_make2 LDS row stride (ushorts, mult of 4)

typedef __attribute__((ext_vector_type(8))) short bf16x8;
typedef __attribute__((ext_vector_type(4))) float f32x4;

// Window mapping: h=h1*8+j1, w=w1*8+j2; j=j1*8+j2 (0..63), p=h1*7+w1 (0..48).
// PADDED windowed linear index n' = j*52 + p (p in [0,52), p>=49 = pad).

static __device__ __forceinline__ unsigned short f2bu(float f) {
    union { __hip_bfloat16 h; unsigned short u; } c;
    c.h = __float2bfloat16(f);
    return c.u;
}
static __device__ __forceinline__ float bu2f(unsigned short us) {
    union { unsigned short u; __hip_bfloat16 h; } c;
    c.u = us;
    return __bfloat162float(c.h);
}

// ---------------------------------------------------------------------------
// K1a: BatchNorm partial sums. Grid (256 c, 8 bq): each block sums 4 batches
// of one channel plane (parallelism 2048 blocks vs old 256).
// ---------------------------------------------------------------------------
__launch_bounds__(256)
__global__ void bn_part(const float* __restrict__ x, float* __restrict__ part)
{
    const int c = blockIdx.x, bq = blockIdx.y;
    const int tid = threadIdx.x;
    float s = 0.f, s2 = 0.f;
    for (int b = bq * 4; b < bq * 4 + 4; ++b) {
        const float4* p = reinterpret_cast<const float4*>(x + ((size_t)b * NC + c) * NHW);
        for (int i = tid; i < 784; i += 256) {
            const float4 v = p[i];
            s += v.x + v.y + v.z + v.w;
            s2 = fmaf(v.x, v.x, s2); s2 = fmaf(v.y, v.y, s2);
            s2 = fmaf(v.z, v.z, s2); s2 = fmaf(v.w, v.w, s2);
        }
    }
    __shared__ float r1[256], r2[256];
    r1[tid] = s; r2[tid] = s2;
    __syncthreads();
    for (int off = 128; off > 0; off >>= 1) {
        if (tid < off) { r1[tid] += r1[tid + off]; r2[tid] += r2[tid + off]; }
        __syncthreads();
    }
    if (tid == 0) {
        part[(c * 8 + bq) * 2] = r1[0];
        part[(c * 8 + bq) * 2 + 1] = r2[0];
    }
}

// ---------------------------------------------------------------------------
// K1b: finalize BN affine (a,b), combined dw weights wcomb = 0.25*(w3+w5+w7),
// bias sum bsum, bf16 copies of qkv/ffn_in/ffn_out weights.
// ---------------------------------------------------------------------------
__launch_bounds__(256)
__global__ void bn_fin(const float* __restrict__ part,
                       const float* __restrict__ gamma, const float* __restrict__ beta,
                       const float* __restrict__ w3, const float* __restrict__ b3,
                       const float* __restrict__ w5, const float* __restrict__ b5,
                       const float* __restrict__ w7, const float* __restrict__ b7,
                       const float* __restrict__ qkvw,
                       const float* __restrict__ fiw, const float* __restrict__ fow,
                       float* __restrict__ ab, float* __restrict__ wcomb,
                       float* __restrict__ bsum, __hip_bfloat16* __restrict__ Wb,
                       __hip_bfloat16* __restrict__ Wfb, __hip_bfloat16* __restrict__ Wob)
{
    const int c = blockIdx.x;
    const int tid = threadIdx.x;

    if (tid < 49) {
        const int ty = tid / 7, tx = tid % 7;
        float wv = w7[c * 49 + tid];
        if (ty >= 1 && ty <= 5 && tx >= 1 && tx <= 5) wv += w5[c * 25 + (ty - 1) * 5 + (tx - 1)];
        if (ty >= 2 && ty <= 4 && tx >= 2 && tx <= 4) wv += w3[c * 9 + (ty - 2) * 3 + (tx - 2)];
        wcomb[c * 49 + tid] = 0.25f * wv;
    }
    if (tid == 63) bsum[c] = 0.25f * (b3[c] + b5[c] + b7[c]);

#pragma unroll
    for (int r = 0; r < 3; ++r) {
        const int o = 3 * c + r;
        Wb[o * 256 + tid] = __float2bfloat16(qkvw[o * 256 + tid]);
    }
    Wfb[c * 256 + tid] = __float2bfloat16(fiw[c * 256 + tid]);
    Wob[c * 256 + tid] = __float2bfloat16(fow[c * 256 + tid]);

    if (tid == 0) {
        float s = 0.f, s2 = 0.f;
#pragma unroll
        for (int q = 0; q < 8; ++q) {
            s += part[(c * 8 + q) * 2];
            s2 += part[(c * 8 + q) * 2 + 1];
        }
        const float inv_n = 1.f / (float)((size_t)NB * NHW);
        const float mean = s * inv_n;
        const float var = s2 * inv_n - mean * mean;
        const float a = gamma[c] / sqrtf(var + 1e-5f);
        ab[c] = a;
        ab[NC + c] = beta[c] - mean * a;
    }
}

// ---------------------------------------------------------------------------
// K1.5: xn = a*x+b applied once; emits PADDED-WINDOWED outputs:
//   XNt bf16 [(b*3328 + n')][c]  (k-contiguous rows for the MFMA GEMM)
//   XWW bf16 [b][c][n']          (padded windowed planes, pads ZEROED)
// ---------------------------------------------------------------------------
__launch_bounds__(256)
__global__ void xnt_make2(const float* __restrict__ x, const float* __restrict__ ab,
                          unsigned short* __restrict__ XNt, unsigned short* __restrict__ XWW)
{
    const int c0 = blockIdx.x * 64;      // channel chunk
    const int j1 = blockIdx.y;           // window row id
    const int b  = blockIdx.z;
    __shared__ unsigned short lt[64 * LTS];   // [c][px], px = h1*56 + w
    __shared__ float aa[64], bb[64];
    const int tid = threadIdx.x;
    if (tid < 64) { aa[tid] = ab[c0 + tid]; bb[tid] = ab[256 + c0 + tid]; }
    __syncthreads();

    // Phase A: load 64c x 7rows x 56w fp32, affine, cvt bf16 -> LDS
    for (int idx = tid; idx < 6272; idx += 256) {       // 64 * 98 float4
        const int c = idx / 98, f = idx - 98 * c;
        const int h1 = f / 14, w4 = (f - 14 * h1) * 4;
        const float4 v = *reinterpret_cast<const float4*>(
            &x[((size_t)(b * NC) + c0 + c) * NHW + (h1 * 8 + j1) * 56 + w4]);
        const float a = aa[c], bv = bb[c];
        union { ushort4 u; __hip_bfloat16 h[4]; } pk;
        pk.h[0] = __float2bfloat16(fmaf(a, v.x, bv));
        pk.h[1] = __float2bfloat16(fmaf(a, v.y, bv));
        pk.h[2] = __float2bfloat16(fmaf(a, v.z, bv));
        pk.h[3] = __float2bfloat16(fmaf(a, v.w, bv));
        *reinterpret_cast<ushort4*>(&lt[c * LTS + h1 * 56 + w4]) = pk.u;
    }
    __syncthreads();

    // Phase B: XWW planes: per (c, j2) one padded window run of 52 (13 ushort4)
    for (int idx = tid; idx < 6656; idx += 256) {       // 64c * 8j2 * 13
        const int c = idx / 104, r = idx - 104 * c;
        const int j2 = r / 13, q4 = (r - 13 * j2) * 4;
        unsigned short tmp[4];
#pragma unroll
        for (int e = 0; e < 4; ++e) {
            const int p = q4 + e;
            if (p < 49) {
                const int h1p = p / 7, w1 = p - 7 * h1p;
                tmp[e] = lt[c * LTS + h1p * 56 + w1 * 8 + j2];
            } else {
                tmp[e] = 0;                              // zero pad (+0.0 bf16)
            }
        }
        ushort4 v; v.x = tmp[0]; v.y = tmp[1]; v.z = tmp[2]; v.w = tmp[3];
        *reinterpret_cast<ushort4*>(
            &XWW[((size_t)(b * NC) + c0 + c) * NPW + (j1 * 8 + j2) * 52 + q4]) = v;
    }

    // Phase C: XNt rows: per (p, j2, c4): 4 channels of one windowed row
    for (int idx = tid; idx < 6272; idx += 256) {       // 49p * 8j2 * 16c4
        const int p = idx >> 7;                          // 0..48
        const int r = idx & 127;
        const int j2 = r >> 4, c4 = (r & 15) * 4;
        const int h1p = p / 7, w1 = p - 7 * h1p;
        const int px = h1p * 56 + w1 * 8 + j2;
        ushort4 v;
        v.x = lt[(c4 + 0) * LTS + px];
        v.y = lt[(c4 + 1) * LTS + px];
        v.z = lt[(c4 + 2) * LTS + px];
        v.w = lt[(c4 + 3) * LTS + px];
        *reinterpret_cast<ushort4*>(
            &XNt[((size_t)b * NPW + (j1 * 8 + j2) * 52 + p) * 256 + c0 + c4]) = v;
    }
}

// ---------------------------------------------------------------------------
// K2: QKV 1x1-conv as bf16 MFMA GEMM. Out[o][nn'] = sum_c Wb[o][c]*XNt[nn'][c].
//   o in [0,512)  (Q,K): QKt[b][n'][512] k-major.
//   o in [512,768) (V):  plane-major Vb[c][n'].
// ---------------------------------------------------------------------------
__launch_bounds__(256)
__global__ void gemm_qkv_mfma(const unsigned short* __restrict__ XNt,
                              const unsigned short* __restrict__ Wb,
                              const float* __restrict__ bias,
                              unsigned short* __restrict__ QKt,
                              unsigned short* __restrict__ Vb)
{
    __shared__ unsigned short As[128 * 72];   // W tile   [o][k]
    __shared__ unsigned short Bs[128 * 72];   // XNt tile [n][k]
    const int t = threadIdx.x;
    const int nn0 = blockIdx.x * 128;
    const int o0 = blockIdx.y * 128;
    const int lane = t & 63;
    const int wid = t >> 6;
    const int lr = lane & 15, lg = lane >> 4;
    const int wo = (wid >> 1) * 64;
    const int wn = (wid & 1) * 64;

    f32x4 acc[4][4];
#pragma unroll
    for (int i = 0; i < 4; ++i)
#pragma unroll
        for (int j = 0; j < 4; ++j)
            acc[i][j] = (f32x4){0.f, 0.f, 0.f, 0.f};

    for (int kt = 0; kt < 4; ++kt) {
        const int k0 = kt * 64;
#pragma unroll
        for (int it = 0; it < 4; ++it) {
            const int idx = it * 256 + t;     // 0..1023
            const int row = idx >> 3;         // 0..127
            const int k8 = (idx & 7) * 8;     // 0..56
            *reinterpret_cast<uint4*>(&As[row * 72 + k8]) =
                *reinterpret_cast<const uint4*>(&Wb[(size_t)(o0 + row) * 256 + k0 + k8]);
            *reinterpret_cast<uint4*>(&Bs[row * 72 + k8]) =
                *reinterpret_cast<const uint4*>(&XNt[(size_t)(nn0 + row) * 256 + k0 + k8]);
        }
        __syncthreads();
#pragma unroll
        for (int ks = 0; ks < 2; ++ks) {
            const int kk = ks * 32 + lg * 8;
            bf16x8 af[4], bfr[4];
#pragma unroll
            for (int i = 0; i < 4; ++i) {
                af[i]  = *reinterpret_cast<const bf16x8*>(&As[(wo + i * 16 + lr) * 72 + kk]);
                bfr[i] = *reinterpret_cast<const bf16x8*>(&Bs[(wn + i * 16 + lr) * 72 + kk]);
            }
#pragma unroll
            for (int i = 0; i < 4; ++i)
#pragma unroll
                for (int j = 0; j < 4; ++j)
                    acc[i][j] = __builtin_amdgcn_mfma_f32_16x16x32_bf16(
                        af[i], bfr[j], acc[i][j], 0, 0, 0);
        }
        __syncthreads();
    }

    // Epilogue: per osub pass, 32 o-rows x 128 n-cols through LDS (aliases As).
    float* Ts = reinterpret_cast<float*>(As);  // 32 x 132 fp32 = 16.5 KB
#pragma unroll
    for (int osub = 0; osub < 4; ++osub) {
        const float4 b4 = *reinterpret_cast<const float4*>(&bias[o0 + wo + osub * 16 + 4 * lg]);
        const int rowb = (wid >> 1) * 16 + 4 * lg;
#pragma unroll
        for (int j = 0; j < 4; ++j) {
            const int col = wn + j * 16 + lr;
            Ts[(rowb + 0) * 132 + col] = acc[osub][j][0] + b4.x;
            Ts[(rowb + 1) * 132 + col] = acc[osub][j][1] + b4.y;
            Ts[(rowb + 2) * 132 + col] = acc[osub][j][2] + b4.z;
            Ts[(rowb + 3) * 132 + col] = acc[osub][j][3] + b4.w;
        }
        __syncthreads();
        if (o0 < 512) {
            // Q/K: k-major QKt[b][n'][512], transposed read of Ts columns
#pragma unroll
            for (int p = 0; p < 4; ++p) {
                const int item = p * 256 + t;     // 0..1023
                const int n = item >> 3;          // 0..127
                const int half = (item >> 2) & 1;
                const int o4 = (item & 3) * 4;
                union { ushort4 u; __hip_bfloat16 h[4]; } pk;
#pragma unroll
                for (int e = 0; e < 4; ++e)
                    pk.h[e] = __float2bfloat16(Ts[(half * 16 + o4 + e) * 132 + n]);
                const int nn = nn0 + n;
                const int bb2 = nn / NPW;
                const int np = nn - bb2 * NPW;
                const int o = o0 + half * 64 + osub * 16 + o4;
                *reinterpret_cast<ushort4*>(&QKt[((size_t)bb2 * NPW + np) * 512 + o]) = pk.u;
            }
        } else {
            // V: plane-major [c][n'] (c = o-512)
#pragma unroll
            for (int p = 0; p < 4; ++p) {
                const int idx = p * 256 + t;      // 0..1023
                const int row = idx >> 5;         // 0..31
                const int c4 = (idx & 31) * 4;    // 0..124
                const float4 v = *reinterpret_cast<const float4*>(&Ts[row * 132 + c4]);
                const int o = o0 + (row >> 4) * 64 + osub * 16 + (row & 15);
                const int nn = nn0 + c4;
                const int bb2 = nn / NPW;
                const int n = nn - bb2 * NPW;     // padded-windowed n'
                union { ushort4 u; __hip_bfloat16 h[4]; } pk;
                pk.h[0] = __float2bfloat16(v.x);
                pk.h[1] = __float2bfloat16(v.y);
                pk.h[2] = __float2bfloat16(v.z);
                pk.h[3] = __float2bfloat16(v.w);
                *reinterpret_cast<ushort4*>(&Vb[((size_t)bb2 * 256 + (o - 512)) * NPW + n]) = pk.u;
            }
        }
        __syncthreads();
    }
}

// ---------------------------------------------------------------------------
// K4/K6: FFN 1x1-conv as bf16 MFMA GEMM (K=256, O=256). B = k-major bf16
// activations [(b*3136+n)][256], n NORMAL order. OUTBF16: write bf16 plane-
// major (T). else fp32 plane-major with optional fp32 shortcut add.
// ---------------------------------------------------------------------------
template<bool RES, bool OUTBF16>
__launch_bounds__(256)
__global__ void gemm_ffn_mfma(const unsigned short* __restrict__ Bt,
                              const unsigned short* __restrict__ Wb2,
                              const float* __restrict__ bias,
                              const float* __restrict__ res, float* __restrict__ outF,
                              unsigned short* __restrict__ outU)
{
    __shared__ unsigned short As[128 * 72];   // W tile [o][k]
    __shared__ unsigned short Bs[128 * 72];   // act tile [n][k]
    const int t = threadIdx.x;
    const int o0 = blockIdx.x * 128;
    const int nn0 = blockIdx.y * 128;
    const int lane = t & 63;
    const int wid = t >> 6;
    const int lr = lane & 15, lg = lane >> 4;
    const int wo = (wid >> 1) * 64;
    const int wn = (wid & 1) * 64;

    f32x4 acc[4][4];
#pragma unroll
    for (int i = 0; i < 4; ++i)
#pragma unroll
        for (int j = 0; j < 4; ++j)
            acc[i][j] = (f32x4){0.f, 0.f, 0.f, 0.f};

    for (int kt = 0; kt < 4; ++kt) {
        const int k0 = kt * 64;
#pragma unroll
        for (int it = 0; it < 4; ++it) {
            const int idx = it * 256 + t;
            const int row = idx >> 3;
            const int k8 = (idx & 7) * 8;
            *reinterpret_cast<uint4*>(&As[row * 72 + k8]) =
                *reinterpret_cast<const uint4*>(&Wb2[(size_t)(o0 + row) * 256 + k0 + k8]);
            *reinterpret_cast<uint4*>(&Bs[row * 72 + k8]) =
                *reinterpret_cast<const uint4*>(&Bt[(size_t)(nn0 + row) * 256 + k0 + k8]);
        }
        __syncthreads();
#pragma unroll
        for (int ks = 0; ks < 2; ++ks) {
            const int kk = ks * 32 + lg * 8;
            bf16x8 af[4], bfr[4];
#pragma unroll
            for (int i = 0; i < 4; ++i) {
                af[i]  = *reinterpret_cast<const bf16x8*>(&As[(wo + i * 16 + lr) * 72 + kk]);
                bfr[i] = *reinterpret_cast<const bf16x8*>(&Bs[(wn + i * 16 + lr) * 72 + kk]);
            }
#pragma unroll
            for (int i = 0; i < 4; ++i)
#pragma unroll
                for (int j = 0; j < 4; ++j)
                    acc[i][j] = __builtin_amdgcn_mfma_f32_16x16x32_bf16(
                        af[i], bfr[j], acc[i][j], 0, 0, 0);
        }
        __syncthreads();
    }

    float* Ts = reinterpret_cast<float*>(As);  // 32 x 132 fp32
#pragma unroll
    for (int osub = 0; osub < 4; ++osub) {
        const float4 b4 = *reinterpret_cast<const float4*>(&bias[o0 + wo + osub * 16 + 4 * lg]);
        const int rowb = (wid >> 1) * 16 + 4 * lg;
#pragma unroll
        for (int j = 0; j < 4; ++j) {
            const int col = wn + j * 16 + lr;
            Ts[(rowb + 0) * 132 + col] = acc[osub][j][0] + b4.x;
            Ts[(rowb + 1) * 132 + col] = acc[osub][j][1] + b4.y;
            Ts[(rowb + 2) * 132 + col] = acc[osub][j][2] + b4.z;
            Ts[(rowb + 3) * 132 + col] = acc[osub][j][3] + b4.w;
        }
        __syncthreads();
#pragma unroll
        for (int p = 0; p < 4; ++p) {
            const int idx = p * 256 + t;      // 0..1023
            const int row = idx >> 5;         // 0..31
            const int c4 = (idx & 31) * 4;    // 0..124
            float4 v = *reinterpret_cast<const float4*>(&Ts[row * 132 + c4]);
            const int o = o0 + (row >> 4) * 64 + osub * 16 + (row & 15);
            const int nn = nn0 + c4;
            const int b2 = nn / NHW;
            const int n = nn - b2 * NHW;      // float4 never straddles (NHW%4==0)
            const size_t po = ((size_t)(b2 * NC + o)) * NHW + n;
            if (OUTBF16) {
                union { ushort4 u; __hip_bfloat16 h[4]; } pk;
                pk.h[0] = __float2bfloat16(v.x);
                pk.h[1] = __float2bfloat16(v.y);
                pk.h[2] = __float2bfloat16(v.z);
                pk.h[3] = __float2bfloat16(v.w);
                *reinterpret_cast<ushort4*>(&outU[po]) = pk.u;
            } else {
                if (RES) {
                    const float4 rv = *reinterpret_cast<const float4*>(&res[po]);
                    v.x += rv.x; v.y += rv.y; v.z += rv.z; v.w += rv.w;
                }
                *reinterpret_cast<float4*>(&outF[po]) = v;
            }
        }
        __syncthreads();
    }
}

// ---------------------------------------------------------------------------
// K3: MFMA attention. ONE WAVE per (window, head), 64-thread blocks, zero
// barriers. Q/K MFMA fragments loaded DIRECTLY from global k-major QKt (the
// address pattern IS the fragment layout); V/X loads issued early into regs
// (T14) and written to LDS under the softmax. Garbage in QKt pad rows is
// provably masked: softmax reads only valid key cols; e3=0 zeroes P cols
// 49..63; garbage query rows only pollute discarded D rows (MFMA row-local).
// LDS 17920 B: P[64][80] @0 (16B rows); VT[32][68] @10240 (b64-read pairs);
// X[32][52] @14592. wcl [0,6272) + SP [6272,9600) overlay dead P post-PV.
// -> 9 blocks/CU (was 8).
// ---------------------------------------------------------------------------
__launch_bounds__(64)
__global__ void attn_mfma(const unsigned short* __restrict__ QKt,
                          const unsigned short* __restrict__ Vb,
                          const unsigned short* __restrict__ XWW,
                          const float* __restrict__ wcomb,
                          const float* __restrict__ bsumg,
                          float* __restrict__ xa)
{
    const int j = blockIdx.x;            // window id 0..63
    const int head = blockIdx.y;         // 0..7
    const int b = blockIdx.z;
    const int c0 = head * 32;
    const int lane = threadIdx.x;
    const int lr = lane & 15, lg = lane >> 4;

    __shared__ __align__(16) char smem[17920];
    unsigned short* P  = (unsigned short*)smem;             // [64][80]
    float*          wcl = (float*)smem;                     // [1568] post-PV alias
    unsigned short* SP = (unsigned short*)(smem + 6272);    // [32][52] post-PV alias
    unsigned short* VT = (unsigned short*)(smem + 10240);   // [32][68]
    unsigned short* X  = (unsigned short*)(smem + 14592);   // [32][52]

    // ---- early global loads: Q/K fragments (direct) + V/X rows into regs
    const size_t qkbase = ((size_t)b * NPW + j * 52) * 512 + c0 + lg * 8;
    uint4 aqr[4], bkr[4];
#pragma unroll
    for (int mi = 0; mi < 4; ++mi) {
        const unsigned short* rp = QKt + qkbase + (size_t)(mi * 16 + lr) * 512;
        aqr[mi] = *reinterpret_cast<const uint4*>(rp);
        bkr[mi] = *reinterpret_cast<const uint4*>(rp + 256);
    }
    const int dd = lane >> 1;                    // V/X row 0..31
    const int qn = (lane & 1) ? 6 : 7;           // chunks per lane
    const int qb = (lane & 1) * 7;               // chunk base
    const size_t pbase = ((size_t)(b * NC) + c0 + dd) * NPW + j * 52;
    ushort4 uvr[7], uxr[7];
#pragma unroll
    for (int ii = 0; ii < 7; ++ii)
        if (ii < qn) {
            const int q4 = (qb + ii) * 4;
            uvr[ii] = *reinterpret_cast<const ushort4*>(&Vb[pbase + q4]);
            uxr[ii] = *reinterpret_cast<const ushort4*>(&XWW[pbase + q4]);
        }

    // ---- S = Q^T K via MFMA (fp32 accum), fragments straight from global
    f32x4 acc[4][4];
#pragma unroll
    for (int mi = 0; mi < 4; ++mi)
#pragma unroll
        for (int ni = 0; ni < 4; ++ni)
            acc[mi][ni] = (f32x4){0.f, 0.f, 0.f, 0.f};
    {
        union { uint4 u; bf16x8 v; } ca, cb;
#pragma unroll
        for (int mi = 0; mi < 4; ++mi)
#pragma unroll
            for (int ni = 0; ni < 4; ++ni) {
                ca.u = aqr[mi]; cb.u = bkr[ni];
                acc[mi][ni] = __builtin_amdgcn_mfma_f32_16x16x32_bf16(
                    ca.v, cb.v, acc[mi][ni], 0, 0, 0);
            }
    }

    // ---- V/X -> LDS (scheduled under softmax); v-residual + pad masking
#pragma unroll
    for (int ii = 0; ii < 7; ++ii)
        if (ii < qn) {
            const int q4 = (qb + ii) * 4;
            union { ushort4 u; unsigned short s[4]; } uo;
            const unsigned short* vs = (const unsigned short*)&uvr[ii];
            const unsigned short* xs2 = (const unsigned short*)&uxr[ii];
#pragma unroll
            for (int e = 0; e < 4; ++e) {
                const float vv = bu2f(vs[e]) + bu2f(xs2[e]);
                uo.s[e] = (q4 + e >= 49) ? (unsigned short)0 : f2bu(vv);
            }
            *reinterpret_cast<ushort4*>(&VT[dd * 68 + q4]) = uo.u;
            *reinterpret_cast<ushort4*>(&X[dd * 52 + q4]) = uxr[ii];
        }
    if (lane & 1) {                       // zero VT cols 52..63 (PV K-pad)
        ushort4 z; z.x = 0; z.y = 0; z.z = 0; z.w = 0;
        *reinterpret_cast<ushort4*>(&VT[dd * 68 + 52]) = z;
        *reinterpret_cast<ushort4*>(&VT[dd * 68 + 56]) = z;
        *reinterpret_cast<ushort4*>(&VT[dd * 68 + 60]) = z;
    }

    // ---- softmax in registers. Row r = mi*16+lg*4+reg spans 16 lanes;
    // cols per lane: lr, 16+lr, 32+lr (valid), 48+lr (valid iff lr==0).
    const float sc = 0.17677669529663687f;
#pragma unroll
    for (int mi = 0; mi < 4; ++mi)
#pragma unroll
        for (int reg = 0; reg < 4; ++reg) {
            const float v0 = acc[mi][0][reg] * sc;
            const float v1 = acc[mi][1][reg] * sc;
            const float v2 = acc[mi][2][reg] * sc;
            const float v3 = acc[mi][3][reg] * sc;
            float m = fmaxf(fmaxf(v0, v1), v2);
            if (lr == 0) m = fmaxf(m, v3);
            m = fmaxf(m, __shfl_xor(m, 1));
            m = fmaxf(m, __shfl_xor(m, 2));
            m = fmaxf(m, __shfl_xor(m, 4));
            m = fmaxf(m, __shfl_xor(m, 8));
            const float e0 = __expf(v0 - m), e1 = __expf(v1 - m), e2 = __expf(v2 - m);
            const float e3 = (lr == 0) ? __expf(v3 - m) : 0.f;
            float s = e0 + e1 + e2 + e3;
            s += __shfl_xor(s, 1);
            s += __shfl_xor(s, 2);
            s += __shfl_xor(s, 4);
            s += __shfl_xor(s, 8);
            const float inv = 1.f / s;
            acc[mi][0][reg] = e0 * inv;
            acc[mi][1][reg] = e1 * inv;
            acc[mi][2][reg] = e2 * inv;
            acc[mi][3][reg] = e3 * inv;
        }

    // ---- P -> LDS bf16 [p][k], stride 80
#pragma unroll
    for (int mi = 0; mi < 4; ++mi)
#pragma unroll
        for (int ni = 0; ni < 4; ++ni)
#pragma unroll
            for (int reg = 0; reg < 4; ++reg)
                P[(mi * 16 + lg * 4 + reg) * 80 + ni * 16 + lr] = f2bu(acc[mi][ni][reg]);

    // ---- O = P @ V via MFMA (K-dim 64, 2 steps); VT rows via 2x b64
    f32x4 acc2[4][2];
#pragma unroll
    for (int mi = 0; mi < 4; ++mi)
#pragma unroll
        for (int ni = 0; ni < 2; ++ni)
            acc2[mi][ni] = (f32x4){0.f, 0.f, 0.f, 0.f};
#pragma unroll
    for (int ks = 0; ks < 2; ++ks) {
        bf16x8 ap[4];
#pragma unroll
        for (int mi = 0; mi < 4; ++mi)
            ap[mi] = *reinterpret_cast<const bf16x8*>(&P[(mi * 16 + lr) * 80 + ks * 32 + lg * 8]);
        bf16x8 bv2[2];
#pragma unroll
        for (int ni = 0; ni < 2; ++ni) {
            union { uint2 u[2]; bf16x8 v; } cv;
            cv.u[0] = *reinterpret_cast<const uint2*>(&VT[(ni * 16 + lr) * 68 + ks * 32 + lg * 8]);
            cv.u[1] = *reinterpret_cast<const uint2*>(&VT[(ni * 16 + lr) * 68 + ks * 32 + lg * 8 + 4]);
            bv2[ni] = cv.v;
        }
#pragma unroll
        for (int mi = 0; mi < 4; ++mi)
#pragma unroll
            for (int ni = 0; ni < 2; ++ni)
                acc2[mi][ni] = __builtin_amdgcn_mfma_f32_16x16x32_bf16(
                    ap[mi], bv2[ni], acc2[mi][ni], 0, 0, 0);
    }
    __builtin_amdgcn_sched_barrier(0);   // keep wcl/SP stores below all P reads

    // ---- spa[d][p] bf16, then wcl fp32 into dead P region
#pragma unroll
    for (int mi = 0; mi < 4; ++mi)
#pragma unroll
        for (int ni = 0; ni < 2; ++ni)
#pragma unroll
            for (int reg = 0; reg < 4; ++reg) {
                const int p = mi * 16 + lg * 4 + reg;
                if (p < 49)
                    SP[(ni * 16 + lr) * 52 + p] = f2bu(acc2[mi][ni][reg]);
            }
    for (int i = lane; i < 392; i += 64)
        *reinterpret_cast<float4*>(&wcl[i * 4]) =
            *reinterpret_cast<const float4*>(&wcomb[c0 * 49 + i * 4]);

    // ---- combined 7x7 dw conv + 0.25*spa + bsum + v residual; NORMAL store
    const int j1 = j >> 3, j2 = j & 7;
    for (int it = 0; it < 4; ++it) {
        const int item = it * 64 + lane;
        if (item < 224) {
            const int d = item / 7, h1 = item - 7 * d;
            const float bsv = bsumg[c0 + d];
            float accw[7];
#pragma unroll
            for (int w1 = 0; w1 < 7; ++w1) {
                const int p = h1 * 7 + w1;
                accw[w1] = fmaf(0.25f, bu2f(SP[d * 52 + p]), bsv + bu2f(VT[d * 68 + p]));
            }
#pragma unroll
            for (int dy = 0; dy < 7; ++dy) {
                const int ry = h1 + dy - 3;
                const bool rok = (ry >= 0) && (ry < 7);
                const int ryc = rok ? ry : 0;
                float xr[7];
#pragma unroll
                for (int i2 = 0; i2 < 7; ++i2) {
                    const float xv = bu2f(X[d * 52 + ryc * 7 + i2]);
                    xr[i2] = rok ? xv : 0.f;
                }
#pragma unroll
                for (int dx = 0; dx < 7; ++dx) {
                    const float wv = wcl[d * 49 + dy * 7 + dx];
#pragma unroll
                    for (int w1 = 0; w1 < 7; ++w1) {
                        const int rx = w1 + dx - 3;
                        if (rx >= 0 && rx < 7) accw[w1] = fmaf(wv, xr[rx], accw[w1]);
                    }
                }
            }
            float* xap = xa + ((size_t)(b * NC + c0 + d)) * NHW + (h1 * 8 + j1) * 56 + j2;
#pragma unroll
            for (int w1 = 0; w1 < 7; ++w1) xap[w1 * 8] = accw[w1];
        }
    }
}

// ---------------------------------------------------------------------------
// K_t256: plane-major -> k-major bf16 transpose (per batch, 64-n chunks).
// F32IN: src fp32 plane stride NHW (xa, normal). else: src bf16 stride NHW (U).
// dst[(b*3136 + n)][256] bf16, n NORMAL order.
// ---------------------------------------------------------------------------
template<bool F32IN>
__launch_bounds__(256)
__global__ void t256(const float* __restrict__ srcF, const unsigned short* __restrict__ srcU,
                     unsigned short* __restrict__ dst)
{
    const int n0 = blockIdx.x * 64;
    const int b = blockIdx.y;
    __shared__ unsigned short lt[64 * 264];
    const int t = threadIdx.x;
    for (int idx = t; idx < 4096; idx += 256) {       // 256c x 16 n-quads
        const int c = idx >> 4, nq = (idx & 15) * 4;
        ushort4 u;
        if (F32IN) {
            const float4 v = *reinterpret_cast<const float4*>(
                &srcF[((size_t)(b * NC) + c) * NHW + n0 + nq]);
            u.x = f2bu(v.x); u.y = f2bu(v.y); u.z = f2bu(v.z); u.w = f2bu(v.w);
        } else {
            u = *reinterpret_cast<const ushort4*>(
                &srcU[((size_t)(b * NC) + c) * NHW + n0 + nq]);
        }
        lt[(nq + 0) * 264 + c] = u.x;
        lt[(nq + 1) * 264 + c] = u.y;
        lt[(nq + 2) * 264 + c] = u.z;
        lt[(nq + 3) * 264 + c] = u.w;
    }
    __syncthreads();
#pragma unroll
    for (int p = 0; p < 16; ++p) {
        const int idx = p * 256 + t;
        const int row = idx >> 6;             // 0..63
        const int c4 = (idx & 63) * 4;
        *reinterpret_cast<ushort4*>(&dst[((size_t)b * NHW + n0 + row) * 256 + c4]) =
            *reinterpret_cast<const ushort4*>(&lt[row * 264 + c4]);
    }
}

// ---------------------------------------------------------------------------
// K5: per-(b,c)-plane: 3x3 depthwise conv (conv_local) + SiLU.
// T is bf16 NORMAL order now -> direct stage (no permute), stencil, U bf16.
// No xa handling (attn writes xa normal directly). LDS 12.8KB -> 12 blocks/CU.
// ---------------------------------------------------------------------------
__launch_bounds__(256)
__global__ void dw3_silu(const unsigned short* __restrict__ T, const float* __restrict__ wloc,
                         const float* __restrict__ bloc, unsigned short* __restrict__ Uu)
{
    const int c = blockIdx.x, b = blockIdx.y;
    const size_t pb = ((size_t)b * NC + c) * NHW;
    __shared__ float pl[56 * 57];        // normal order, stride-57 rows
    const int tid = threadIdx.x;
    const ushort4* t4 = reinterpret_cast<const ushort4*>(T + pb);
    for (int i = tid; i < 784; i += 256) {
        const ushort4 tv = t4[i];
        const int n = 4 * i;
        const int h = n / 56, w = n - 56 * h;    // quad never straddles rows
        pl[h * 57 + w] = bu2f(tv.x);
        pl[h * 57 + w + 1] = bu2f(tv.y);
        pl[h * 57 + w + 2] = bu2f(tv.z);
        pl[h * 57 + w + 3] = bu2f(tv.w);
    }
    __syncthreads();

    float wk[9];
#pragma unroll
    for (int k = 0; k < 9; ++k) wk[k] = wloc[c * 9 + k];
    const float bs = bloc[c];
    unsigned short* up = Uu + pb;
    for (int i4 = tid; i4 < 784; i4 += 256) {
        ushort4 pk;
        unsigned short* pks = (unsigned short*)&pk;
#pragma unroll
        for (int e = 0; e < 4; ++e) {
            const int i = 4 * i4 + e;
            const int h = i / 56, w = i - 56 * h;
            float acc = bs;
#pragma unroll
            for (int dy = -1; dy <= 1; ++dy) {
                const int hh = h + dy;
                if (hh < 0 || hh >= 56) continue;
#pragma unroll
                for (int dx = -1; dx <= 1; ++dx) {
                    const int ww = w + dx;
                    if (ww < 0 || ww >= 56) continue;
                    acc = fmaf(wk[(dy + 1) * 3 + (dx + 1)], pl[hh * 57 + ww], acc);
                }
            }
            pks[e] = f2bu(acc / (1.f + __expf(-acc)));   // silu
        }
        *reinterpret_cast<ushort4*>(&up[4 * i4]) = pk;
    }
}

// ---------------------------------------------------------------------------
// Launch. Workspace layout (floats):
//   [0,512)              : BN affine a[256], b[256]
//   wcomb = W+512        : 256*49
//   bsum  = W+13056      : 256
//   part  = W+13312      : 256*8*2 partial BN sums -> ends 17408
//   Wb    = W+17408      : 768*256 bf16 (98304 fl) -> ends 115712
//   Wfb   = W+115712     : 256*256 bf16 (32768 fl) -> ends 148480
//   Wob   = W+148480     : 256*256 bf16 (32768 fl) -> ends 181248
//   xa    = W+181248     : NA fl — XNt alias (dead after QKV GEMM), then attn
//                          output in NORMAL fp32 layout (shortcut for ffn2)
//   R     = xa+NA        : 54,525,952 fl shared region:
//     phase 1: QKt us [b][3328][512] | Vb planes | XWW planes
//     phase 2: T bf16 NA us + Uu bf16 NA us (both in QKt's 54.5M-us region);
//              XAt in Vb region; Ut in XWW region.
//   total ~ 321.6 MB
// ---------------------------------------------------------------------------
extern "C" void kernel_launch(void* const* d_in, const int* in_sizes, int n_in,
                              void* d_out, int out_size, void* d_ws, size_t ws_size,
                              hipStream_t stream)
{
    (void)in_sizes; (void)n_in; (void)out_size; (void)ws_size;
    const float* x    = (const float*)d_in[0];
    const float* g    = (const float*)d_in[1];
    const float* be   = (const float*)d_in[2];
    const float* qkvw = (const float*)d_in[3];
    const float* qkvb = (const float*)d_in[4];
    const float* w3   = (const float*)d_in[5];
    const float* b3   = (const float*)d_in[6];
    const float* w5   = (const float*)d_in[7];
    const float* b5   = (const float*)d_in[8];
    const float* w7   = (const float*)d_in[9];
    const float* b7   = (const float*)d_in[10];
    const float* fiw  = (const float*)d_in[11];
    const float* fib  = (const float*)d_in[12];
    const float* clw  = (const float*)d_in[13];
    const float* clb  = (const float*)d_in[14];
    const float* fow  = (const float*)d_in[15];
    const float* fob  = (const float*)d_in[16];
    float* out = (float*)d_out;

    float* W     = (float*)d_ws;
    float* ab    = W;
    float* wcomb = W + 512;
    float* bsum  = W + 13056;
    float* part  = W + 13312;
    __hip_bfloat16* Wb  = (__hip_bfloat16*)(W + 17408);
    __hip_bfloat16* Wfb = (__hip_bfloat16*)(W + 115712);
    __hip_bfloat16* Wob = (__hip_bfloat16*)(W + 148480);
    float* xa    = W + 181248;
    unsigned short* XNt = (unsigned short*)xa;              // dead after QKV GEMM
    float* R     = xa + NA;
    unsigned short* QKt = (unsigned short*)R;               // [b][3328][512]
    unsigned short* Vb  = QKt + (size_t)NB * NPW * 512;
    unsigned short* XWW = Vb + (size_t)NB * 256 * NPW;
    unsigned short* T   = (unsigned short*)R;               // bf16 NA, in QKt region
    unsigned short* Uu  = T + NA;                           // bf16 NA, in QKt region
    unsigned short* XAt = Vb;                               // aliases Vb (dead)
    unsigned short* Ut  = XWW;                              // aliases XWW (dead)

    bn_part<<<dim3(256, 8), dim3(256), 0, stream>>>(x, part);
    bn_fin<<<dim3(256), dim3(256), 0, stream>>>(part, g, be, w3, b3, w5, b5, w7, b7,
                                                qkvw, fiw, fow, ab, wcomb, bsum,
                                                Wb, Wfb, Wob);
    xnt_make2<<<dim3(4, 8, NB), dim3(256), 0, stream>>>(x, ab, XNt, XWW);
    gemm_qkv_mfma<<<dim3(832, 6), dim3(256), 0, stream>>>(
        XNt, (const unsigned short*)Wb, qkvb, QKt, Vb);
    attn_mfma<<<dim3(64, 8, NB), dim3(64), 0, stream>>>(
        QKt, Vb, XWW, wcomb, bsum, xa);
    t256<true><<<dim3(49, NB), dim3(256), 0, stream>>>(xa, nullptr, XAt);
    gemm_ffn_mfma<false, true><<<dim3(2, 784), dim3(256), 0, stream>>>(
        XAt, (const unsigned short*)Wfb, fib, nullptr, nullptr, T);
    dw3_silu<<<dim3(256, NB), dim3(256), 0, stream>>>(T, clw, clb, Uu);
    t256<false><<<dim3(49, NB), dim3(256), 0, stream>>>(nullptr, Uu, Ut);
    gemm_ffn_mfma<true, false><<<dim3(2, 784), dim3(256), 0, stream>>>(
        Ut, (const unsigned short*)Wob, fob, xa, out, nullptr);
}

// Round 7
// 792.447 us; speedup vs baseline: 2.2656x; 1.0528x over previous
//
#include <hip/hip_runtime.h>
#include <hip/hip_bf16.h>

// Problem constants
#define NB 32
#define NC 256
#define NHW 3136                 // 56*56
#define NA 25690112ull           // NB*NC*NHW elements (one NCHW tensor)
#define NPW 3328                 // padded windowed plane: 64 windows * 52
#define LTS 396                  // xnt_make2 LDS row stride (ushorts, mult of 4)

typedef __attribute__((ext_vector_type(8))) short bf16x8;
typedef __attribute__((ext_vector_type(4))) float f32x4;

// Window mapping: h=h1*8+j1, w=w1*8+j2; j=j1*8+j2 (0..63), p=h1*7+w1 (0..48).
// PADDED windowed linear index n' = j*52 + p (p in [0,52), p>=49 = pad).

static __device__ __forceinline__ unsigned short f2bu(float f) {
    union { __hip_bfloat16 h; unsigned short u; } c;
    c.h = __float2bfloat16(f);
    return c.u;
}
static __device__ __forceinline__ float bu2f(unsigned short us) {
    union { unsigned short u; __hip_bfloat16 h; } c;
    c.u = us;
    return __bfloat162float(c.h);
}

// ---------------------------------------------------------------------------
// K1a: BatchNorm partial sums. Grid (256 c, 8 bq).
// ---------------------------------------------------------------------------
__launch_bounds__(256)
__global__ void bn_part(const float* __restrict__ x, float* __restrict__ part)
{
    const int c = blockIdx.x, bq = blockIdx.y;
    const int tid = threadIdx.x;
    float s = 0.f, s2 = 0.f;
    for (int b = bq * 4; b < bq * 4 + 4; ++b) {
        const float4* p = reinterpret_cast<const float4*>(x + ((size_t)b * NC + c) * NHW);
        for (int i = tid; i < 784; i += 256) {
            const float4 v = p[i];
            s += v.x + v.y + v.z + v.w;
            s2 = fmaf(v.x, v.x, s2); s2 = fmaf(v.y, v.y, s2);
            s2 = fmaf(v.z, v.z, s2); s2 = fmaf(v.w, v.w, s2);
        }
    }
    __shared__ float r1[256], r2[256];
    r1[tid] = s; r2[tid] = s2;
    __syncthreads();
    for (int off = 128; off > 0; off >>= 1) {
        if (tid < off) { r1[tid] += r1[tid + off]; r2[tid] += r2[tid + off]; }
        __syncthreads();
    }
    if (tid == 0) {
        part[(c * 8 + bq) * 2] = r1[0];
        part[(c * 8 + bq) * 2 + 1] = r2[0];
    }
}

// ---------------------------------------------------------------------------
// K1b: finalize BN affine (a,b), combined dw weights, bias sum, bf16 weights.
// ---------------------------------------------------------------------------
__launch_bounds__(256)
__global__ void bn_fin(const float* __restrict__ part,
                       const float* __restrict__ gamma, const float* __restrict__ beta,
                       const float* __restrict__ w3, const float* __restrict__ b3,
                       const float* __restrict__ w5, const float* __restrict__ b5,
                       const float* __restrict__ w7, const float* __restrict__ b7,
                       const float* __restrict__ qkvw,
                       const float* __restrict__ fiw, const float* __restrict__ fow,
                       float* __restrict__ ab, float* __restrict__ wcomb,
                       float* __restrict__ bsum, __hip_bfloat16* __restrict__ Wb,
                       __hip_bfloat16* __restrict__ Wfb, __hip_bfloat16* __restrict__ Wob)
{
    const int c = blockIdx.x;
    const int tid = threadIdx.x;

    if (tid < 49) {
        const int ty = tid / 7, tx = tid % 7;
        float wv = w7[c * 49 + tid];
        if (ty >= 1 && ty <= 5 && tx >= 1 && tx <= 5) wv += w5[c * 25 + (ty - 1) * 5 + (tx - 1)];
        if (ty >= 2 && ty <= 4 && tx >= 2 && tx <= 4) wv += w3[c * 9 + (ty - 2) * 3 + (tx - 2)];
        wcomb[c * 49 + tid] = 0.25f * wv;
    }
    if (tid == 63) bsum[c] = 0.25f * (b3[c] + b5[c] + b7[c]);

#pragma unroll
    for (int r = 0; r < 3; ++r) {
        const int o = 3 * c + r;
        Wb[o * 256 + tid] = __float2bfloat16(qkvw[o * 256 + tid]);
    }
    Wfb[c * 256 + tid] = __float2bfloat16(fiw[c * 256 + tid]);
    Wob[c * 256 + tid] = __float2bfloat16(fow[c * 256 + tid]);

    if (tid == 0) {
        float s = 0.f, s2 = 0.f;
#pragma unroll
        for (int q = 0; q < 8; ++q) {
            s += part[(c * 8 + q) * 2];
            s2 += part[(c * 8 + q) * 2 + 1];
        }
        const float inv_n = 1.f / (float)((size_t)NB * NHW);
        const float mean = s * inv_n;
        const float var = s2 * inv_n - mean * mean;
        const float a = gamma[c] / sqrtf(var + 1e-5f);
        ab[c] = a;
        ab[NC + c] = beta[c] - mean * a;
    }
}

// ---------------------------------------------------------------------------
// K1.5: xn = a*x+b applied once; emits PADDED-WINDOWED outputs:
//   XNt bf16 [(b*3328 + n')][c]  (k-contiguous rows for the MFMA GEMM)
//   XWW bf16 [b][c][n']          (padded windowed planes, pads ZEROED)
// ---------------------------------------------------------------------------
__launch_bounds__(256)
__global__ void xnt_make2(const float* __restrict__ x, const float* __restrict__ ab,
                          unsigned short* __restrict__ XNt, unsigned short* __restrict__ XWW)
{
    const int c0 = blockIdx.x * 64;      // channel chunk
    const int j1 = blockIdx.y;           // window row id
    const int b  = blockIdx.z;
    __shared__ unsigned short lt[64 * LTS];   // [c][px], px = h1*56 + w
    __shared__ float aa[64], bb[64];
    const int tid = threadIdx.x;
    if (tid < 64) { aa[tid] = ab[c0 + tid]; bb[tid] = ab[256 + c0 + tid]; }
    __syncthreads();

    // Phase A: load 64c x 7rows x 56w fp32, affine, cvt bf16 -> LDS
    for (int idx = tid; idx < 6272; idx += 256) {       // 64 * 98 float4
        const int c = idx / 98, f = idx - 98 * c;
        const int h1 = f / 14, w4 = (f - 14 * h1) * 4;
        const float4 v = *reinterpret_cast<const float4*>(
            &x[((size_t)(b * NC) + c0 + c) * NHW + (h1 * 8 + j1) * 56 + w4]);
        const float a = aa[c], bv = bb[c];
        union { ushort4 u; __hip_bfloat16 h[4]; } pk;
        pk.h[0] = __float2bfloat16(fmaf(a, v.x, bv));
        pk.h[1] = __float2bfloat16(fmaf(a, v.y, bv));
        pk.h[2] = __float2bfloat16(fmaf(a, v.z, bv));
        pk.h[3] = __float2bfloat16(fmaf(a, v.w, bv));
        *reinterpret_cast<ushort4*>(&lt[c * LTS + h1 * 56 + w4]) = pk.u;
    }
    __syncthreads();

    // Phase B: XWW planes: per (c, j2) one padded window run of 52 (13 ushort4)
    for (int idx = tid; idx < 6656; idx += 256) {       // 64c * 8j2 * 13
        const int c = idx / 104, r = idx - 104 * c;
        const int j2 = r / 13, q4 = (r - 13 * j2) * 4;
        unsigned short tmp[4];
#pragma unroll
        for (int e = 0; e < 4; ++e) {
            const int p = q4 + e;
            if (p < 49) {
                const int h1p = p / 7, w1 = p - 7 * h1p;
                tmp[e] = lt[c * LTS + h1p * 56 + w1 * 8 + j2];
            } else {
                tmp[e] = 0;                              // zero pad (+0.0 bf16)
            }
        }
        ushort4 v; v.x = tmp[0]; v.y = tmp[1]; v.z = tmp[2]; v.w = tmp[3];
        *reinterpret_cast<ushort4*>(
            &XWW[((size_t)(b * NC) + c0 + c) * NPW + (j1 * 8 + j2) * 52 + q4]) = v;
    }

    // Phase C: XNt rows: per (p, j2, c4): 4 channels of one windowed row
    for (int idx = tid; idx < 6272; idx += 256) {       // 49p * 8j2 * 16c4
        const int p = idx >> 7;                          // 0..48
        const int r = idx & 127;
        const int j2 = r >> 4, c4 = (r & 15) * 4;
        const int h1p = p / 7, w1 = p - 7 * h1p;
        const int px = h1p * 56 + w1 * 8 + j2;
        ushort4 v;
        v.x = lt[(c4 + 0) * LTS + px];
        v.y = lt[(c4 + 1) * LTS + px];
        v.z = lt[(c4 + 2) * LTS + px];
        v.w = lt[(c4 + 3) * LTS + px];
        *reinterpret_cast<ushort4*>(
            &XNt[((size_t)b * NPW + (j1 * 8 + j2) * 52 + p) * 256 + c0 + c4]) = v;
    }
}

// ---------------------------------------------------------------------------
// K2: QKV 1x1-conv as bf16 MFMA GEMM. Out[o][nn'] = sum_c Wb[o][c]*XNt[nn'][c].
//   o in [0,512)  (Q,K): QKt[b][n'][512] k-major.
//   o in [512,768) (V):  plane-major Vb[c][n'].
// ---------------------------------------------------------------------------
__launch_bounds__(256)
__global__ void gemm_qkv_mfma(const unsigned short* __restrict__ XNt,
                              const unsigned short* __restrict__ Wb,
                              const float* __restrict__ bias,
                              unsigned short* __restrict__ QKt,
                              unsigned short* __restrict__ Vb)
{
    __shared__ unsigned short As[128 * 72];   // W tile   [o][k]
    __shared__ unsigned short Bs[128 * 72];   // XNt tile [n][k]
    const int t = threadIdx.x;
    const int nn0 = blockIdx.x * 128;
    const int o0 = blockIdx.y * 128;
    const int lane = t & 63;
    const int wid = t >> 6;
    const int lr = lane & 15, lg = lane >> 4;
    const int wo = (wid >> 1) * 64;
    const int wn = (wid & 1) * 64;

    f32x4 acc[4][4];
#pragma unroll
    for (int i = 0; i < 4; ++i)
#pragma unroll
        for (int j = 0; j < 4; ++j)
            acc[i][j] = (f32x4){0.f, 0.f, 0.f, 0.f};

    for (int kt = 0; kt < 4; ++kt) {
        const int k0 = kt * 64;
#pragma unroll
        for (int it = 0; it < 4; ++it) {
            const int idx = it * 256 + t;     // 0..1023
            const int row = idx >> 3;         // 0..127
            const int k8 = (idx & 7) * 8;     // 0..56
            *reinterpret_cast<uint4*>(&As[row * 72 + k8]) =
                *reinterpret_cast<const uint4*>(&Wb[(size_t)(o0 + row) * 256 + k0 + k8]);
            *reinterpret_cast<uint4*>(&Bs[row * 72 + k8]) =
                *reinterpret_cast<const uint4*>(&XNt[(size_t)(nn0 + row) * 256 + k0 + k8]);
        }
        __syncthreads();
#pragma unroll
        for (int ks = 0; ks < 2; ++ks) {
            const int kk = ks * 32 + lg * 8;
            bf16x8 af[4], bfr[4];
#pragma unroll
            for (int i = 0; i < 4; ++i) {
                af[i]  = *reinterpret_cast<const bf16x8*>(&As[(wo + i * 16 + lr) * 72 + kk]);
                bfr[i] = *reinterpret_cast<const bf16x8*>(&Bs[(wn + i * 16 + lr) * 72 + kk]);
            }
#pragma unroll
            for (int i = 0; i < 4; ++i)
#pragma unroll
                for (int j = 0; j < 4; ++j)
                    acc[i][j] = __builtin_amdgcn_mfma_f32_16x16x32_bf16(
                        af[i], bfr[j], acc[i][j], 0, 0, 0);
        }
        __syncthreads();
    }

    // Epilogue: per osub pass, 32 o-rows x 128 n-cols through LDS (aliases As).
    float* Ts = reinterpret_cast<float*>(As);  // 32 x 132 fp32 = 16.5 KB
#pragma unroll
    for (int osub = 0; osub < 4; ++osub) {
        const float4 b4 = *reinterpret_cast<const float4*>(&bias[o0 + wo + osub * 16 + 4 * lg]);
        const int rowb = (wid >> 1) * 16 + 4 * lg;
#pragma unroll
        for (int j = 0; j < 4; ++j) {
            const int col = wn + j * 16 + lr;
            Ts[(rowb + 0) * 132 + col] = acc[osub][j][0] + b4.x;
            Ts[(rowb + 1) * 132 + col] = acc[osub][j][1] + b4.y;
            Ts[(rowb + 2) * 132 + col] = acc[osub][j][2] + b4.z;
            Ts[(rowb + 3) * 132 + col] = acc[osub][j][3] + b4.w;
        }
        __syncthreads();
        if (o0 < 512) {
            // Q/K: k-major QKt[b][n'][512], transposed read of Ts columns
#pragma unroll
            for (int p = 0; p < 4; ++p) {
                const int item = p * 256 + t;     // 0..1023
                const int n = item >> 3;          // 0..127
                const int half = (item >> 2) & 1;
                const int o4 = (item & 3) * 4;
                union { ushort4 u; __hip_bfloat16 h[4]; } pk;
#pragma unroll
                for (int e = 0; e < 4; ++e)
                    pk.h[e] = __float2bfloat16(Ts[(half * 16 + o4 + e) * 132 + n]);
                const int nn = nn0 + n;
                const int bb2 = nn / NPW;
                const int np = nn - bb2 * NPW;
                const int o = o0 + half * 64 + osub * 16 + o4;
                *reinterpret_cast<ushort4*>(&QKt[((size_t)bb2 * NPW + np) * 512 + o]) = pk.u;
            }
        } else {
            // V: plane-major [c][n'] (c = o-512)
#pragma unroll
            for (int p = 0; p < 4; ++p) {
                const int idx = p * 256 + t;      // 0..1023
                const int row = idx >> 5;         // 0..31
                const int c4 = (idx & 31) * 4;    // 0..124
                const float4 v = *reinterpret_cast<const float4*>(&Ts[row * 132 + c4]);
                const int o = o0 + (row >> 4) * 64 + osub * 16 + (row & 15);
                const int nn = nn0 + c4;
                const int bb2 = nn / NPW;
                const int n = nn - bb2 * NPW;     // padded-windowed n'
                union { ushort4 u; __hip_bfloat16 h[4]; } pk;
                pk.h[0] = __float2bfloat16(v.x);
                pk.h[1] = __float2bfloat16(v.y);
                pk.h[2] = __float2bfloat16(v.z);
                pk.h[3] = __float2bfloat16(v.w);
                *reinterpret_cast<ushort4*>(&Vb[((size_t)bb2 * 256 + (o - 512)) * NPW + n]) = pk.u;
            }
        }
        __syncthreads();
    }
}

// ---------------------------------------------------------------------------
// K4/K6: FFN 1x1-conv as bf16 MFMA GEMM (K=256, O=256). B = k-major bf16
// activations [(b*3136+n)][256]; n-order carried through from B's producer.
// OUTBF16: write bf16 plane-major (T, windowed order). else fp32 plane-major
// (normal order) with optional fp32 shortcut add.
// ---------------------------------------------------------------------------
template<bool RES, bool OUTBF16>
__launch_bounds__(256)
__global__ void gemm_ffn_mfma(const unsigned short* __restrict__ Bt,
                              const unsigned short* __restrict__ Wb2,
                              const float* __restrict__ bias,
                              const float* __restrict__ res, float* __restrict__ outF,
                              unsigned short* __restrict__ outU)
{
    __shared__ unsigned short As[128 * 72];   // W tile [o][k]
    __shared__ unsigned short Bs[128 * 72];   // act tile [n][k]
    const int t = threadIdx.x;
    const int o0 = blockIdx.x * 128;
    const int nn0 = blockIdx.y * 128;
    const int lane = t & 63;
    const int wid = t >> 6;
    const int lr = lane & 15, lg = lane >> 4;
    const int wo = (wid >> 1) * 64;
    const int wn = (wid & 1) * 64;

    f32x4 acc[4][4];
#pragma unroll
    for (int i = 0; i < 4; ++i)
#pragma unroll
        for (int j = 0; j < 4; ++j)
            acc[i][j] = (f32x4){0.f, 0.f, 0.f, 0.f};

    for (int kt = 0; kt < 4; ++kt) {
        const int k0 = kt * 64;
#pragma unroll
        for (int it = 0; it < 4; ++it) {
            const int idx = it * 256 + t;
            const int row = idx >> 3;
            const int k8 = (idx & 7) * 8;
            *reinterpret_cast<uint4*>(&As[row * 72 + k8]) =
                *reinterpret_cast<const uint4*>(&Wb2[(size_t)(o0 + row) * 256 + k0 + k8]);
            *reinterpret_cast<uint4*>(&Bs[row * 72 + k8]) =
                *reinterpret_cast<const uint4*>(&Bt[(size_t)(nn0 + row) * 256 + k0 + k8]);
        }
        __syncthreads();
#pragma unroll
        for (int ks = 0; ks < 2; ++ks) {
            const int kk = ks * 32 + lg * 8;
            bf16x8 af[4], bfr[4];
#pragma unroll
            for (int i = 0; i < 4; ++i) {
                af[i]  = *reinterpret_cast<const bf16x8*>(&As[(wo + i * 16 + lr) * 72 + kk]);
                bfr[i] = *reinterpret_cast<const bf16x8*>(&Bs[(wn + i * 16 + lr) * 72 + kk]);
            }
#pragma unroll
            for (int i = 0; i < 4; ++i)
#pragma unroll
                for (int j = 0; j < 4; ++j)
                    acc[i][j] = __builtin_amdgcn_mfma_f32_16x16x32_bf16(
                        af[i], bfr[j], acc[i][j], 0, 0, 0);
        }
        __syncthreads();
    }

    float* Ts = reinterpret_cast<float*>(As);  // 32 x 132 fp32
#pragma unroll
    for (int osub = 0; osub < 4; ++osub) {
        const float4 b4 = *reinterpret_cast<const float4*>(&bias[o0 + wo + osub * 16 + 4 * lg]);
        const int rowb = (wid >> 1) * 16 + 4 * lg;
#pragma unroll
        for (int j = 0; j < 4; ++j) {
            const int col = wn + j * 16 + lr;
            Ts[(rowb + 0) * 132 + col] = acc[osub][j][0] + b4.x;
            Ts[(rowb + 1) * 132 + col] = acc[osub][j][1] + b4.y;
            Ts[(rowb + 2) * 132 + col] = acc[osub][j][2] + b4.z;
            Ts[(rowb + 3) * 132 + col] = acc[osub][j][3] + b4.w;
        }
        __syncthreads();
#pragma unroll
        for (int p = 0; p < 4; ++p) {
            const int idx = p * 256 + t;      // 0..1023
            const int row = idx >> 5;         // 0..31
            const int c4 = (idx & 31) * 4;    // 0..124
            float4 v = *reinterpret_cast<const float4*>(&Ts[row * 132 + c4]);
            const int o = o0 + (row >> 4) * 64 + osub * 16 + (row & 15);
            const int nn = nn0 + c4;
            const int b2 = nn / NHW;
            const int n = nn - b2 * NHW;      // float4 never straddles (NHW%4==0)
            const size_t po = ((size_t)(b2 * NC + o)) * NHW + n;
            if (OUTBF16) {
                union { ushort4 u; __hip_bfloat16 h[4]; } pk;
                pk.h[0] = __float2bfloat16(v.x);
                pk.h[1] = __float2bfloat16(v.y);
                pk.h[2] = __float2bfloat16(v.z);
                pk.h[3] = __float2bfloat16(v.w);
                *reinterpret_cast<ushort4*>(&outU[po]) = pk.u;
            } else {
                if (RES) {
                    const float4 rv = *reinterpret_cast<const float4*>(&res[po]);
                    v.x += rv.x; v.y += rv.y; v.z += rv.z; v.w += rv.w;
                }
                *reinterpret_cast<float4*>(&outF[po]) = v;
            }
        }
        __syncthreads();
    }
}

// ---------------------------------------------------------------------------
// K3: MFMA attention. ONE WAVE per (window, head), 64-thread blocks, zero
// barriers. Q/K MFMA fragments loaded DIRECTLY from global k-major QKt;
// V/X loads issued early into regs (T14), LDS writes under the softmax.
// xa written in WINDOWED layout (contiguous 28B runs) — NOT normal layout:
// stride-8 normal stores caused 7.4x HBM write amplification (R6 counters:
// WRITE_SIZE 114->849 MB; cross-XCD partial-line writes never merge).
// ---------------------------------------------------------------------------
__launch_bounds__(64)
__global__ void attn_mfma(const unsigned short* __restrict__ QKt,
                          const unsigned short* __restrict__ Vb,
                          const unsigned short* __restrict__ XWW,
                          const float* __restrict__ wcomb,
                          const float* __restrict__ bsumg,
                          float* __restrict__ xa)
{
    const int j = blockIdx.x;            // window id 0..63
    const int head = blockIdx.y;         // 0..7
    const int b = blockIdx.z;
    const int c0 = head * 32;
    const int lane = threadIdx.x;
    const int lr = lane & 15, lg = lane >> 4;

    __shared__ __align__(16) char smem[17920];
    unsigned short* P  = (unsigned short*)smem;             // [64][80]
    float*          wcl = (float*)smem;                     // [1568] post-PV alias
    unsigned short* SP = (unsigned short*)(smem + 6272);    // [32][52] post-PV alias
    unsigned short* VT = (unsigned short*)(smem + 10240);   // [32][68]
    unsigned short* X  = (unsigned short*)(smem + 14592);   // [32][52]

    // ---- early global loads: Q/K fragments (direct) + V/X rows into regs
    const size_t qkbase = ((size_t)b * NPW + j * 52) * 512 + c0 + lg * 8;
    uint4 aqr[4], bkr[4];
#pragma unroll
    for (int mi = 0; mi < 4; ++mi) {
        const unsigned short* rp = QKt + qkbase + (size_t)(mi * 16 + lr) * 512;
        aqr[mi] = *reinterpret_cast<const uint4*>(rp);
        bkr[mi] = *reinterpret_cast<const uint4*>(rp + 256);
    }
    const int dd = lane >> 1;                    // V/X row 0..31
    const int qn = (lane & 1) ? 6 : 7;           // chunks per lane
    const int qb = (lane & 1) * 7;               // chunk base
    const size_t pbase = ((size_t)(b * NC) + c0 + dd) * NPW + j * 52;
    ushort4 uvr[7], uxr[7];
#pragma unroll
    for (int ii = 0; ii < 7; ++ii)
        if (ii < qn) {
            const int q4 = (qb + ii) * 4;
            uvr[ii] = *reinterpret_cast<const ushort4*>(&Vb[pbase + q4]);
            uxr[ii] = *reinterpret_cast<const ushort4*>(&XWW[pbase + q4]);
        }

    // ---- S = Q^T K via MFMA (fp32 accum), fragments straight from global
    f32x4 acc[4][4];
#pragma unroll
    for (int mi = 0; mi < 4; ++mi)
#pragma unroll
        for (int ni = 0; ni < 4; ++ni)
            acc[mi][ni] = (f32x4){0.f, 0.f, 0.f, 0.f};
    {
        union { uint4 u; bf16x8 v; } ca, cb;
#pragma unroll
        for (int mi = 0; mi < 4; ++mi)
#pragma unroll
            for (int ni = 0; ni < 4; ++ni) {
                ca.u = aqr[mi]; cb.u = bkr[ni];
                acc[mi][ni] = __builtin_amdgcn_mfma_f32_16x16x32_bf16(
                    ca.v, cb.v, acc[mi][ni], 0, 0, 0);
            }
    }

    // ---- V/X -> LDS (scheduled under softmax); v-residual + pad masking
#pragma unroll
    for (int ii = 0; ii < 7; ++ii)
        if (ii < qn) {
            const int q4 = (qb + ii) * 4;
            union { ushort4 u; unsigned short s[4]; } uo;
            const unsigned short* vs = (const unsigned short*)&uvr[ii];
            const unsigned short* xs2 = (const unsigned short*)&uxr[ii];
#pragma unroll
            for (int e = 0; e < 4; ++e) {
                const float vv = bu2f(vs[e]) + bu2f(xs2[e]);
                uo.s[e] = (q4 + e >= 49) ? (unsigned short)0 : f2bu(vv);
            }
            *reinterpret_cast<ushort4*>(&VT[dd * 68 + q4]) = uo.u;
            *reinterpret_cast<ushort4*>(&X[dd * 52 + q4]) = uxr[ii];
        }
    if (lane & 1) {                       // zero VT cols 52..63 (PV K-pad)
        ushort4 z; z.x = 0; z.y = 0; z.z = 0; z.w = 0;
        *reinterpret_cast<ushort4*>(&VT[dd * 68 + 52]) = z;
        *reinterpret_cast<ushort4*>(&VT[dd * 68 + 56]) = z;
        *reinterpret_cast<ushort4*>(&VT[dd * 68 + 60]) = z;
    }

    // ---- softmax in registers. Row r = mi*16+lg*4+reg spans 16 lanes;
    // cols per lane: lr, 16+lr, 32+lr (valid), 48+lr (valid iff lr==0).
    const float sc = 0.17677669529663687f;
#pragma unroll
    for (int mi = 0; mi < 4; ++mi)
#pragma unroll
        for (int reg = 0; reg < 4; ++reg) {
            const float v0 = acc[mi][0][reg] * sc;
            const float v1 = acc[mi][1][reg] * sc;
            const float v2 = acc[mi][2][reg] * sc;
            const float v3 = acc[mi][3][reg] * sc;
            float m = fmaxf(fmaxf(v0, v1), v2);
            if (lr == 0) m = fmaxf(m, v3);
            m = fmaxf(m, __shfl_xor(m, 1));
            m = fmaxf(m, __shfl_xor(m, 2));
            m = fmaxf(m, __shfl_xor(m, 4));
            m = fmaxf(m, __shfl_xor(m, 8));
            const float e0 = __expf(v0 - m), e1 = __expf(v1 - m), e2 = __expf(v2 - m);
            const float e3 = (lr == 0) ? __expf(v3 - m) : 0.f;
            float s = e0 + e1 + e2 + e3;
            s += __shfl_xor(s, 1);
            s += __shfl_xor(s, 2);
            s += __shfl_xor(s, 4);
            s += __shfl_xor(s, 8);
            const float inv = 1.f / s;
            acc[mi][0][reg] = e0 * inv;
            acc[mi][1][reg] = e1 * inv;
            acc[mi][2][reg] = e2 * inv;
            acc[mi][3][reg] = e3 * inv;
        }

    // ---- P -> LDS bf16 [p][k], stride 80
#pragma unroll
    for (int mi = 0; mi < 4; ++mi)
#pragma unroll
        for (int ni = 0; ni < 4; ++ni)
#pragma unroll
            for (int reg = 0; reg < 4; ++reg)
                P[(mi * 16 + lg * 4 + reg) * 80 + ni * 16 + lr] = f2bu(acc[mi][ni][reg]);

    // ---- O = P @ V via MFMA (K-dim 64, 2 steps); VT rows via 2x b64
    f32x4 acc2[4][2];
#pragma unroll
    for (int mi = 0; mi < 4; ++mi)
#pragma unroll
        for (int ni = 0; ni < 2; ++ni)
            acc2[mi][ni] = (f32x4){0.f, 0.f, 0.f, 0.f};
#pragma unroll
    for (int ks = 0; ks < 2; ++ks) {
        bf16x8 ap[4];
#pragma unroll
        for (int mi = 0; mi < 4; ++mi)
            ap[mi] = *reinterpret_cast<const bf16x8*>(&P[(mi * 16 + lr) * 80 + ks * 32 + lg * 8]);
        bf16x8 bv2[2];
#pragma unroll
        for (int ni = 0; ni < 2; ++ni) {
            union { uint2 u[2]; bf16x8 v; } cv;
            cv.u[0] = *reinterpret_cast<const uint2*>(&VT[(ni * 16 + lr) * 68 + ks * 32 + lg * 8]);
            cv.u[1] = *reinterpret_cast<const uint2*>(&VT[(ni * 16 + lr) * 68 + ks * 32 + lg * 8 + 4]);
            bv2[ni] = cv.v;
        }
#pragma unroll
        for (int mi = 0; mi < 4; ++mi)
#pragma unroll
            for (int ni = 0; ni < 2; ++ni)
                acc2[mi][ni] = __builtin_amdgcn_mfma_f32_16x16x32_bf16(
                    ap[mi], bv2[ni], acc2[mi][ni], 0, 0, 0);
    }
    __builtin_amdgcn_sched_barrier(0);   // keep wcl/SP stores below all P reads

    // ---- spa[d][p] bf16, then wcl fp32 into dead P region
#pragma unroll
    for (int mi = 0; mi < 4; ++mi)
#pragma unroll
        for (int ni = 0; ni < 2; ++ni)
#pragma unroll
            for (int reg = 0; reg < 4; ++reg) {
                const int p = mi * 16 + lg * 4 + reg;
                if (p < 49)
                    SP[(ni * 16 + lr) * 52 + p] = f2bu(acc2[mi][ni][reg]);
            }
    for (int i = lane; i < 392; i += 64)
        *reinterpret_cast<float4*>(&wcl[i * 4]) =
            *reinterpret_cast<const float4*>(&wcomb[c0 * 49 + i * 4]);

    // ---- combined 7x7 dw conv + 0.25*spa + bsum + v residual; WINDOWED store
    for (int it = 0; it < 4; ++it) {
        const int item = it * 64 + lane;
        if (item < 224) {
            const int d = item / 7, h1 = item - 7 * d;
            const float bsv = bsumg[c0 + d];
            float accw[7];
#pragma unroll
            for (int w1 = 0; w1 < 7; ++w1) {
                const int p = h1 * 7 + w1;
                accw[w1] = fmaf(0.25f, bu2f(SP[d * 52 + p]), bsv + bu2f(VT[d * 68 + p]));
            }
#pragma unroll
            for (int dy = 0; dy < 7; ++dy) {
                const int ry = h1 + dy - 3;
                const bool rok = (ry >= 0) && (ry < 7);
                const int ryc = rok ? ry : 0;
                float xr[7];
#pragma unroll
                for (int i2 = 0; i2 < 7; ++i2) {
                    const float xv = bu2f(X[d * 52 + ryc * 7 + i2]);
                    xr[i2] = rok ? xv : 0.f;
                }
#pragma unroll
                for (int dx = 0; dx < 7; ++dx) {
                    const float wv = wcl[d * 49 + dy * 7 + dx];
#pragma unroll
                    for (int w1 = 0; w1 < 7; ++w1) {
                        const int rx = w1 + dx - 3;
                        if (rx >= 0 && rx < 7) accw[w1] = fmaf(wv, xr[rx], accw[w1]);
                    }
                }
            }
            float* xap = xa + ((size_t)(b * NC + c0 + d)) * NHW + j * 49 + h1 * 7;
#pragma unroll
            for (int w1 = 0; w1 < 7; ++w1) xap[w1] = accw[w1];
        }
    }
}

// ---------------------------------------------------------------------------
// K_t256: plane-major -> k-major bf16 transpose (per batch, 64-n chunks).
// F32IN: src fp32 plane stride NHW (xa, windowed). else: src bf16 (U, normal).
// dst[(b*3136 + n)][256] bf16, n-order = src's plane order.
// ---------------------------------------------------------------------------
template<bool F32IN>
__launch_bounds__(256)
__global__ void t256(const float* __restrict__ srcF, const unsigned short* __restrict__ srcU,
                     unsigned short* __restrict__ dst)
{
    const int n0 = blockIdx.x * 64;
    const int b = blockIdx.y;
    __shared__ unsigned short lt[64 * 264];
    const int t = threadIdx.x;
    for (int idx = t; idx < 4096; idx += 256) {       // 256c x 16 n-quads
        const int c = idx >> 4, nq = (idx & 15) * 4;
        ushort4 u;
        if (F32IN) {
            const float4 v = *reinterpret_cast<const float4*>(
                &srcF[((size_t)(b * NC) + c) * NHW + n0 + nq]);
            u.x = f2bu(v.x); u.y = f2bu(v.y); u.z = f2bu(v.z); u.w = f2bu(v.w);
        } else {
            u = *reinterpret_cast<const ushort4*>(
                &srcU[((size_t)(b * NC) + c) * NHW + n0 + nq]);
        }
        lt[(nq + 0) * 264 + c] = u.x;
        lt[(nq + 1) * 264 + c] = u.y;
        lt[(nq + 2) * 264 + c] = u.z;
        lt[(nq + 3) * 264 + c] = u.w;
    }
    __syncthreads();
#pragma unroll
    for (int p = 0; p < 16; ++p) {
        const int idx = p * 256 + t;
        const int row = idx >> 6;             // 0..63
        const int c4 = (idx & 63) * 4;
        *reinterpret_cast<ushort4*>(&dst[((size_t)b * NHW + n0 + row) * 256 + c4]) =
            *reinterpret_cast<const ushort4*>(&lt[row * 264 + c4]);
    }
}

// ---------------------------------------------------------------------------
// K5: per-(b,c)-plane: 3x3 depthwise conv (conv_local) + SiLU on T
// (T bf16 WINDOWED -> LDS-normal -> stencil -> U bf16 NORMAL), plus in-place
// windowed->normal permute of xa (shortcut for the final GEMM). All HBM
// accesses coalesced; scatter only inside LDS.
// ---------------------------------------------------------------------------
__launch_bounds__(256)
__global__ void dw3_silu(const unsigned short* __restrict__ T, const float* __restrict__ wloc,
                         const float* __restrict__ bloc, unsigned short* __restrict__ Uu,
                         float* xa)
{
    const int c = blockIdx.x, b = blockIdx.y;
    const size_t pb = ((size_t)b * NC + c) * NHW;
    __shared__ float pl[56 * 57];        // T, normal order, stride-57 rows
    __shared__ float xpl[3136];          // xa, normal order
    const int tid = threadIdx.x;
    const ushort4* t4 = reinterpret_cast<const ushort4*>(T + pb);
    const float4* x4 = reinterpret_cast<const float4*>(xa + pb);
    for (int i = tid; i < 784; i += 256) {
        const ushort4 tv = t4[i];
        const float4 xv = x4[i];
        const float tt[4] = {bu2f(tv.x), bu2f(tv.y), bu2f(tv.z), bu2f(tv.w)};
        const float xx[4] = {xv.x, xv.y, xv.z, xv.w};
#pragma unroll
        for (int e = 0; e < 4; ++e) {
            const int n = 4 * i + e;
            const int j = n / 49, p = n - 49 * j;
            const int h1 = p / 7, w1 = p - 7 * h1;
            const int h = h1 * 8 + (j >> 3), w = w1 * 8 + (j & 7);
            pl[h * 57 + w] = tt[e];
            xpl[h * 56 + w] = xx[e];
        }
    }
    __syncthreads();

    float wk[9];
#pragma unroll
    for (int k = 0; k < 9; ++k) wk[k] = wloc[c * 9 + k];
    const float bs = bloc[c];
    unsigned short* up = Uu + pb;
    for (int i4 = tid; i4 < 784; i4 += 256) {
        ushort4 pk;
        unsigned short* pks = (unsigned short*)&pk;
#pragma unroll
        for (int e = 0; e < 4; ++e) {
            const int i = 4 * i4 + e;
            const int h = i / 56, w = i - 56 * h;
            float acc = bs;
#pragma unroll
            for (int dy = -1; dy <= 1; ++dy) {
                const int hh = h + dy;
                if (hh < 0 || hh >= 56) continue;
#pragma unroll
                for (int dx = -1; dx <= 1; ++dx) {
                    const int ww = w + dx;
                    if (ww < 0 || ww >= 56) continue;
                    acc = fmaf(wk[(dy + 1) * 3 + (dx + 1)], pl[hh * 57 + ww], acc);
                }
            }
            pks[e] = f2bu(acc / (1.f + __expf(-acc)));   // silu
        }
        *reinterpret_cast<ushort4*>(&up[4 * i4]) = pk;
    }

    float4* xo4 = reinterpret_cast<float4*>(xa + pb);
    for (int i = tid; i < 784; i += 256)
        xo4[i] = make_float4(xpl[4 * i], xpl[4 * i + 1], xpl[4 * i + 2], xpl[4 * i + 3]);
}

// ---------------------------------------------------------------------------
// Launch. Workspace layout (floats):
//   [0,512)              : BN affine a[256], b[256]
//   wcomb = W+512        : 256*49
//   bsum  = W+13056      : 256
//   part  = W+13312      : 256*8*2 partial BN sums -> ends 17408
//   Wb    = W+17408      : 768*256 bf16 (98304 fl) -> ends 115712
//   Wfb   = W+115712     : 256*256 bf16 (32768 fl) -> ends 148480
//   Wob   = W+148480     : 256*256 bf16 (32768 fl) -> ends 181248
//   xa    = W+181248     : NA fl — XNt alias (dead after QKV GEMM), attn
//                          output WINDOWED fp32, NORMAL after K5 (in-place)
//   R     = xa+NA        : 54,525,952 fl shared region:
//     phase 1: QKt us [b][3328][512] | Vb planes | XWW planes
//     phase 2: T bf16 (windowed order) + Uu bf16 (normal) in QKt region;
//              XAt (windowed order) in Vb region; Ut (normal) in XWW region.
//   total ~ 321.6 MB
// ---------------------------------------------------------------------------
extern "C" void kernel_launch(void* const* d_in, const int* in_sizes, int n_in,
                              void* d_out, int out_size, void* d_ws, size_t ws_size,
                              hipStream_t stream)
{
    (void)in_sizes; (void)n_in; (void)out_size; (void)ws_size;
    const float* x    = (const float*)d_in[0];
    const float* g    = (const float*)d_in[1];
    const float* be   = (const float*)d_in[2];
    const float* qkvw = (const float*)d_in[3];
    const float* qkvb = (const float*)d_in[4];
    const float* w3   = (const float*)d_in[5];
    const float* b3   = (const float*)d_in[6];
    const float* w5   = (const float*)d_in[7];
    const float* b5   = (const float*)d_in[8];
    const float* w7   = (const float*)d_in[9];
    const float* b7   = (const float*)d_in[10];
    const float* fiw  = (const float*)d_in[11];
    const float* fib  = (const float*)d_in[12];
    const float* clw  = (const float*)d_in[13];
    const float* clb  = (const float*)d_in[14];
    const float* fow  = (const float*)d_in[15];
    const float* fob  = (const float*)d_in[16];
    float* out = (float*)d_out;

    float* W     = (float*)d_ws;
    float* ab    = W;
    float* wcomb = W + 512;
    float* bsum  = W + 13056;
    float* part  = W + 13312;
    __hip_bfloat16* Wb  = (__hip_bfloat16*)(W + 17408);
    __hip_bfloat16* Wfb = (__hip_bfloat16*)(W + 115712);
    __hip_bfloat16* Wob = (__hip_bfloat16*)(W + 148480);
    float* xa    = W + 181248;
    unsigned short* XNt = (unsigned short*)xa;              // dead after QKV GEMM
    float* R     = xa + NA;
    unsigned short* QKt = (unsigned short*)R;               // [b][3328][512]
    unsigned short* Vb  = QKt + (size_t)NB * NPW * 512;
    unsigned short* XWW = Vb + (size_t)NB * 256 * NPW;
    unsigned short* T   = (unsigned short*)R;               // bf16, in QKt region
    unsigned short* Uu  = T + NA;                           // bf16, in QKt region
    unsigned short* XAt = Vb;                               // aliases Vb (dead)
    unsigned short* Ut  = XWW;                              // aliases XWW (dead)

    bn_part<<<dim3(256, 8), dim3(256), 0, stream>>>(x, part);
    bn_fin<<<dim3(256), dim3(256), 0, stream>>>(part, g, be, w3, b3, w5, b5, w7, b7,
                                                qkvw, fiw, fow, ab, wcomb, bsum,
                                                Wb, Wfb, Wob);
    xnt_make2<<<dim3(4, 8, NB), dim3(256), 0, stream>>>(x, ab, XNt, XWW);
    gemm_qkv_mfma<<<dim3(832, 6), dim3(256), 0, stream>>>(
        XNt, (const unsigned short*)Wb, qkvb, QKt, Vb);
    attn_mfma<<<dim3(64, 8, NB), dim3(64), 0, stream>>>(
        QKt, Vb, XWW, wcomb, bsum, xa);
    t256<true><<<dim3(49, NB), dim3(256), 0, stream>>>(xa, nullptr, XAt);
    gemm_ffn_mfma<false, true><<<dim3(2, 784), dim3(256), 0, stream>>>(
        XAt, (const unsigned short*)Wfb, fib, nullptr, nullptr, T);
    dw3_silu<<<dim3(256, NB), dim3(256), 0, stream>>>(T, clw, clb, Uu, xa);
    t256<false><<<dim3(49, NB), dim3(256), 0, stream>>>(nullptr, Uu, Ut);
    gemm_ffn_mfma<true, false><<<dim3(2, 784), dim3(256), 0, stream>>>(
        Ut, (const unsigned short*)Wob, fob, xa, out, nullptr);
}

// Round 8
// 700.448 us; speedup vs baseline: 2.5632x; 1.1313x over previous
//
#include <hip/hip_runtime.h>
#include <hip/hip_bf16.h>

// Problem constants
#define NB 32
#define NC 256
#define NHW 3136                 // 56*56
#define NA 25690112ull           // NB*NC*NHW elements (one NCHW tensor)
#define NPW 3328                 // padded windowed plane: 64 windows * 52
#define LTS 396                  // xnt_make2 LDS row stride (ushorts, mult of 4)

typedef __attribute__((ext_vector_type(8))) short bf16x8;
typedef __attribute__((ext_vector_type(4))) float f32x4;

// Window mapping: h=h1*8+j1, w=w1*8+j2; j=j1*8+j2 (0..63), p=h1*7+w1 (0..48).
// PADDED windowed linear index n' = j*52 + p (p in [0,52), p>=49 = pad).

static __device__ __forceinline__ unsigned short f2bu(float f) {
    union { __hip_bfloat16 h; unsigned short u; } c;
    c.h = __float2bfloat16(f);
    return c.u;
}
static __device__ __forceinline__ float bu2f(unsigned short us) {
    union { unsigned short u; __hip_bfloat16 h; } c;
    c.u = us;
    return __bfloat162float(c.h);
}

// ---------------------------------------------------------------------------
// K1a: BatchNorm partial sums. Grid (256 c, 8 bq).
// ---------------------------------------------------------------------------
__launch_bounds__(256)
__global__ void bn_part(const float* __restrict__ x, float* __restrict__ part)
{
    const int c = blockIdx.x, bq = blockIdx.y;
    const int tid = threadIdx.x;
    float s = 0.f, s2 = 0.f;
    for (int b = bq * 4; b < bq * 4 + 4; ++b) {
        const float4* p = reinterpret_cast<const float4*>(x + ((size_t)b * NC + c) * NHW);
        for (int i = tid; i < 784; i += 256) {
            const float4 v = p[i];
            s += v.x + v.y + v.z + v.w;
            s2 = fmaf(v.x, v.x, s2); s2 = fmaf(v.y, v.y, s2);
            s2 = fmaf(v.z, v.z, s2); s2 = fmaf(v.w, v.w, s2);
        }
    }
    __shared__ float r1[256], r2[256];
    r1[tid] = s; r2[tid] = s2;
    __syncthreads();
    for (int off = 128; off > 0; off >>= 1) {
        if (tid < off) { r1[tid] += r1[tid + off]; r2[tid] += r2[tid + off]; }
        __syncthreads();
    }
    if (tid == 0) {
        part[(c * 8 + bq) * 2] = r1[0];
        part[(c * 8 + bq) * 2 + 1] = r2[0];
    }
}

// ---------------------------------------------------------------------------
// K1b: finalize BN affine (a,b), combined dw weights, bias sum, bf16 weights.
// ---------------------------------------------------------------------------
__launch_bounds__(256)
__global__ void bn_fin(const float* __restrict__ part,
                       const float* __restrict__ gamma, const float* __restrict__ beta,
                       const float* __restrict__ w3, const float* __restrict__ b3,
                       const float* __restrict__ w5, const float* __restrict__ b5,
                       const float* __restrict__ w7, const float* __restrict__ b7,
                       const float* __restrict__ qkvw,
                       const float* __restrict__ fiw, const float* __restrict__ fow,
                       float* __restrict__ ab, float* __restrict__ wcomb,
                       float* __restrict__ bsum, __hip_bfloat16* __restrict__ Wb,
                       __hip_bfloat16* __restrict__ Wfb, __hip_bfloat16* __restrict__ Wob)
{
    const int c = blockIdx.x;
    const int tid = threadIdx.x;

    if (tid < 49) {
        const int ty = tid / 7, tx = tid % 7;
        float wv = w7[c * 49 + tid];
        if (ty >= 1 && ty <= 5 && tx >= 1 && tx <= 5) wv += w5[c * 25 + (ty - 1) * 5 + (tx - 1)];
        if (ty >= 2 && ty <= 4 && tx >= 2 && tx <= 4) wv += w3[c * 9 + (ty - 2) * 3 + (tx - 2)];
        wcomb[c * 49 + tid] = 0.25f * wv;
    }
    if (tid == 63) bsum[c] = 0.25f * (b3[c] + b5[c] + b7[c]);

#pragma unroll
    for (int r = 0; r < 3; ++r) {
        const int o = 3 * c + r;
        Wb[o * 256 + tid] = __float2bfloat16(qkvw[o * 256 + tid]);
    }
    Wfb[c * 256 + tid] = __float2bfloat16(fiw[c * 256 + tid]);
    Wob[c * 256 + tid] = __float2bfloat16(fow[c * 256 + tid]);

    if (tid == 0) {
        float s = 0.f, s2 = 0.f;
#pragma unroll
        for (int q = 0; q < 8; ++q) {
            s += part[(c * 8 + q) * 2];
            s2 += part[(c * 8 + q) * 2 + 1];
        }
        const float inv_n = 1.f / (float)((size_t)NB * NHW);
        const float mean = s * inv_n;
        const float var = s2 * inv_n - mean * mean;
        const float a = gamma[c] / sqrtf(var + 1e-5f);
        ab[c] = a;
        ab[NC + c] = beta[c] - mean * a;
    }
}

// ---------------------------------------------------------------------------
// K1.5: xn = a*x+b applied once; emits PADDED-WINDOWED outputs:
//   XNt bf16 [(b*3328 + n')][c]  (k-contiguous rows for the MFMA GEMM)
//   XWW bf16 [b][c][n']          (padded windowed planes, pads ZEROED)
// ---------------------------------------------------------------------------
__launch_bounds__(256)
__global__ void xnt_make2(const float* __restrict__ x, const float* __restrict__ ab,
                          unsigned short* __restrict__ XNt, unsigned short* __restrict__ XWW)
{
    const int c0 = blockIdx.x * 64;      // channel chunk
    const int j1 = blockIdx.y;           // window row id
    const int b  = blockIdx.z;
    __shared__ unsigned short lt[64 * LTS];   // [c][px], px = h1*56 + w
    __shared__ float aa[64], bb[64];
    const int tid = threadIdx.x;
    if (tid < 64) { aa[tid] = ab[c0 + tid]; bb[tid] = ab[256 + c0 + tid]; }
    __syncthreads();

    // Phase A: load 64c x 7rows x 56w fp32, affine, cvt bf16 -> LDS
    for (int idx = tid; idx < 6272; idx += 256) {       // 64 * 98 float4
        const int c = idx / 98, f = idx - 98 * c;
        const int h1 = f / 14, w4 = (f - 14 * h1) * 4;
        const float4 v = *reinterpret_cast<const float4*>(
            &x[((size_t)(b * NC) + c0 + c) * NHW + (h1 * 8 + j1) * 56 + w4]);
        const float a = aa[c], bv = bb[c];
        union { ushort4 u; __hip_bfloat16 h[4]; } pk;
        pk.h[0] = __float2bfloat16(fmaf(a, v.x, bv));
        pk.h[1] = __float2bfloat16(fmaf(a, v.y, bv));
        pk.h[2] = __float2bfloat16(fmaf(a, v.z, bv));
        pk.h[3] = __float2bfloat16(fmaf(a, v.w, bv));
        *reinterpret_cast<ushort4*>(&lt[c * LTS + h1 * 56 + w4]) = pk.u;
    }
    __syncthreads();

    // Phase B: XWW planes: per (c, j2) one padded window run of 52 (13 ushort4)
    for (int idx = tid; idx < 6656; idx += 256) {       // 64c * 8j2 * 13
        const int c = idx / 104, r = idx - 104 * c;
        const int j2 = r / 13, q4 = (r - 13 * j2) * 4;
        unsigned short tmp[4];
#pragma unroll
        for (int e = 0; e < 4; ++e) {
            const int p = q4 + e;
            if (p < 49) {
                const int h1p = p / 7, w1 = p - 7 * h1p;
                tmp[e] = lt[c * LTS + h1p * 56 + w1 * 8 + j2];
            } else {
                tmp[e] = 0;                              // zero pad (+0.0 bf16)
            }
        }
        ushort4 v; v.x = tmp[0]; v.y = tmp[1]; v.z = tmp[2]; v.w = tmp[3];
        *reinterpret_cast<ushort4*>(
            &XWW[((size_t)(b * NC) + c0 + c) * NPW + (j1 * 8 + j2) * 52 + q4]) = v;
    }

    // Phase C: XNt rows: per (p, j2, c4): 4 channels of one windowed row
    for (int idx = tid; idx < 6272; idx += 256) {       // 49p * 8j2 * 16c4
        const int p = idx >> 7;                          // 0..48
        const int r = idx & 127;
        const int j2 = r >> 4, c4 = (r & 15) * 4;
        const int h1p = p / 7, w1 = p - 7 * h1p;
        const int px = h1p * 56 + w1 * 8 + j2;
        ushort4 v;
        v.x = lt[(c4 + 0) * LTS + px];
        v.y = lt[(c4 + 1) * LTS + px];
        v.z = lt[(c4 + 2) * LTS + px];
        v.w = lt[(c4 + 3) * LTS + px];
        *reinterpret_cast<ushort4*>(
            &XNt[((size_t)b * NPW + (j1 * 8 + j2) * 52 + p) * 256 + c0 + c4]) = v;
    }
}

// ---------------------------------------------------------------------------
// K2: QKV 1x1-conv as bf16 MFMA GEMM. Out[o][nn'] = sum_c Wb[o][c]*XNt[nn'][c].
//   o in [0,512)  (Q,K): QKt[b][n'][512] k-major.
//   o in [512,768) (V):  plane-major Vb[c][n'].
// ---------------------------------------------------------------------------
__launch_bounds__(256)
__global__ void gemm_qkv_mfma(const unsigned short* __restrict__ XNt,
                              const unsigned short* __restrict__ Wb,
                              const float* __restrict__ bias,
                              unsigned short* __restrict__ QKt,
                              unsigned short* __restrict__ Vb)
{
    __shared__ unsigned short As[128 * 72];   // W tile   [o][k]
    __shared__ unsigned short Bs[128 * 72];   // XNt tile [n][k]
    const int t = threadIdx.x;
    const int nn0 = blockIdx.x * 128;
    const int o0 = blockIdx.y * 128;
    const int lane = t & 63;
    const int wid = t >> 6;
    const int lr = lane & 15, lg = lane >> 4;
    const int wo = (wid >> 1) * 64;
    const int wn = (wid & 1) * 64;

    f32x4 acc[4][4];
#pragma unroll
    for (int i = 0; i < 4; ++i)
#pragma unroll
        for (int j = 0; j < 4; ++j)
            acc[i][j] = (f32x4){0.f, 0.f, 0.f, 0.f};

    for (int kt = 0; kt < 4; ++kt) {
        const int k0 = kt * 64;
#pragma unroll
        for (int it = 0; it < 4; ++it) {
            const int idx = it * 256 + t;     // 0..1023
            const int row = idx >> 3;         // 0..127
            const int k8 = (idx & 7) * 8;     // 0..56
            *reinterpret_cast<uint4*>(&As[row * 72 + k8]) =
                *reinterpret_cast<const uint4*>(&Wb[(size_t)(o0 + row) * 256 + k0 + k8]);
            *reinterpret_cast<uint4*>(&Bs[row * 72 + k8]) =
                *reinterpret_cast<const uint4*>(&XNt[(size_t)(nn0 + row) * 256 + k0 + k8]);
        }
        __syncthreads();
#pragma unroll
        for (int ks = 0; ks < 2; ++ks) {
            const int kk = ks * 32 + lg * 8;
            bf16x8 af[4], bfr[4];
#pragma unroll
            for (int i = 0; i < 4; ++i) {
                af[i]  = *reinterpret_cast<const bf16x8*>(&As[(wo + i * 16 + lr) * 72 + kk]);
                bfr[i] = *reinterpret_cast<const bf16x8*>(&Bs[(wn + i * 16 + lr) * 72 + kk]);
            }
#pragma unroll
            for (int i = 0; i < 4; ++i)
#pragma unroll
                for (int j = 0; j < 4; ++j)
                    acc[i][j] = __builtin_amdgcn_mfma_f32_16x16x32_bf16(
                        af[i], bfr[j], acc[i][j], 0, 0, 0);
        }
        __syncthreads();
    }

    // Epilogue: per osub pass, 32 o-rows x 128 n-cols through LDS (aliases As).
    float* Ts = reinterpret_cast<float*>(As);  // 32 x 132 fp32 = 16.5 KB
#pragma unroll
    for (int osub = 0; osub < 4; ++osub) {
        const float4 b4 = *reinterpret_cast<const float4*>(&bias[o0 + wo + osub * 16 + 4 * lg]);
        const int rowb = (wid >> 1) * 16 + 4 * lg;
#pragma unroll
        for (int j = 0; j < 4; ++j) {
            const int col = wn + j * 16 + lr;
            Ts[(rowb + 0) * 132 + col] = acc[osub][j][0] + b4.x;
            Ts[(rowb + 1) * 132 + col] = acc[osub][j][1] + b4.y;
            Ts[(rowb + 2) * 132 + col] = acc[osub][j][2] + b4.z;
            Ts[(rowb + 3) * 132 + col] = acc[osub][j][3] + b4.w;
        }
        __syncthreads();
        if (o0 < 512) {
            // Q/K: k-major QKt[b][n'][512], transposed read of Ts columns
#pragma unroll
            for (int p = 0; p < 4; ++p) {
                const int item = p * 256 + t;     // 0..1023
                const int n = item >> 3;          // 0..127
                const int half = (item >> 2) & 1;
                const int o4 = (item & 3) * 4;
                union { ushort4 u; __hip_bfloat16 h[4]; } pk;
#pragma unroll
                for (int e = 0; e < 4; ++e)
                    pk.h[e] = __float2bfloat16(Ts[(half * 16 + o4 + e) * 132 + n]);
                const int nn = nn0 + n;
                const int bb2 = nn / NPW;
                const int np = nn - bb2 * NPW;
                const int o = o0 + half * 64 + osub * 16 + o4;
                *reinterpret_cast<ushort4*>(&QKt[((size_t)bb2 * NPW + np) * 512 + o]) = pk.u;
            }
        } else {
            // V: plane-major [c][n'] (c = o-512)
#pragma unroll
            for (int p = 0; p < 4; ++p) {
                const int idx = p * 256 + t;      // 0..1023
                const int row = idx >> 5;         // 0..31
                const int c4 = (idx & 31) * 4;    // 0..124
                const float4 v = *reinterpret_cast<const float4*>(&Ts[row * 132 + c4]);
                const int o = o0 + (row >> 4) * 64 + osub * 16 + (row & 15);
                const int nn = nn0 + c4;
                const int bb2 = nn / NPW;
                const int n = nn - bb2 * NPW;     // padded-windowed n'
                union { ushort4 u; __hip_bfloat16 h[4]; } pk;
                pk.h[0] = __float2bfloat16(v.x);
                pk.h[1] = __float2bfloat16(v.y);
                pk.h[2] = __float2bfloat16(v.z);
                pk.h[3] = __float2bfloat16(v.w);
                *reinterpret_cast<ushort4*>(&Vb[((size_t)bb2 * 256 + (o - 512)) * NPW + n]) = pk.u;
            }
        }
        __syncthreads();
    }
}

// ---------------------------------------------------------------------------
// K4/K6: FFN 1x1-conv as bf16 MFMA GEMM (K=256, O=256). B operand staged with
// TRANSPOSE-IN-LDS directly from the plane-major source (no separate t256):
//   SRCF32=1 (ffn1): B from xa fp32 plane-major (windowed order), f2bu in
//     staging; OUTPUT bf16 plane-major T (same windowed n-order).
//   SRCF32=0 (ffn2): B from U bf16 plane-major (normal order); OUTPUT fp32
//     plane-major with fp32 shortcut add (res, normal order).
// Staging reads: per lane 128B (fp32) / 64B (bf16) contiguous; LDS writes
// 64 lanes x 2B consecutive = 2-way bank aliasing (free, m136).
// ---------------------------------------------------------------------------
template<bool RES, bool SRCF32>
__launch_bounds__(256)
__global__ void gemm_ffn_mfma(const float* __restrict__ BF,
                              const unsigned short* __restrict__ BU,
                              const unsigned short* __restrict__ Wb2,
                              const float* __restrict__ bias,
                              const float* __restrict__ res, float* __restrict__ outF,
                              unsigned short* __restrict__ outU)
{
    __shared__ unsigned short As[128 * 72];   // W tile [o][k]
    __shared__ unsigned short Bs[128 * 72];   // act tile [n][k]
    const int t = threadIdx.x;
    const int o0 = blockIdx.x * 128;
    const int nn0 = blockIdx.y * 128;
    const int lane = t & 63;
    const int wid = t >> 6;
    const int lr = lane & 15, lg = lane >> 4;
    const int wo = (wid >> 1) * 64;
    const int wn = (wid & 1) * 64;

    f32x4 acc[4][4];
#pragma unroll
    for (int i = 0; i < 4; ++i)
#pragma unroll
        for (int j = 0; j < 4; ++j)
            acc[i][j] = (f32x4){0.f, 0.f, 0.f, 0.f};

    // B source row (32 n per thread, 32|3136 so no plane straddle)
    const int cl = t & 63;                 // channel within k-tile
    const int nseg = (t >> 6) * 32;        // n offset within tile
    const int nnB = nn0 + nseg;
    const int b2B = nnB / NHW;
    const int nB = nnB - b2B * NHW;

    for (int kt = 0; kt < 4; ++kt) {
        const int k0 = kt * 64;
        // A stage (weights, k-major): 4 iters x 16B
#pragma unroll
        for (int it = 0; it < 4; ++it) {
            const int idx = it * 256 + t;
            const int row = idx >> 3;
            const int k8 = (idx & 7) * 8;
            *reinterpret_cast<uint4*>(&As[row * 72 + k8]) =
                *reinterpret_cast<const uint4*>(&Wb2[(size_t)(o0 + row) * 256 + k0 + k8]);
        }
        // B stage: transpose from plane-major source
        {
            unsigned short* bd = &Bs[nseg * 72 + cl];
            if (SRCF32) {
                const float* src = BF + ((size_t)(b2B * NC) + k0 + cl) * NHW + nB;
#pragma unroll
                for (int q = 0; q < 8; ++q) {
                    const float4 vv = *reinterpret_cast<const float4*>(src + q * 4);
                    bd[(q * 4 + 0) * 72] = f2bu(vv.x);
                    bd[(q * 4 + 1) * 72] = f2bu(vv.y);
                    bd[(q * 4 + 2) * 72] = f2bu(vv.z);
                    bd[(q * 4 + 3) * 72] = f2bu(vv.w);
                }
            } else {
                const unsigned short* src = BU + ((size_t)(b2B * NC) + k0 + cl) * NHW + nB;
#pragma unroll
                for (int q = 0; q < 8; ++q) {
                    const ushort4 uu = *reinterpret_cast<const ushort4*>(src + q * 4);
                    bd[(q * 4 + 0) * 72] = uu.x;
                    bd[(q * 4 + 1) * 72] = uu.y;
                    bd[(q * 4 + 2) * 72] = uu.z;
                    bd[(q * 4 + 3) * 72] = uu.w;
                }
            }
        }
        __syncthreads();
#pragma unroll
        for (int ks = 0; ks < 2; ++ks) {
            const int kk = ks * 32 + lg * 8;
            bf16x8 af[4], bfr[4];
#pragma unroll
            for (int i = 0; i < 4; ++i) {
                af[i]  = *reinterpret_cast<const bf16x8*>(&As[(wo + i * 16 + lr) * 72 + kk]);
                bfr[i] = *reinterpret_cast<const bf16x8*>(&Bs[(wn + i * 16 + lr) * 72 + kk]);
            }
#pragma unroll
            for (int i = 0; i < 4; ++i)
#pragma unroll
                for (int j = 0; j < 4; ++j)
                    acc[i][j] = __builtin_amdgcn_mfma_f32_16x16x32_bf16(
                        af[i], bfr[j], acc[i][j], 0, 0, 0);
        }
        __syncthreads();
    }

    float* Ts = reinterpret_cast<float*>(As);  // 32 x 132 fp32
#pragma unroll
    for (int osub = 0; osub < 4; ++osub) {
        const float4 b4 = *reinterpret_cast<const float4*>(&bias[o0 + wo + osub * 16 + 4 * lg]);
        const int rowb = (wid >> 1) * 16 + 4 * lg;
#pragma unroll
        for (int j = 0; j < 4; ++j) {
            const int col = wn + j * 16 + lr;
            Ts[(rowb + 0) * 132 + col] = acc[osub][j][0] + b4.x;
            Ts[(rowb + 1) * 132 + col] = acc[osub][j][1] + b4.y;
            Ts[(rowb + 2) * 132 + col] = acc[osub][j][2] + b4.z;
            Ts[(rowb + 3) * 132 + col] = acc[osub][j][3] + b4.w;
        }
        __syncthreads();
#pragma unroll
        for (int p = 0; p < 4; ++p) {
            const int idx = p * 256 + t;      // 0..1023
            const int row = idx >> 5;         // 0..31
            const int c4 = (idx & 31) * 4;    // 0..124
            float4 v = *reinterpret_cast<const float4*>(&Ts[row * 132 + c4]);
            const int o = o0 + (row >> 4) * 64 + osub * 16 + (row & 15);
            const int nn = nn0 + c4;
            const int b2 = nn / NHW;
            const int n = nn - b2 * NHW;      // float4 never straddles (NHW%4==0)
            const size_t po = ((size_t)(b2 * NC + o)) * NHW + n;
            if (SRCF32) {                     // ffn1 -> bf16 T
                union { ushort4 u; __hip_bfloat16 h[4]; } pk;
                pk.h[0] = __float2bfloat16(v.x);
                pk.h[1] = __float2bfloat16(v.y);
                pk.h[2] = __float2bfloat16(v.z);
                pk.h[3] = __float2bfloat16(v.w);
                *reinterpret_cast<ushort4*>(&outU[po]) = pk.u;
            } else {                          // ffn2 -> fp32 + shortcut
                if (RES) {
                    const float4 rv = *reinterpret_cast<const float4*>(&res[po]);
                    v.x += rv.x; v.y += rv.y; v.z += rv.z; v.w += rv.w;
                }
                *reinterpret_cast<float4*>(&outF[po]) = v;
            }
        }
        __syncthreads();
    }
}

// ---------------------------------------------------------------------------
// K3: MFMA attention. ONE WAVE per (window, head), 64-thread blocks, zero
// barriers. Q/K MFMA fragments loaded DIRECTLY from global k-major QKt.
// SWAPPED QK^T: S^T = mfma(K, Q) so each lane holds 16 k-values locally per
// q (col) — softmax max/sum are local tree reductions + only TWO shfl_xor
// (16, 32) per q-group, vs 128 serialized shuffles in the unswapped form.
// Pad-k masked to -1e30 before max (cndmask kills NaN) -> exp underflows to
// exact 0; garbage-q rows stay row-local through PV, discarded at SP store.
// xa written WINDOWED (R6 lesson: normal-layout stride-8 stores = 7.4x HBM
// write amplification).
// ---------------------------------------------------------------------------
__launch_bounds__(64)
__global__ void attn_mfma(const unsigned short* __restrict__ QKt,
                          const unsigned short* __restrict__ Vb,
                          const unsigned short* __restrict__ XWW,
                          const float* __restrict__ wcomb,
                          const float* __restrict__ bsumg,
                          float* __restrict__ xa)
{
    const int j = blockIdx.x;            // window id 0..63
    const int head = blockIdx.y;         // 0..7
    const int b = blockIdx.z;
    const int c0 = head * 32;
    const int lane = threadIdx.x;
    const int lr = lane & 15, lg = lane >> 4;

    __shared__ __align__(16) char smem[17920];
    unsigned short* P  = (unsigned short*)smem;             // [64][80], rows=q cols=k
    float*          wcl = (float*)smem;                     // [1568] post-PV alias
    unsigned short* SP = (unsigned short*)(smem + 6272);    // [32][52] post-PV alias
    unsigned short* VT = (unsigned short*)(smem + 10240);   // [32][68]
    unsigned short* X  = (unsigned short*)(smem + 14592);   // [32][52]

    // ---- early global loads: Q/K fragments (direct) + V/X rows into regs
    const size_t qkbase = ((size_t)b * NPW + j * 52) * 512 + c0 + lg * 8;
    uint4 aqr[4], bkr[4];
#pragma unroll
    for (int mi = 0; mi < 4; ++mi) {
        const unsigned short* rp = QKt + qkbase + (size_t)(mi * 16 + lr) * 512;
        aqr[mi] = *reinterpret_cast<const uint4*>(rp);
        bkr[mi] = *reinterpret_cast<const uint4*>(rp + 256);
    }
    const int dd = lane >> 1;                    // V/X row 0..31
    const int qn = (lane & 1) ? 6 : 7;           // chunks per lane
    const int qb = (lane & 1) * 7;               // chunk base
    const size_t pbase = ((size_t)(b * NC) + c0 + dd) * NPW + j * 52;
    ushort4 uvr[7], uxr[7];
#pragma unroll
    for (int ii = 0; ii < 7; ++ii)
        if (ii < qn) {
            const int q4 = (qb + ii) * 4;
            uvr[ii] = *reinterpret_cast<const ushort4*>(&Vb[pbase + q4]);
            uxr[ii] = *reinterpret_cast<const ushort4*>(&XWW[pbase + q4]);
        }

    // ---- S^T = K Q via MFMA (swapped operands, fp32 accum).
    // acc[mi][ni]: rows k = mi*16+lg*4+reg, cols q = ni*16+lr.
    f32x4 acc[4][4];
#pragma unroll
    for (int mi = 0; mi < 4; ++mi)
#pragma unroll
        for (int ni = 0; ni < 4; ++ni)
            acc[mi][ni] = (f32x4){0.f, 0.f, 0.f, 0.f};
    {
        union { uint4 u; bf16x8 v; } ca, cb;
#pragma unroll
        for (int mi = 0; mi < 4; ++mi)
#pragma unroll
            for (int ni = 0; ni < 4; ++ni) {
                cb.u = bkr[mi]; ca.u = aqr[ni];
                acc[mi][ni] = __builtin_amdgcn_mfma_f32_16x16x32_bf16(
                    cb.v, ca.v, acc[mi][ni], 0, 0, 0);
            }
    }

    // ---- V/X -> LDS (scheduled under softmax); v-residual + pad masking
#pragma unroll
    for (int ii = 0; ii < 7; ++ii)
        if (ii < qn) {
            const int q4 = (qb + ii) * 4;
            union { ushort4 u; unsigned short s[4]; } uo;
            const unsigned short* vs = (const unsigned short*)&uvr[ii];
            const unsigned short* xs2 = (const unsigned short*)&uxr[ii];
#pragma unroll
            for (int e = 0; e < 4; ++e) {
                const float vv = bu2f(vs[e]) + bu2f(xs2[e]);
                uo.s[e] = (q4 + e >= 49) ? (unsigned short)0 : f2bu(vv);
            }
            *reinterpret_cast<ushort4*>(&VT[dd * 68 + q4]) = uo.u;
            *reinterpret_cast<ushort4*>(&X[dd * 52 + q4]) = uxr[ii];
        }
    if (lane & 1) {                       // zero VT cols 52..63 (PV K-pad)
        ushort4 z; z.x = 0; z.y = 0; z.z = 0; z.w = 0;
        *reinterpret_cast<ushort4*>(&VT[dd * 68 + 52]) = z;
        *reinterpret_cast<ushort4*>(&VT[dd * 68 + 56]) = z;
        *reinterpret_cast<ushort4*>(&VT[dd * 68 + 60]) = z;
    }

    // ---- softmax: per lane, per ni (q = ni*16+lr): 16 local k values
    // (k = mi*16 + lg*4 + reg), local tree max/sum + 2 shuffles each.
    const float sc = 0.17677669529663687f;
    const int kb = lg * 4;
#pragma unroll
    for (int ni = 0; ni < 4; ++ni) {
        float v[4][4];
#pragma unroll
        for (int mi = 0; mi < 4; ++mi)
#pragma unroll
            for (int reg = 0; reg < 4; ++reg) {
                const float raw = acc[mi][ni][reg] * sc;
                v[mi][reg] = (mi * 16 + kb + reg < 49) ? raw : -1e30f;
            }
        float m = -1e30f;
#pragma unroll
        for (int mi = 0; mi < 4; ++mi) {
            const float a0 = fmaxf(v[mi][0], v[mi][1]);
            const float a1 = fmaxf(v[mi][2], v[mi][3]);
            m = fmaxf(m, fmaxf(a0, a1));
        }
        m = fmaxf(m, __shfl_xor(m, 16));
        m = fmaxf(m, __shfl_xor(m, 32));
        float s = 0.f;
#pragma unroll
        for (int mi = 0; mi < 4; ++mi)
#pragma unroll
            for (int reg = 0; reg < 4; ++reg) {
                const float e = __expf(v[mi][reg] - m);   // invalid -> 0
                v[mi][reg] = e;
                s += e;
            }
        s += __shfl_xor(s, 16);
        s += __shfl_xor(s, 32);
        const float inv = 1.f / s;
        // store P[q][k] (P^T from registers), stride 80
        unsigned short* Pq = &P[(ni * 16 + lr) * 80];
#pragma unroll
        for (int mi = 0; mi < 4; ++mi)
#pragma unroll
            for (int reg = 0; reg < 4; ++reg)
                Pq[mi * 16 + kb + reg] = f2bu(v[mi][reg] * inv);
    }

    // ---- O = P @ V via MFMA (K-dim 64, 2 steps); VT rows via 2x b64
    f32x4 acc2[4][2];
#pragma unroll
    for (int mi = 0; mi < 4; ++mi)
#pragma unroll
        for (int ni = 0; ni < 2; ++ni)
            acc2[mi][ni] = (f32x4){0.f, 0.f, 0.f, 0.f};
#pragma unroll
    for (int ks = 0; ks < 2; ++ks) {
        bf16x8 ap[4];
#pragma unroll
        for (int mi = 0; mi < 4; ++mi)
            ap[mi] = *reinterpret_cast<const bf16x8*>(&P[(mi * 16 + lr) * 80 + ks * 32 + lg * 8]);
        bf16x8 bv2[2];
#pragma unroll
        for (int ni = 0; ni < 2; ++ni) {
            union { uint2 u[2]; bf16x8 v; } cv;
            cv.u[0] = *reinterpret_cast<const uint2*>(&VT[(ni * 16 + lr) * 68 + ks * 32 + lg * 8]);
            cv.u[1] = *reinterpret_cast<const uint2*>(&VT[(ni * 16 + lr) * 68 + ks * 32 + lg * 8 + 4]);
            bv2[ni] = cv.v;
        }
#pragma unroll
        for (int mi = 0; mi < 4; ++mi)
#pragma unroll
            for (int ni = 0; ni < 2; ++ni)
                acc2[mi][ni] = __builtin_amdgcn_mfma_f32_16x16x32_bf16(
                    ap[mi], bv2[ni], acc2[mi][ni], 0, 0, 0);
    }
    __builtin_amdgcn_sched_barrier(0);   // keep wcl/SP stores below all P reads

    // ---- spa[d][p] bf16, then wcl fp32 into dead P region
#pragma unroll
    for (int mi = 0; mi < 4; ++mi)
#pragma unroll
        for (int ni = 0; ni < 2; ++ni)
#pragma unroll
            for (int reg = 0; reg < 4; ++reg) {
                const int p = mi * 16 + lg * 4 + reg;
                if (p < 49)
                    SP[(ni * 16 + lr) * 52 + p] = f2bu(acc2[mi][ni][reg]);
            }
    for (int i = lane; i < 392; i += 64)
        *reinterpret_cast<float4*>(&wcl[i * 4]) =
            *reinterpret_cast<const float4*>(&wcomb[c0 * 49 + i * 4]);

    // ---- combined 7x7 dw conv + 0.25*spa + bsum + v residual; WINDOWED store
    for (int it = 0; it < 4; ++it) {
        const int item = it * 64 + lane;
        if (item < 224) {
            const int d = item / 7, h1 = item - 7 * d;
            const float bsv = bsumg[c0 + d];
            float accw[7];
#pragma unroll
            for (int w1 = 0; w1 < 7; ++w1) {
                const int p = h1 * 7 + w1;
                accw[w1] = fmaf(0.25f, bu2f(SP[d * 52 + p]), bsv + bu2f(VT[d * 68 + p]));
            }
#pragma unroll
            for (int dy = 0; dy < 7; ++dy) {
                const int ry = h1 + dy - 3;
                const bool rok = (ry >= 0) && (ry < 7);
                const int ryc = rok ? ry : 0;
                float xr[7];
#pragma unroll
                for (int i2 = 0; i2 < 7; ++i2) {
                    const float xv = bu2f(X[d * 52 + ryc * 7 + i2]);
                    xr[i2] = rok ? xv : 0.f;
                }
#pragma unroll
                for (int dx = 0; dx < 7; ++dx) {
                    const float wv = wcl[d * 49 + dy * 7 + dx];
#pragma unroll
                    for (int w1 = 0; w1 < 7; ++w1) {
                        const int rx = w1 + dx - 3;
                        if (rx >= 0 && rx < 7) accw[w1] = fmaf(wv, xr[rx], accw[w1]);
                    }
                }
            }
            float* xap = xa + ((size_t)(b * NC + c0 + d)) * NHW + j * 49 + h1 * 7;
#pragma unroll
            for (int w1 = 0; w1 < 7; ++w1) xap[w1] = accw[w1];
        }
    }
}

// ---------------------------------------------------------------------------
// K5: per-(b,c)-plane: 3x3 depthwise conv (conv_local) + SiLU on T
// (T bf16 WINDOWED -> LDS-normal -> stencil -> U bf16 NORMAL), plus in-place
// windowed->normal permute of xa (shortcut for the final GEMM).
// ---------------------------------------------------------------------------
__launch_bounds__(256)
__global__ void dw3_silu(const unsigned short* __restrict__ T, const float* __restrict__ wloc,
                         const float* __restrict__ bloc, unsigned short* __restrict__ Uu,
                         float* xa)
{
    const int c = blockIdx.x, b = blockIdx.y;
    const size_t pb = ((size_t)b * NC + c) * NHW;
    __shared__ float pl[56 * 57];        // T, normal order, stride-57 rows
    __shared__ float xpl[3136];          // xa, normal order
    const int tid = threadIdx.x;
    const ushort4* t4 = reinterpret_cast<const ushort4*>(T + pb);
    const float4* x4 = reinterpret_cast<const float4*>(xa + pb);
    for (int i = tid; i < 784; i += 256) {
        const ushort4 tv = t4[i];
        const float4 xv = x4[i];
        const float tt[4] = {bu2f(tv.x), bu2f(tv.y), bu2f(tv.z), bu2f(tv.w)};
        const float xx[4] = {xv.x, xv.y, xv.z, xv.w};
#pragma unroll
        for (int e = 0; e < 4; ++e) {
            const int n = 4 * i + e;
            const int j = n / 49, p = n - 49 * j;
            const int h1 = p / 7, w1 = p - 7 * h1;
            const int h = h1 * 8 + (j >> 3), w = w1 * 8 + (j & 7);
            pl[h * 57 + w] = tt[e];
            xpl[h * 56 + w] = xx[e];
        }
    }
    __syncthreads();

    float wk[9];
#pragma unroll
    for (int k = 0; k < 9; ++k) wk[k] = wloc[c * 9 + k];
    const float bs = bloc[c];
    unsigned short* up = Uu + pb;
    for (int i4 = tid; i4 < 784; i4 += 256) {
        ushort4 pk;
        unsigned short* pks = (unsigned short*)&pk;
#pragma unroll
        for (int e = 0; e < 4; ++e) {
            const int i = 4 * i4 + e;
            const int h = i / 56, w = i - 56 * h;
            float acc = bs;
#pragma unroll
            for (int dy = -1; dy <= 1; ++dy) {
                const int hh = h + dy;
                if (hh < 0 || hh >= 56) continue;
#pragma unroll
                for (int dx = -1; dx <= 1; ++dx) {
                    const int ww = w + dx;
                    if (ww < 0 || ww >= 56) continue;
                    acc = fmaf(wk[(dy + 1) * 3 + (dx + 1)], pl[hh * 57 + ww], acc);
                }
            }
            pks[e] = f2bu(acc / (1.f + __expf(-acc)));   // silu
        }
        *reinterpret_cast<ushort4*>(&up[4 * i4]) = pk;
    }

    float4* xo4 = reinterpret_cast<float4*>(xa + pb);
    for (int i = tid; i < 784; i += 256)
        xo4[i] = make_float4(xpl[4 * i], xpl[4 * i + 1], xpl[4 * i + 2], xpl[4 * i + 3]);
}

// ---------------------------------------------------------------------------
// Launch. Workspace layout (floats):
//   [0,512)              : BN affine a[256], b[256]
//   wcomb = W+512        : 256*49
//   bsum  = W+13056      : 256
//   part  = W+13312      : 256*8*2 partial BN sums -> ends 17408
//   Wb    = W+17408      : 768*256 bf16 (98304 fl) -> ends 115712
//   Wfb   = W+115712     : 256*256 bf16 (32768 fl) -> ends 148480
//   Wob   = W+148480     : 256*256 bf16 (32768 fl) -> ends 181248
//   xa    = W+181248     : NA fl — XNt alias (dead after QKV GEMM), attn
//                          output WINDOWED fp32, NORMAL after K5 (in-place)
//   R     = xa+NA        : 54,525,952 fl shared region:
//     phase 1: QKt us [b][3328][512] | Vb planes | XWW planes
//     phase 2: T bf16 (windowed order) + Uu bf16 (normal) in QKt region.
//   total ~ 321.6 MB
// ---------------------------------------------------------------------------
extern "C" void kernel_launch(void* const* d_in, const int* in_sizes, int n_in,
                              void* d_out, int out_size, void* d_ws, size_t ws_size,
                              hipStream_t stream)
{
    (void)in_sizes; (void)n_in; (void)out_size; (void)ws_size;
    const float* x    = (const float*)d_in[0];
    const float* g    = (const float*)d_in[1];
    const float* be   = (const float*)d_in[2];
    const float* qkvw = (const float*)d_in[3];
    const float* qkvb = (const float*)d_in[4];
    const float* w3   = (const float*)d_in[5];
    const float* b3   = (const float*)d_in[6];
    const float* w5   = (const float*)d_in[7];
    const float* b5   = (const float*)d_in[8];
    const float* w7   = (const float*)d_in[9];
    const float* b7   = (const float*)d_in[10];
    const float* fiw  = (const float*)d_in[11];
    const float* fib  = (const float*)d_in[12];
    const float* clw  = (const float*)d_in[13];
    const float* clb  = (const float*)d_in[14];
    const float* fow  = (const float*)d_in[15];
    const float* fob  = (const float*)d_in[16];
    float* out = (float*)d_out;

    float* W     = (float*)d_ws;
    float* ab    = W;
    float* wcomb = W + 512;
    float* bsum  = W + 13056;
    float* part  = W + 13312;
    __hip_bfloat16* Wb  = (__hip_bfloat16*)(W + 17408);
    __hip_bfloat16* Wfb = (__hip_bfloat16*)(W + 115712);
    __hip_bfloat16* Wob = (__hip_bfloat16*)(W + 148480);
    float* xa    = W + 181248;
    unsigned short* XNt = (unsigned short*)xa;              // dead after QKV GEMM
    float* R     = xa + NA;
    unsigned short* QKt = (unsigned short*)R;               // [b][3328][512]
    unsigned short* Vb  = QKt + (size_t)NB * NPW * 512;
    unsigned short* XWW = Vb + (size_t)NB * 256 * NPW;
    unsigned short* T   = (unsigned short*)R;               // bf16, in QKt region
    unsigned short* Uu  = T + NA;                           // bf16, in QKt region

    bn_part<<<dim3(256, 8), dim3(256), 0, stream>>>(x, part);
    bn_fin<<<dim3(256), dim3(256), 0, stream>>>(part, g, be, w3, b3, w5, b5, w7, b7,
                                                qkvw, fiw, fow, ab, wcomb, bsum,
                                                Wb, Wfb, Wob);
    xnt_make2<<<dim3(4, 8, NB), dim3(256), 0, stream>>>(x, ab, XNt, XWW);
    gemm_qkv_mfma<<<dim3(832, 6), dim3(256), 0, stream>>>(
        XNt, (const unsigned short*)Wb, qkvb, QKt, Vb);
    attn_mfma<<<dim3(64, 8, NB), dim3(64), 0, stream>>>(
        QKt, Vb, XWW, wcomb, bsum, xa);
    gemm_ffn_mfma<false, true><<<dim3(2, 784), dim3(256), 0, stream>>>(
        xa, nullptr, (const unsigned short*)Wfb, fib, nullptr, nullptr, T);
    dw3_silu<<<dim3(256, NB), dim3(256), 0, stream>>>(T, clw, clb, Uu, xa);
    gemm_ffn_mfma<true, false><<<dim3(2, 784), dim3(256), 0, stream>>>(
        nullptr, Uu, (const unsigned short*)Wob, fob, xa, out, nullptr);
}